// Round 9
// baseline (434.125 us; speedup 1.0000x reference)
//
#include <hip/hip_runtime.h>
#include <math.h>

#define D 128

typedef __attribute__((ext_vector_type(8))) short bf16x8;
typedef __attribute__((ext_vector_type(4))) float f32x4;

__device__ __forceinline__ float sigmoidf_(float x) { return 1.f / (1.f + __expf(-x)); }
__device__ __forceinline__ float bf2f(unsigned short u) { return __uint_as_float(((unsigned)u) << 16); }
__device__ __forceinline__ float u2f_lo(unsigned u) { return __uint_as_float(u << 16); }
__device__ __forceinline__ float u2f_hi(unsigned u) { return __uint_as_float(u & 0xffff0000u); }
__device__ __forceinline__ unsigned short f2b(float f) {
  unsigned u = __float_as_uint(f);
  return (unsigned short)((u + 0x7fffu + ((u >> 16) & 1u)) >> 16);  // RNE
}

// ---------- fp32 -> bf16 convert ----------
__global__ void __launch_bounds__(256) k_f2b(const float* __restrict__ in,
                                             unsigned short* __restrict__ out, int n) {
  int i = blockIdx.x * 256 + threadIdx.x;
  if (i < n) out[i] = f2b(in[i]);
}

// ---------- packing helpers ----------
__device__ __forceinline__ void pack_w_elem(const float* __restrict__ W,
                                            unsigned short* __restrict__ Bp, int i, int ncols16) {
  int j = i & 7;
  int lane = (i >> 3) & 63;
  int rest = i >> 9;
  int db = rest % ncols16;
  int kb = rest / ncols16;
  int k = kb * 32 + ((lane >> 4) << 3) + j;
  int col = db * 16 + (lane & 15);
  int h = col >> 7, d = col & 127;
  Bp[i] = f2b(W[((size_t)h * 128 + k) * 128 + d]);
}
__device__ __forceinline__ void pack_gru_elem(const float* __restrict__ S,
                                              unsigned short* __restrict__ Bp, int i) {
  int j = i & 7;
  int lane = (i >> 3) & 63;
  int rest = i >> 9;
  int db = rest % 24;
  int kb = rest / 24;
  int k = kb * 32 + ((lane >> 4) << 3) + j;
  int col = db * 16 + (lane & 15);
  Bp[i] = f2b(S[(size_t)col * 128 + k]);
}

// ---------- pack ALL weights in one dispatch ----------
__global__ void __launch_bounds__(256) k_pack_all(const float* __restrict__ W1, const float* __restrict__ W2,
                                                  const float* __restrict__ W3, const float* __restrict__ W4,
                                                  const float* __restrict__ Wih, const float* __restrict__ Whh,
                                                  unsigned short* __restrict__ B1, unsigned short* __restrict__ B2,
                                                  unsigned short* __restrict__ B3, unsigned short* __restrict__ B4,
                                                  unsigned short* __restrict__ Bih, unsigned short* __restrict__ Bhh) {
  int i = blockIdx.x * 256 + threadIdx.x;
  if (i < 65536) pack_w_elem(W1, B1, i, 32);
  else if (i < 131072) pack_w_elem(W2, B2, i - 65536, 32);
  else if (i < 196608) pack_w_elem(W3, B3, i - 131072, 32);
  else if (i < 212992) pack_w_elem(W4, B4, i - 196608, 8);
  else if (i < 262144) pack_gru_elem(Wih, Bih, i - 212992);
  else if (i < 311296) pack_gru_elem(Whh, Bhh, i - 262144);
}

// ---------- MFMA GEMM: M=64 / 8 waves; fused es/ed epilogue ----------
// wave w owns col-tiles [w*TPW, (w+1)*TPW); 4 row-fragments per wave.
template <int NCOLS, bool FUSE>
__global__ void __launch_bounds__(512) k_wh_mfma(const unsigned short* __restrict__ hb,
                                                 const unsigned short* __restrict__ Bp,
                                                 unsigned short* __restrict__ Whb,
                                                 const float* __restrict__ a_src,
                                                 const float* __restrict__ a_dst,
                                                 float* __restrict__ es,
                                                 float* __restrict__ ed, int N) {
  constexpr int TPW = NCOLS / 128;  // 4 (NCOLS=512) or 1 (NCOLS=128)
  __shared__ float s_red[2][64][8];
  const int n0 = blockIdx.x * 64;
  const int w = threadIdx.x >> 6;
  const int lane = threadIdx.x & 63;
  const int r = lane & 15, g = lane >> 4;
  f32x4 acc[4][TPW];
#pragma unroll
  for (int m = 0; m < 4; ++m)
#pragma unroll
    for (int t = 0; t < TPW; ++t) acc[m][t] = (f32x4)0.f;
  const int koff = g << 3;
#pragma unroll
  for (int kb = 0; kb < 4; ++kb) {
    bf16x8 a[4];
#pragma unroll
    for (int m = 0; m < 4; ++m) {
      int row = n0 + m * 16 + r;
      row = min(row, N - 1);
      a[m] = *(const bf16x8*)&hb[(size_t)row * 128 + kb * 32 + koff];
    }
#pragma unroll
    for (int t = 0; t < TPW; ++t) {
      const int ct = w * TPW + t;
      bf16x8 b = *(const bf16x8*)&Bp[((size_t)(kb * (NCOLS / 16) + ct) * 64 + lane) * 8];
#pragma unroll
      for (int m = 0; m < 4; ++m) {
        acc[m][t] = __builtin_amdgcn_mfma_f32_16x16x32_bf16(a[m], b, acc[m][t], 0, 0, 0);
      }
    }
  }
  // store Whb
#pragma unroll
  for (int m = 0; m < 4; ++m) {
    const int rb = n0 + m * 16 + g * 4;
#pragma unroll
    for (int t = 0; t < TPW; ++t) {
      const int col = (w * TPW + t) * 16 + r;
#pragma unroll
      for (int i = 0; i < 4; ++i) {
        if (rb + i < N) Whb[(size_t)(rb + i) * NCOLS + col] = f2b(acc[m][t][i]);
      }
    }
  }
  if constexpr (FUSE) {
    float av[TPW], bv[TPW];
#pragma unroll
    for (int t = 0; t < TPW; ++t) {
      av[t] = a_src[(w * TPW + t) * 16 + r];
      bv[t] = a_dst[(w * TPW + t) * 16 + r];
    }
    float sp[4][4], dp[4][4];
#pragma unroll
    for (int m = 0; m < 4; ++m)
#pragma unroll
      for (int i = 0; i < 4; ++i) {
        float s = 0.f, dd = 0.f;
#pragma unroll
        for (int t = 0; t < TPW; ++t) {
          s += acc[m][t][i] * av[t];
          dd += acc[m][t][i] * bv[t];
        }
        sp[m][i] = s;
        dp[m][i] = dd;
      }
#pragma unroll
    for (int off = 1; off < 16; off <<= 1)
#pragma unroll
      for (int m = 0; m < 4; ++m)
#pragma unroll
        for (int i = 0; i < 4; ++i) {
          sp[m][i] += __shfl_xor(sp[m][i], off);
          dp[m][i] += __shfl_xor(dp[m][i], off);
        }
    if (r == 0) {
#pragma unroll
      for (int m = 0; m < 4; ++m)
#pragma unroll
        for (int i = 0; i < 4; ++i) {
          s_red[0][m * 16 + g * 4 + i][w] = sp[m][i];
          s_red[1][m * 16 + g * 4 + i][w] = dp[m][i];
        }
    }
    __syncthreads();
    const int tid = threadIdx.x;
    if constexpr (NCOLS == 512) {
      // head hh partial lives in waves 2*hh, 2*hh+1
      int c = tid >> 8;           // 0 = es, 1 = ed
      int rem = tid & 255;
      int row = rem >> 2;
      int hh = rem & 3;
      float val = s_red[c][row][2 * hh] + s_red[c][row][2 * hh + 1];
      int gr = n0 + row;
      if (gr < N) (c ? ed : es)[(size_t)gr * 4 + hh] = val;
    } else {
      if (tid < 128) {
        int c = tid >> 6;
        int row = tid & 63;
        float val = 0.f;
#pragma unroll
        for (int ww = 0; ww < 8; ++ww) val += s_red[c][row][ww];
        int gr = n0 + row;
        if (gr < N) (c ? ed : es)[gr] = val;
      }
    }
  }
}

// ---------- CSR build ----------
__global__ void __launch_bounds__(256) k_hist(const int* __restrict__ dst, int* __restrict__ deg, int E) {
  int e = blockIdx.x * 256 + threadIdx.x;
  if (e < E) atomicAdd(&deg[dst[e]], 1);
}

__global__ void __launch_bounds__(1024) k_scan(const int* __restrict__ deg, int* __restrict__ rowptr,
                                               int* __restrict__ fill, int N) {
  __shared__ int part[1024];
  const int tid = threadIdx.x;
  const int chunk = (N + 1023) / 1024;
  const int b = tid * chunk;
  const int e = min(N, b + chunk);
  int s = 0;
  for (int i = b; i < e; ++i) s += deg[i];
  part[tid] = s;
  __syncthreads();
  for (int off = 1; off < 1024; off <<= 1) {
    int v = (tid >= off) ? part[tid - off] : 0;
    __syncthreads();
    part[tid] += v;
    __syncthreads();
  }
  int run = (tid == 0) ? 0 : part[tid - 1];
  for (int i = b; i < e; ++i) {
    rowptr[i] = run;
    fill[i] = run;
    run += deg[i];
  }
  if (b < N && e == N) rowptr[N] = run;
}

__global__ void __launch_bounds__(256) k_scatter(const int* __restrict__ src, const int* __restrict__ dst,
                                                 int* __restrict__ fill, int* __restrict__ srcs, int E) {
  int e = blockIdx.x * 256 + threadIdx.x;
  if (e >= E) return;
  int pos = atomicAdd(&fill[dst[e]], 1);
  srcs[pos] = src[e];
}

// ---------- fused edge phase v5 (H=4): 64 lanes/node; LDS-cached phase-A values ----------
// EPI=0: agg f32; EPI=1: elu f32 + bf16; EPI=2: elu bf16 only
template <int EPI>
__global__ void __launch_bounds__(256) k_edge_fused4(const int* __restrict__ rowptr,
                                                     const int* __restrict__ srcs,
                                                     const float* __restrict__ es,
                                                     const float* __restrict__ ed,
                                                     const unsigned short* __restrict__ Whb,
                                                     float* __restrict__ outf,
                                                     unsigned short* __restrict__ outb,
                                                     int N) {
  __shared__ unsigned s_off[4][64];
  __shared__ float s_af[4][64][4];
  __shared__ float4 s_v[4][64];
  const int wid = threadIdx.x >> 6;
  const int t = blockIdx.x * 4 + wid;
  if (t >= N) return;
  const int lane = threadIdx.x & 63;
  const int q = lane & 15;
  const int b0 = rowptr[t];
  const int deg = rowptr[t + 1] - b0;
  if (deg == 0) {
    if (lane < 16) {
      if constexpr (EPI != 2) {
        *(float4*)&outf[(size_t)t * D + q * 8] = make_float4(0.f, 0.f, 0.f, 0.f);
        *(float4*)&outf[(size_t)t * D + q * 8 + 4] = make_float4(0.f, 0.f, 0.f, 0.f);
      }
      if constexpr (EPI != 0) {
        *(uint4*)&outb[(size_t)t * D + q * 8] = make_uint4(0u, 0u, 0u, 0u);
      }
    }
    return;
  }
  float edv[4];
#pragma unroll
  for (int h = 0; h < 4; ++h) edv[h] = ed[t * 4 + h];
  // ---- phase A: online softmax; first 64 edges' leaky values + offsets cached in LDS ----
  float m[4], den[4];
#pragma unroll
  for (int h = 0; h < 4; ++h) {
    m[h] = -1e30f;
    den[h] = 0.f;
  }
  for (int i = lane; i < deg; i += 64) {
    int s = srcs[b0 + i];
    float4 ev = *(const float4*)&es[(size_t)s * 4];
    float vv[4] = {ev.x + edv[0], ev.y + edv[1], ev.z + edv[2], ev.w + edv[3]};
#pragma unroll
    for (int h = 0; h < 4; ++h) {
      float v = vv[h];
      v = v > 0.f ? v : 0.2f * v;
      vv[h] = v;
      float nm = fmaxf(m[h], v);
      den[h] = den[h] * __expf(m[h] - nm) + __expf(v - nm);
      m[h] = nm;
    }
    if (i == lane) {
      s_off[wid][lane] = (unsigned)s << 10;  // row stride 1024 B
      s_v[wid][lane] = make_float4(vv[0], vv[1], vv[2], vv[3]);
    }
  }
#pragma unroll
  for (int off = 32; off; off >>= 1) {
#pragma unroll
    for (int h = 0; h < 4; ++h) {
      float om = __shfl_xor(m[h], off);
      float od = __shfl_xor(den[h], off);
      float nm = fmaxf(m[h], om);
      den[h] = den[h] * __expf(m[h] - nm) + od * __expf(om - nm);
      m[h] = nm;
    }
  }
  float rden[4];
#pragma unroll
  for (int h = 0; h < 4; ++h) rden[h] = 1.f / den[h];
  // ---- phase B: 1 dwordx4 per edge per lane, deep unroll ----
  float acc[8];
#pragma unroll
  for (int j = 0; j < 8; ++j) acc[j] = 0.f;
  const char* wptr = (const char*)Whb + (unsigned)lane * 16u;
  const int h4 = lane >> 4;
  for (int c0 = 0; c0 < deg; c0 += 64) {
    const int ce = min(64, deg - c0);
    if (c0 == 0) {
      if (lane < ce) {
        float4 vv = s_v[wid][lane];
        s_af[wid][lane][0] = __expf(vv.x - m[0]) * rden[0];
        s_af[wid][lane][1] = __expf(vv.y - m[1]) * rden[1];
        s_af[wid][lane][2] = __expf(vv.z - m[2]) * rden[2];
        s_af[wid][lane][3] = __expf(vv.w - m[3]) * rden[3];
      }
    } else {
      int i = c0 + lane;
      if (i < deg) {
        int s = srcs[b0 + i];
        s_off[wid][lane] = (unsigned)s << 10;
        float4 ev = *(const float4*)&es[(size_t)s * 4];
        float vv[4] = {ev.x + edv[0], ev.y + edv[1], ev.z + edv[2], ev.w + edv[3]};
#pragma unroll
        for (int h = 0; h < 4; ++h) {
          float v = vv[h];
          v = v > 0.f ? v : 0.2f * v;
          s_af[wid][lane][h] = __expf(v - m[h]) * rden[h];
        }
      }
    }
#pragma unroll 8
    for (int e = 0; e < ce; ++e) {
      unsigned idx = s_off[wid][e];
      float af = s_af[wid][e][h4];
      uint4 v = *(const uint4*)(wptr + idx);
      acc[0] += af * u2f_lo(v.x);
      acc[1] += af * u2f_hi(v.x);
      acc[2] += af * u2f_lo(v.y);
      acc[3] += af * u2f_hi(v.y);
      acc[4] += af * u2f_lo(v.z);
      acc[5] += af * u2f_hi(v.z);
      acc[6] += af * u2f_lo(v.w);
      acc[7] += af * u2f_hi(v.w);
    }
  }
  // fold 4 head-groups -> head-mean
#pragma unroll
  for (int j = 0; j < 8; ++j) {
    acc[j] += __shfl_xor(acc[j], 16);
    acc[j] += __shfl_xor(acc[j], 32);
  }
  if (lane < 16) {
    float o[8];
#pragma unroll
    for (int j = 0; j < 8; ++j) o[j] = acc[j] * 0.25f;
    if constexpr (EPI != 0) {
#pragma unroll
      for (int j = 0; j < 8; ++j) o[j] = o[j] > 0.f ? o[j] : expm1f(o[j]);
      uint4 pk;
      pk.x = (unsigned)f2b(o[0]) | ((unsigned)f2b(o[1]) << 16);
      pk.y = (unsigned)f2b(o[2]) | ((unsigned)f2b(o[3]) << 16);
      pk.z = (unsigned)f2b(o[4]) | ((unsigned)f2b(o[5]) << 16);
      pk.w = (unsigned)f2b(o[6]) | ((unsigned)f2b(o[7]) << 16);
      *(uint4*)&outb[(size_t)t * D + q * 8] = pk;
    }
    if constexpr (EPI != 2) {
      *(float4*)&outf[(size_t)t * D + q * 8] = make_float4(o[0], o[1], o[2], o[3]);
      *(float4*)&outf[(size_t)t * D + q * 8 + 4] = make_float4(o[4], o[5], o[6], o[7]);
    }
  }
}

// ---------- fused edge phase, H=1: 16-lane group per node (row = 256 B) ----------
template <int EPI>
__global__ void __launch_bounds__(256) k_edge_fused1(const int* __restrict__ rowptr,
                                                     const int* __restrict__ srcs,
                                                     const float* __restrict__ es,
                                                     const float* __restrict__ ed,
                                                     const unsigned short* __restrict__ Whb,
                                                     float* __restrict__ outf,
                                                     unsigned short* __restrict__ outb,
                                                     int N) {
  const int t = blockIdx.x * 16 + (threadIdx.x >> 4);
  if (t >= N) return;
  const int lane = threadIdx.x & 63;
  const int q = lane & 15;
  const int gbase = lane & 48;
  const int b0 = rowptr[t];
  const int deg = rowptr[t + 1] - b0;
  if (deg == 0) {
    if constexpr (EPI != 2) {
      *(float4*)&outf[(size_t)t * D + q * 8] = make_float4(0.f, 0.f, 0.f, 0.f);
      *(float4*)&outf[(size_t)t * D + q * 8 + 4] = make_float4(0.f, 0.f, 0.f, 0.f);
    }
    if constexpr (EPI != 0) {
      *(uint4*)&outb[(size_t)t * D + q * 8] = make_uint4(0u, 0u, 0u, 0u);
    }
    return;
  }
  float edv = ed[t];
  float m = -1e30f, den = 0.f, vreg = -1e30f;
  int sreg = 0;
  for (int i = q; i < deg; i += 16) {
    int s = srcs[b0 + i];
    float v = es[s] + edv;
    v = v > 0.f ? v : 0.2f * v;
    float nm = fmaxf(m, v);
    den = den * __expf(m - nm) + __expf(v - nm);
    m = nm;
    if (i == q) {
      sreg = s;
      vreg = v;
    }
  }
#pragma unroll
  for (int off = 1; off < 16; off <<= 1) {
    float om = __shfl_xor(m, off);
    float od = __shfl_xor(den, off);
    float nm = fmaxf(m, om);
    den = den * __expf(m - nm) + od * __expf(om - nm);
    m = nm;
  }
  float rden = 1.f / den;
  float acc[8];
#pragma unroll
  for (int j = 0; j < 8; ++j) acc[j] = 0.f;
  const unsigned short* whq = Whb + q * 8;
  for (int c0 = 0; c0 < deg; c0 += 16) {
    const int ce = min(16, deg - c0);
    float ar = 0.f;
    int sr = 0;
    if (c0 == 0) {
      sr = sreg;
      ar = __expf(vreg - m) * rden;
    } else {
      int i = c0 + q;
      if (i < deg) {
        int s = srcs[b0 + i];
        sr = s;
        float v = es[s] + edv;
        v = v > 0.f ? v : 0.2f * v;
        ar = __expf(v - m) * rden;
      }
    }
#pragma unroll 4
    for (int e = 0; e < ce; ++e) {
      int s = __shfl(sr, gbase + e);
      float a = __shfl(ar, gbase + e);
      bf16x8 v = *(const bf16x8*)&whq[(size_t)s * D];
#pragma unroll
      for (int j = 0; j < 8; ++j) {
        acc[j] += a * bf2f((unsigned short)v[j]);
      }
    }
  }
  float o[8];
#pragma unroll
  for (int j = 0; j < 8; ++j) o[j] = acc[j];
  if constexpr (EPI != 0) {
#pragma unroll
    for (int j = 0; j < 8; ++j) o[j] = o[j] > 0.f ? o[j] : expm1f(o[j]);
    uint4 pk;
    pk.x = (unsigned)f2b(o[0]) | ((unsigned)f2b(o[1]) << 16);
    pk.y = (unsigned)f2b(o[2]) | ((unsigned)f2b(o[3]) << 16);
    pk.z = (unsigned)f2b(o[4]) | ((unsigned)f2b(o[5]) << 16);
    pk.w = (unsigned)f2b(o[6]) | ((unsigned)f2b(o[7]) << 16);
    *(uint4*)&outb[(size_t)t * D + q * 8] = pk;
  }
  if constexpr (EPI != 2) {
    *(float4*)&outf[(size_t)t * D + q * 8] = make_float4(o[0], o[1], o[2], o[3]);
    *(float4*)&outf[(size_t)t * D + q * 8 + 4] = make_float4(o[4], o[5], o[6], o[7]);
  }
}

// ---------- fused GRU: M=64 / 8 waves; wave w owns j-tile w across all 3 gates ----------
__global__ void __launch_bounds__(512) k_gru_mfma(const unsigned short* __restrict__ xb,
                                                  const unsigned short* __restrict__ hb,
                                                  const float* __restrict__ hf,
                                                  const unsigned short* __restrict__ Bih,
                                                  const unsigned short* __restrict__ Bhh,
                                                  const float* __restrict__ bih,
                                                  const float* __restrict__ bhh,
                                                  float* __restrict__ houtf,
                                                  unsigned short* __restrict__ houtb, int N) {
  const int n0 = blockIdx.x * 64;
  const int w = threadIdx.x >> 6;
  const int lane = threadIdx.x & 63;
  const int r = lane & 15, g = lane >> 4;
  f32x4 ai[3][4], ah[3][4];  // [gate][rowgroup]
#pragma unroll
  for (int p = 0; p < 3; ++p)
#pragma unroll
    for (int m = 0; m < 4; ++m) {
      ai[p][m] = (f32x4)0.f;
      ah[p][m] = (f32x4)0.f;
    }
  const int koff = g << 3;
#pragma unroll
  for (int kb = 0; kb < 4; ++kb) {
    bf16x8 ax[4], ahr[4];
#pragma unroll
    for (int m = 0; m < 4; ++m) {
      int row = n0 + m * 16 + r;
      row = min(row, N - 1);
      const size_t abase = (size_t)row * 128 + kb * 32 + koff;
      ax[m] = *(const bf16x8*)&xb[abase];
      ahr[m] = *(const bf16x8*)&hb[abase];
    }
#pragma unroll
    for (int p = 0; p < 3; ++p) {
      const int ct = p * 8 + w;
      bf16x8 bi = *(const bf16x8*)&Bih[((size_t)(kb * 24 + ct) * 64 + lane) * 8];
      bf16x8 bh = *(const bf16x8*)&Bhh[((size_t)(kb * 24 + ct) * 64 + lane) * 8];
#pragma unroll
      for (int m = 0; m < 4; ++m) {
        ai[p][m] = __builtin_amdgcn_mfma_f32_16x16x32_bf16(ax[m], bi, ai[p][m], 0, 0, 0);
        ah[p][m] = __builtin_amdgcn_mfma_f32_16x16x32_bf16(ahr[m], bh, ah[p][m], 0, 0, 0);
      }
    }
  }
  const int j = w * 16 + r;
  const float bir = bih[j], biz = bih[128 + j], bin = bih[256 + j];
  const float bhr = bhh[j], bhz = bhh[128 + j], bhn = bhh[256 + j];
#pragma unroll
  for (int m = 0; m < 4; ++m) {
#pragma unroll
    for (int i = 0; i < 4; ++i) {
      const int row = n0 + m * 16 + g * 4 + i;
      if (row < N) {
        float rr = sigmoidf_(ai[0][m][i] + bir + ah[0][m][i] + bhr);
        float z = sigmoidf_(ai[1][m][i] + biz + ah[1][m][i] + bhz);
        float nn = tanhf(ai[2][m][i] + bin + rr * (ah[2][m][i] + bhn));
        float hp = hf[(size_t)row * 128 + j];
        float o = (1.f - z) * nn + z * hp;
        houtf[(size_t)row * 128 + j] = o;
        houtb[(size_t)row * 128 + j] = f2b(o);
      }
    }
  }
}

// ---------- final: out[n] = sigmoid(dot(h[n,:], W5) + b5) ----------
__global__ void __launch_bounds__(256) k_final(const float* __restrict__ h, const float* __restrict__ W5,
                                               const float* __restrict__ b5, float* __restrict__ out, int N) {
  int w = blockIdx.x * 4 + (threadIdx.x >> 6);
  int lane = threadIdx.x & 63;
  if (w >= N) return;
  float x = h[(size_t)w * D + lane] * W5[lane] + h[(size_t)w * D + lane + 64] * W5[lane + 64];
#pragma unroll
  for (int off = 32; off; off >>= 1) x += __shfl_down(x, off);
  if (lane == 0) out[w] = sigmoidf_(x + b5[0]);
}

extern "C" void kernel_launch(void* const* d_in, const int* in_sizes, int n_in,
                              void* d_out, int out_size, void* d_ws, size_t ws_size,
                              hipStream_t stream) {
  const float* h0 = (const float*)d_in[0];
  const int* ei = (const int*)d_in[1];
  const float* W1 = (const float*)d_in[2];
  const float* as1 = (const float*)d_in[3];
  const float* ad1 = (const float*)d_in[4];
  const float* W2 = (const float*)d_in[5];
  const float* as2 = (const float*)d_in[6];
  const float* ad2 = (const float*)d_in[7];
  const float* W3 = (const float*)d_in[8];
  const float* as3 = (const float*)d_in[9];
  const float* ad3 = (const float*)d_in[10];
  const float* W4 = (const float*)d_in[11];
  const float* as4 = (const float*)d_in[12];
  const float* ad4 = (const float*)d_in[13];
  const float* Wih = (const float*)d_in[14];
  const float* Whh = (const float*)d_in[15];
  const float* bih = (const float*)d_in[16];
  const float* bhh = (const float*)d_in[17];
  const float* W5 = (const float*)d_in[18];
  const float* b5 = (const float*)d_in[19];

  const int N = in_sizes[0] / D;  // 20000
  const int E = in_sizes[1] / 2;  // 320000
  const int* src = ei;
  const int* dst = ei + E;

  // ---- workspace layout ----
  float* ws = (float*)d_ws;
  unsigned short* Whb = (unsigned short*)ws;          // N*512 us
  float* hA = ws + (size_t)N * 256;                   // N*128 f32
  float* hB = hA + (size_t)N * 128;                   // N*128 f32
  unsigned short* xb = (unsigned short*)(hB + (size_t)N * 128);  // N*128 us
  float* es = (float*)(xb + (size_t)N * 128);         // N*4
  float* ed = es + (size_t)N * 4;                     // N*4
  unsigned short* h0b = (unsigned short*)(ed + (size_t)N * 4);   // N*128 us
  unsigned short* hAb = h0b + (size_t)N * 128;        // N*128 us
  unsigned short* hBb = hAb + (size_t)N * 128;        // N*128 us
  unsigned short* B1 = hBb + (size_t)N * 128;         // 65536 us
  unsigned short* B2 = B1 + 65536;                    // 65536 us
  unsigned short* B3 = B2 + 65536;                    // 65536 us
  unsigned short* B4 = B3 + 65536;                    // 16384 us
  unsigned short* Bih = B4 + 16384;                   // 49152 us
  unsigned short* Bhh = Bih + 49152;                  // 49152 us
  int* deg = (int*)(Bhh + 49152);                     // N
  int* rowptr = deg + N;                              // N+1
  int* fill = rowptr + N + 1;                         // N
  int* srcs = fill + N;                               // E

  // ---- one-time prep ----
  k_f2b<<<(N * 128 + 255) / 256, 256, 0, stream>>>(h0, h0b, N * 128);
  k_pack_all<<<1216, 256, 0, stream>>>(W1, W2, W3, W4, Wih, Whh, B1, B2, B3, B4, Bih, Bhh);
  hipMemsetAsync(deg, 0, (size_t)N * 4, stream);
  k_hist<<<(E + 255) / 256, 256, 0, stream>>>(dst, deg, E);
  k_scan<<<1, 1024, 0, stream>>>(deg, rowptr, fill, N);
  k_scatter<<<(E + 255) / 256, 256, 0, stream>>>(src, dst, fill, srcs, E);

  const int gW = (N + 63) / 64;  // 313
  const int gE4 = (N + 3) / 4;   // 5000
  const int gE1 = (N + 15) / 16; // 1250
  // ---- layer 1: H=4, no GRU; edge emits elu as f32 (hA) + bf16 (hAb) ----
  k_wh_mfma<512, true><<<gW, 512, 0, stream>>>(h0b, B1, Whb, as1, ad1, es, ed, N);
  k_edge_fused4<1><<<gE4, 256, 0, stream>>>(rowptr, srcs, es, ed, Whb, hA, hAb, N);
  // ---- layer 2: H=4, GRU; edge emits xb bf16 only ----
  k_wh_mfma<512, true><<<gW, 512, 0, stream>>>(hAb, B2, Whb, as2, ad2, es, ed, N);
  k_edge_fused4<2><<<gE4, 256, 0, stream>>>(rowptr, srcs, es, ed, Whb, nullptr, xb, N);
  k_gru_mfma<<<gW, 512, 0, stream>>>(xb, hAb, hA, Bih, Bhh, bih, bhh, hB, hBb, N);
  // ---- layer 3: H=4, GRU ----
  k_wh_mfma<512, true><<<gW, 512, 0, stream>>>(hBb, B3, Whb, as3, ad3, es, ed, N);
  k_edge_fused4<2><<<gE4, 256, 0, stream>>>(rowptr, srcs, es, ed, Whb, nullptr, xb, N);
  k_gru_mfma<<<gW, 512, 0, stream>>>(xb, hBb, hB, Bih, Bhh, bih, bhh, hA, hAb, N);
  // ---- layer 4: H=1, GRU; es/ed fused into the GEMM ----
  k_wh_mfma<128, true><<<gW, 512, 0, stream>>>(hAb, B4, Whb, as4, ad4, es, ed, N);
  k_edge_fused1<2><<<gE1, 256, 0, stream>>>(rowptr, srcs, es, ed, Whb, nullptr, xb, N);
  k_gru_mfma<<<gW, 512, 0, stream>>>(xb, hAb, hA, Bih, Bhh, bih, bhh, hB, hBb, N);

  // ---- output head ----
  k_final<<<(N + 3) / 4, 256, 0, stream>>>(hB, W5, b5, (float*)d_out, N);
}

// Round 10
// 365.606 us; speedup vs baseline: 1.1874x; 1.1874x over previous
//
#include <hip/hip_runtime.h>
#include <math.h>

#define D 128

typedef __attribute__((ext_vector_type(8))) short bf16x8;
typedef __attribute__((ext_vector_type(4))) float f32x4;

__device__ __forceinline__ float sigmoidf_(float x) { return 1.f / (1.f + __expf(-x)); }
__device__ __forceinline__ float bf2f(unsigned short u) { return __uint_as_float(((unsigned)u) << 16); }
__device__ __forceinline__ float u2f_lo(unsigned u) { return __uint_as_float(u << 16); }
__device__ __forceinline__ float u2f_hi(unsigned u) { return __uint_as_float(u & 0xffff0000u); }
__device__ __forceinline__ unsigned short f2b(float f) {
  unsigned u = __float_as_uint(f);
  return (unsigned short)((u + 0x7fffu + ((u >> 16) & 1u)) >> 16);  // RNE
}

// ---------- fp32 -> bf16 convert ----------
__global__ void __launch_bounds__(256) k_f2b(const float* __restrict__ in,
                                             unsigned short* __restrict__ out, int n) {
  int i = blockIdx.x * 256 + threadIdx.x;
  if (i < n) out[i] = f2b(in[i]);
}

// ---------- packing helpers ----------
__device__ __forceinline__ void pack_w_elem(const float* __restrict__ W,
                                            unsigned short* __restrict__ Bp, int i, int ncols16) {
  int j = i & 7;
  int lane = (i >> 3) & 63;
  int rest = i >> 9;
  int db = rest % ncols16;
  int kb = rest / ncols16;
  int k = kb * 32 + ((lane >> 4) << 3) + j;
  int col = db * 16 + (lane & 15);
  int h = col >> 7, d = col & 127;
  Bp[i] = f2b(W[((size_t)h * 128 + k) * 128 + d]);
}
__device__ __forceinline__ void pack_gru_elem(const float* __restrict__ S,
                                              unsigned short* __restrict__ Bp, int i) {
  int j = i & 7;
  int lane = (i >> 3) & 63;
  int rest = i >> 9;
  int db = rest % 24;
  int kb = rest / 24;
  int k = kb * 32 + ((lane >> 4) << 3) + j;
  int col = db * 16 + (lane & 15);
  Bp[i] = f2b(S[(size_t)col * 128 + k]);
}

// ---------- pack ALL weights in one dispatch ----------
__global__ void __launch_bounds__(256) k_pack_all(const float* __restrict__ W1, const float* __restrict__ W2,
                                                  const float* __restrict__ W3, const float* __restrict__ W4,
                                                  const float* __restrict__ Wih, const float* __restrict__ Whh,
                                                  unsigned short* __restrict__ B1, unsigned short* __restrict__ B2,
                                                  unsigned short* __restrict__ B3, unsigned short* __restrict__ B4,
                                                  unsigned short* __restrict__ Bih, unsigned short* __restrict__ Bhh) {
  int i = blockIdx.x * 256 + threadIdx.x;
  if (i < 65536) pack_w_elem(W1, B1, i, 32);
  else if (i < 131072) pack_w_elem(W2, B2, i - 65536, 32);
  else if (i < 196608) pack_w_elem(W3, B3, i - 131072, 32);
  else if (i < 212992) pack_w_elem(W4, B4, i - 196608, 8);
  else if (i < 262144) pack_gru_elem(Wih, Bih, i - 212992);
  else if (i < 311296) pack_gru_elem(Whh, Bhh, i - 262144);
}

// ---------- MFMA GEMM: M=16, column-split grid; fused es/ed (NCOLS=512, NY=2) ----------
// blockIdx.y selects a 256-col slice (2 heads); wave slot handles TPW col-tiles.
template <int NCOLS, int NY, bool FUSE>
__global__ void __launch_bounds__(256) k_wh_mfma(const unsigned short* __restrict__ hb,
                                                 const unsigned short* __restrict__ Bp,
                                                 unsigned short* __restrict__ Whb,
                                                 const float* __restrict__ a_src,
                                                 const float* __restrict__ a_dst,
                                                 float* __restrict__ es,
                                                 float* __restrict__ ed) {
  constexpr int TPW = NCOLS / (64 * NY);  // 4 (512,NY=2) or 2 (128,NY=1)
  const int n0 = blockIdx.x * 16;
  const int w = threadIdx.x >> 6;
  const int lane = threadIdx.x & 63;
  const int r = lane & 15, g = lane >> 4;
  const int slot = blockIdx.y * 4 + w;
  f32x4 acc[TPW];
#pragma unroll
  for (int t = 0; t < TPW; ++t) acc[t] = (f32x4)0.f;
  const int koff = g << 3;
#pragma unroll
  for (int kb = 0; kb < 4; ++kb) {
    bf16x8 a = *(const bf16x8*)&hb[(size_t)(n0 + r) * 128 + kb * 32 + koff];
#pragma unroll
    for (int t = 0; t < TPW; ++t) {
      const int ct = slot * TPW + t;
      bf16x8 b = *(const bf16x8*)&Bp[((size_t)(kb * (NCOLS / 16) + ct) * 64 + lane) * 8];
      acc[t] = __builtin_amdgcn_mfma_f32_16x16x32_bf16(a, b, acc[t], 0, 0, 0);
    }
  }
  const int rbase = n0 + g * 4;
#pragma unroll
  for (int t = 0; t < TPW; ++t) {
    const int col = (slot * TPW + t) * 16 + r;
#pragma unroll
    for (int i = 0; i < 4; ++i) {
      Whb[(size_t)(rbase + i) * NCOLS + col] = f2b(acc[t][i]);
    }
  }
  if constexpr (FUSE) {
    // NCOLS=512, NY=2: block covers heads {2y, 2y+1}; wave w: head-local = w>>1, pair = w&1
    __shared__ float s_red[2][16][4];
    float av[TPW], bv[TPW];
#pragma unroll
    for (int t = 0; t < TPW; ++t) {
      const int col = (slot * TPW + t) * 16 + r;
      av[t] = a_src[col];
      bv[t] = a_dst[col];
    }
    float sp[4], dp[4];
#pragma unroll
    for (int i = 0; i < 4; ++i) {
      float s = 0.f, dd = 0.f;
#pragma unroll
      for (int t = 0; t < TPW; ++t) {
        s += acc[t][i] * av[t];
        dd += acc[t][i] * bv[t];
      }
      sp[i] = s;
      dp[i] = dd;
    }
#pragma unroll
    for (int off = 1; off < 16; off <<= 1)
#pragma unroll
      for (int i = 0; i < 4; ++i) {
        sp[i] += __shfl_xor(sp[i], off);
        dp[i] += __shfl_xor(dp[i], off);
      }
    if (r == 0) {
#pragma unroll
      for (int i = 0; i < 4; ++i) {
        s_red[0][g * 4 + i][w] = sp[i];
        s_red[1][g * 4 + i][w] = dp[i];
      }
    }
    __syncthreads();
    const int tid = threadIdx.x;
    if (tid < 64) {
      int c = tid >> 5;          // 0=es 1=ed
      int rem = tid & 31;
      int hl = rem >> 4;         // head-local
      int row = rem & 15;
      float val = s_red[c][row][hl * 2] + s_red[c][row][hl * 2 + 1];
      int head = blockIdx.y * 2 + hl;
      (c ? ed : es)[(size_t)(n0 + row) * 4 + head] = val;
    }
  }
}

// ---------- es/ed for H=1 (layer 4) ----------
__global__ void __launch_bounds__(256) k_es_ed1(const unsigned short* __restrict__ Whb,
                                                const float* __restrict__ a_src,
                                                const float* __restrict__ a_dst,
                                                float* __restrict__ es,
                                                float* __restrict__ ed, int N) {
  int w = blockIdx.x * 4 + (threadIdx.x >> 6);
  int lane = threadIdx.x & 63;
  if (w >= N) return;
  const unsigned short* row = Whb + (size_t)w * D;
  float x0 = bf2f(row[lane]), x1 = bf2f(row[lane + 64]);
  float s = x0 * a_src[lane] + x1 * a_src[lane + 64];
  float t = x0 * a_dst[lane] + x1 * a_dst[lane + 64];
#pragma unroll
  for (int off = 32; off; off >>= 1) {
    s += __shfl_down(s, off);
    t += __shfl_down(t, off);
  }
  if (lane == 0) {
    es[w] = s;
    ed[w] = t;
  }
}

// ---------- CSR build ----------
__global__ void __launch_bounds__(256) k_hist(const int* __restrict__ dst, int* __restrict__ deg, int E) {
  int e = blockIdx.x * 256 + threadIdx.x;
  if (e < E) atomicAdd(&deg[dst[e]], 1);
}

__global__ void __launch_bounds__(1024) k_scan(const int* __restrict__ deg, int* __restrict__ rowptr,
                                               int* __restrict__ fill, int N) {
  __shared__ int part[1024];
  const int tid = threadIdx.x;
  const int chunk = (N + 1023) / 1024;
  const int b = tid * chunk;
  const int e = min(N, b + chunk);
  int s = 0;
  for (int i = b; i < e; ++i) s += deg[i];
  part[tid] = s;
  __syncthreads();
  for (int off = 1; off < 1024; off <<= 1) {
    int v = (tid >= off) ? part[tid - off] : 0;
    __syncthreads();
    part[tid] += v;
    __syncthreads();
  }
  int run = (tid == 0) ? 0 : part[tid - 1];
  for (int i = b; i < e; ++i) {
    rowptr[i] = run;
    fill[i] = run;
    run += deg[i];
  }
  if (b < N && e == N) rowptr[N] = run;
}

__global__ void __launch_bounds__(256) k_scatter(const int* __restrict__ src, const int* __restrict__ dst,
                                                 int* __restrict__ fill, int* __restrict__ srcs, int E) {
  int e = blockIdx.x * 256 + threadIdx.x;
  if (e >= E) return;
  int pos = atomicAdd(&fill[dst[e]], 1);
  srcs[pos] = src[e];
}

// ---------- fused edge phase v4 (H=4): 64 lanes/node, LDS-staged alpha/offset (R8) ----------
// EPI=0: agg f32; EPI=1: elu f32 + bf16; EPI=2: elu bf16 only
template <int EPI>
__global__ void __launch_bounds__(256) k_edge_fused4(const int* __restrict__ rowptr,
                                                     const int* __restrict__ srcs,
                                                     const float* __restrict__ es,
                                                     const float* __restrict__ ed,
                                                     const unsigned short* __restrict__ Whb,
                                                     float* __restrict__ outf,
                                                     unsigned short* __restrict__ outb,
                                                     int N) {
  __shared__ unsigned s_off[4][64];
  __shared__ float s_af[4][64][4];
  const int wid = threadIdx.x >> 6;
  const int t = blockIdx.x * 4 + wid;
  if (t >= N) return;
  const int lane = threadIdx.x & 63;
  const int q = lane & 15;
  const int b0 = rowptr[t];
  const int deg = rowptr[t + 1] - b0;
  if (deg == 0) {
    if (lane < 16) {
      if constexpr (EPI != 2) {
        *(float4*)&outf[(size_t)t * D + q * 8] = make_float4(0.f, 0.f, 0.f, 0.f);
        *(float4*)&outf[(size_t)t * D + q * 8 + 4] = make_float4(0.f, 0.f, 0.f, 0.f);
      }
      if constexpr (EPI != 0) {
        *(uint4*)&outb[(size_t)t * D + q * 8] = make_uint4(0u, 0u, 0u, 0u);
      }
    }
    return;
  }
  float edv[4];
#pragma unroll
  for (int h = 0; h < 4; ++h) edv[h] = ed[t * 4 + h];
  // ---- phase A: online softmax across 64 lanes; keep first-chunk state in regs ----
  float m[4], den[4], vreg[4];
  int sreg = 0;
#pragma unroll
  for (int h = 0; h < 4; ++h) {
    m[h] = -1e30f;
    den[h] = 0.f;
    vreg[h] = -1e30f;
  }
  for (int i = lane; i < deg; i += 64) {
    int s = srcs[b0 + i];
    float4 ev = *(const float4*)&es[(size_t)s * 4];
    float vv[4] = {ev.x + edv[0], ev.y + edv[1], ev.z + edv[2], ev.w + edv[3]};
#pragma unroll
    for (int h = 0; h < 4; ++h) {
      float v = vv[h];
      v = v > 0.f ? v : 0.2f * v;
      vv[h] = v;
      float nm = fmaxf(m[h], v);
      den[h] = den[h] * __expf(m[h] - nm) + __expf(v - nm);
      m[h] = nm;
    }
    if (i == lane) {
      sreg = s;
#pragma unroll
      for (int h = 0; h < 4; ++h) vreg[h] = vv[h];
    }
  }
#pragma unroll
  for (int off = 32; off; off >>= 1) {
#pragma unroll
    for (int h = 0; h < 4; ++h) {
      float om = __shfl_xor(m[h], off);
      float od = __shfl_xor(den[h], off);
      float nm = fmaxf(m[h], om);
      den[h] = den[h] * __expf(m[h] - nm) + od * __expf(om - nm);
      m[h] = nm;
    }
  }
  float rden[4];
#pragma unroll
  for (int h = 0; h < 4; ++h) rden[h] = 1.f / den[h];
  // ---- phase B: LDS-staged {offset, alpha}; 1 dwordx4 per edge per lane ----
  float acc[8];
#pragma unroll
  for (int j = 0; j < 8; ++j) acc[j] = 0.f;
  const char* wbase = (const char*)Whb;
  const unsigned laneByte = (unsigned)lane * 16u;
  const int h4 = lane >> 4;
  for (int c0 = 0; c0 < deg; c0 += 64) {
    const int ce = min(64, deg - c0);
    if (c0 == 0) {
      if (lane < deg) {
        s_off[wid][lane] = (unsigned)sreg << 10;  // *1024 bytes per row
#pragma unroll
        for (int h = 0; h < 4; ++h)
          s_af[wid][lane][h] = __expf(vreg[h] - m[h]) * rden[h];
      }
    } else {
      int i = c0 + lane;
      if (i < deg) {
        int s = srcs[b0 + i];
        s_off[wid][lane] = (unsigned)s << 10;
        float4 ev = *(const float4*)&es[(size_t)s * 4];
        float vv[4] = {ev.x + edv[0], ev.y + edv[1], ev.z + edv[2], ev.w + edv[3]};
#pragma unroll
        for (int h = 0; h < 4; ++h) {
          float v = vv[h];
          v = v > 0.f ? v : 0.2f * v;
          s_af[wid][lane][h] = __expf(v - m[h]) * rden[h];
        }
      }
    }
#pragma unroll 4
    for (int e = 0; e < ce; ++e) {
      unsigned idx = s_off[wid][e] + laneByte;
      float af = s_af[wid][e][h4];
      uint4 v = *(const uint4*)(wbase + idx);
      acc[0] += af * u2f_lo(v.x);
      acc[1] += af * u2f_hi(v.x);
      acc[2] += af * u2f_lo(v.y);
      acc[3] += af * u2f_hi(v.y);
      acc[4] += af * u2f_lo(v.z);
      acc[5] += af * u2f_hi(v.z);
      acc[6] += af * u2f_lo(v.w);
      acc[7] += af * u2f_hi(v.w);
    }
  }
  // fold 4 head-groups -> head-mean
#pragma unroll
  for (int j = 0; j < 8; ++j) {
    acc[j] += __shfl_xor(acc[j], 16);
    acc[j] += __shfl_xor(acc[j], 32);
  }
  if (lane < 16) {
    float o[8];
#pragma unroll
    for (int j = 0; j < 8; ++j) o[j] = acc[j] * 0.25f;
    if constexpr (EPI != 0) {
#pragma unroll
      for (int j = 0; j < 8; ++j) o[j] = o[j] > 0.f ? o[j] : expm1f(o[j]);
      uint4 pk;
      pk.x = (unsigned)f2b(o[0]) | ((unsigned)f2b(o[1]) << 16);
      pk.y = (unsigned)f2b(o[2]) | ((unsigned)f2b(o[3]) << 16);
      pk.z = (unsigned)f2b(o[4]) | ((unsigned)f2b(o[5]) << 16);
      pk.w = (unsigned)f2b(o[6]) | ((unsigned)f2b(o[7]) << 16);
      *(uint4*)&outb[(size_t)t * D + q * 8] = pk;
    }
    if constexpr (EPI != 2) {
      *(float4*)&outf[(size_t)t * D + q * 8] = make_float4(o[0], o[1], o[2], o[3]);
      *(float4*)&outf[(size_t)t * D + q * 8 + 4] = make_float4(o[4], o[5], o[6], o[7]);
    }
  }
}

// ---------- fused edge phase, H=1: 16-lane group per node (row = 256 B) ----------
template <int EPI>
__global__ void __launch_bounds__(256) k_edge_fused1(const int* __restrict__ rowptr,
                                                     const int* __restrict__ srcs,
                                                     const float* __restrict__ es,
                                                     const float* __restrict__ ed,
                                                     const unsigned short* __restrict__ Whb,
                                                     float* __restrict__ outf,
                                                     unsigned short* __restrict__ outb,
                                                     int N) {
  const int t = blockIdx.x * 16 + (threadIdx.x >> 4);
  if (t >= N) return;
  const int lane = threadIdx.x & 63;
  const int q = lane & 15;
  const int gbase = lane & 48;
  const int b0 = rowptr[t];
  const int deg = rowptr[t + 1] - b0;
  if (deg == 0) {
    if constexpr (EPI != 2) {
      *(float4*)&outf[(size_t)t * D + q * 8] = make_float4(0.f, 0.f, 0.f, 0.f);
      *(float4*)&outf[(size_t)t * D + q * 8 + 4] = make_float4(0.f, 0.f, 0.f, 0.f);
    }
    if constexpr (EPI != 0) {
      *(uint4*)&outb[(size_t)t * D + q * 8] = make_uint4(0u, 0u, 0u, 0u);
    }
    return;
  }
  float edv = ed[t];
  float m = -1e30f, den = 0.f, vreg = -1e30f;
  int sreg = 0;
  for (int i = q; i < deg; i += 16) {
    int s = srcs[b0 + i];
    float v = es[s] + edv;
    v = v > 0.f ? v : 0.2f * v;
    float nm = fmaxf(m, v);
    den = den * __expf(m - nm) + __expf(v - nm);
    m = nm;
    if (i == q) {
      sreg = s;
      vreg = v;
    }
  }
#pragma unroll
  for (int off = 1; off < 16; off <<= 1) {
    float om = __shfl_xor(m, off);
    float od = __shfl_xor(den, off);
    float nm = fmaxf(m, om);
    den = den * __expf(m - nm) + od * __expf(om - nm);
    m = nm;
  }
  float rden = 1.f / den;
  float acc[8];
#pragma unroll
  for (int j = 0; j < 8; ++j) acc[j] = 0.f;
  const unsigned short* whq = Whb + q * 8;
  for (int c0 = 0; c0 < deg; c0 += 16) {
    const int ce = min(16, deg - c0);
    float ar = 0.f;
    int sr = 0;
    if (c0 == 0) {
      sr = sreg;
      ar = __expf(vreg - m) * rden;
    } else {
      int i = c0 + q;
      if (i < deg) {
        int s = srcs[b0 + i];
        sr = s;
        float v = es[s] + edv;
        v = v > 0.f ? v : 0.2f * v;
        ar = __expf(v - m) * rden;
      }
    }
#pragma unroll 2
    for (int e = 0; e < ce; ++e) {
      int s = __shfl(sr, gbase + e);
      float a = __shfl(ar, gbase + e);
      bf16x8 v = *(const bf16x8*)&whq[(size_t)s * D];
#pragma unroll
      for (int j = 0; j < 8; ++j) {
        acc[j] += a * bf2f((unsigned short)v[j]);
      }
    }
  }
  float o[8];
#pragma unroll
  for (int j = 0; j < 8; ++j) o[j] = acc[j];
  if constexpr (EPI != 0) {
#pragma unroll
    for (int j = 0; j < 8; ++j) o[j] = o[j] > 0.f ? o[j] : expm1f(o[j]);
    uint4 pk;
    pk.x = (unsigned)f2b(o[0]) | ((unsigned)f2b(o[1]) << 16);
    pk.y = (unsigned)f2b(o[2]) | ((unsigned)f2b(o[3]) << 16);
    pk.z = (unsigned)f2b(o[4]) | ((unsigned)f2b(o[5]) << 16);
    pk.w = (unsigned)f2b(o[6]) | ((unsigned)f2b(o[7]) << 16);
    *(uint4*)&outb[(size_t)t * D + q * 8] = pk;
  }
  if constexpr (EPI != 2) {
    *(float4*)&outf[(size_t)t * D + q * 8] = make_float4(o[0], o[1], o[2], o[3]);
    *(float4*)&outf[(size_t)t * D + q * 8 + 4] = make_float4(o[4], o[5], o[6], o[7]);
  }
}

// ---------- fused GRU: M=16 ----------
// MODE=0: grid (N/16, 2); wave handles j-tile q = y*4+w, all 3 gates; writes houtf/houtb.
// MODE=1: grid (N/16, 1); wave handles 2 j-tiles; fused sigmoid(h@W5+b5) head -> out.
template <int MODE>
__global__ void __launch_bounds__(256) k_gru_mfma(const unsigned short* __restrict__ xb,
                                                  const unsigned short* __restrict__ hb,
                                                  const float* __restrict__ hf,
                                                  const unsigned short* __restrict__ Bih,
                                                  const unsigned short* __restrict__ Bhh,
                                                  const float* __restrict__ bih,
                                                  const float* __restrict__ bhh,
                                                  float* __restrict__ houtf,
                                                  unsigned short* __restrict__ houtb,
                                                  const float* __restrict__ W5,
                                                  const float* __restrict__ b5,
                                                  float* __restrict__ out) {
  constexpr int QT = (MODE == 0) ? 1 : 2;
  const int n0 = blockIdx.x * 16;
  const int w = threadIdx.x >> 6;
  const int lane = threadIdx.x & 63;
  const int r = lane & 15, g = lane >> 4;
  const int qbase = (MODE == 0) ? (blockIdx.y * 4 + w) : (w * 2);
  f32x4 ai[3][QT], ah[3][QT];
#pragma unroll
  for (int p = 0; p < 3; ++p)
#pragma unroll
    for (int t = 0; t < QT; ++t) {
      ai[p][t] = (f32x4)0.f;
      ah[p][t] = (f32x4)0.f;
    }
  const int koff = g << 3;
#pragma unroll
  for (int kb = 0; kb < 4; ++kb) {
    const size_t abase = (size_t)(n0 + r) * 128 + kb * 32 + koff;
    bf16x8 ax = *(const bf16x8*)&xb[abase];
    bf16x8 ahr = *(const bf16x8*)&hb[abase];
#pragma unroll
    for (int p = 0; p < 3; ++p) {
#pragma unroll
      for (int t = 0; t < QT; ++t) {
        const int ct = p * 8 + qbase + t;
        bf16x8 bi = *(const bf16x8*)&Bih[((size_t)(kb * 24 + ct) * 64 + lane) * 8];
        bf16x8 bh = *(const bf16x8*)&Bhh[((size_t)(kb * 24 + ct) * 64 + lane) * 8];
        ai[p][t] = __builtin_amdgcn_mfma_f32_16x16x32_bf16(ax, bi, ai[p][t], 0, 0, 0);
        ah[p][t] = __builtin_amdgcn_mfma_f32_16x16x32_bf16(ahr, bh, ah[p][t], 0, 0, 0);
      }
    }
  }
  if constexpr (MODE == 0) {
    const int j = qbase * 16 + r;
    const float bir = bih[j], biz = bih[128 + j], bin = bih[256 + j];
    const float bhr = bhh[j], bhz = bhh[128 + j], bhn = bhh[256 + j];
#pragma unroll
    for (int i = 0; i < 4; ++i) {
      const int row = n0 + g * 4 + i;
      float rr = sigmoidf_(ai[0][0][i] + bir + ah[0][0][i] + bhr);
      float z = sigmoidf_(ai[1][0][i] + biz + ah[1][0][i] + bhz);
      float nn = tanhf(ai[2][0][i] + bin + rr * (ah[2][0][i] + bhn));
      float hp = hf[(size_t)row * 128 + j];
      float o = (1.f - z) * nn + z * hp;
      houtf[(size_t)row * 128 + j] = o;
      houtb[(size_t)row * 128 + j] = f2b(o);
    }
  } else {
    __shared__ float s_fin[16][4];
    float pfin[4] = {0.f, 0.f, 0.f, 0.f};
#pragma unroll
    for (int t = 0; t < QT; ++t) {
      const int j = (qbase + t) * 16 + r;
      const float bir = bih[j], biz = bih[128 + j], bin = bih[256 + j];
      const float bhr = bhh[j], bhz = bhh[128 + j], bhn = bhh[256 + j];
      const float w5 = W5[j];
#pragma unroll
      for (int i = 0; i < 4; ++i) {
        const int row = n0 + g * 4 + i;
        float rr = sigmoidf_(ai[0][t][i] + bir + ah[0][t][i] + bhr);
        float z = sigmoidf_(ai[1][t][i] + biz + ah[1][t][i] + bhz);
        float nn = tanhf(ai[2][t][i] + bin + rr * (ah[2][t][i] + bhn));
        float hp = hf[(size_t)row * 128 + j];
        float o = (1.f - z) * nn + z * hp;
        pfin[i] += o * w5;
      }
    }
#pragma unroll
    for (int off = 1; off < 16; off <<= 1)
#pragma unroll
      for (int i = 0; i < 4; ++i) pfin[i] += __shfl_xor(pfin[i], off);
    if (r == 0) {
#pragma unroll
      for (int i = 0; i < 4; ++i) s_fin[g * 4 + i][w] = pfin[i];
    }
    __syncthreads();
    if (threadIdx.x < 16) {
      float s = s_fin[threadIdx.x][0] + s_fin[threadIdx.x][1] +
                s_fin[threadIdx.x][2] + s_fin[threadIdx.x][3] + b5[0];
      out[n0 + threadIdx.x] = sigmoidf_(s);
    }
  }
}

extern "C" void kernel_launch(void* const* d_in, const int* in_sizes, int n_in,
                              void* d_out, int out_size, void* d_ws, size_t ws_size,
                              hipStream_t stream) {
  const float* h0 = (const float*)d_in[0];
  const int* ei = (const int*)d_in[1];
  const float* W1 = (const float*)d_in[2];
  const float* as1 = (const float*)d_in[3];
  const float* ad1 = (const float*)d_in[4];
  const float* W2 = (const float*)d_in[5];
  const float* as2 = (const float*)d_in[6];
  const float* ad2 = (const float*)d_in[7];
  const float* W3 = (const float*)d_in[8];
  const float* as3 = (const float*)d_in[9];
  const float* ad3 = (const float*)d_in[10];
  const float* W4 = (const float*)d_in[11];
  const float* as4 = (const float*)d_in[12];
  const float* ad4 = (const float*)d_in[13];
  const float* Wih = (const float*)d_in[14];
  const float* Whh = (const float*)d_in[15];
  const float* bih = (const float*)d_in[16];
  const float* bhh = (const float*)d_in[17];
  const float* W5 = (const float*)d_in[18];
  const float* b5 = (const float*)d_in[19];

  const int N = in_sizes[0] / D;  // 20000
  const int E = in_sizes[1] / 2;  // 320000
  const int* src = ei;
  const int* dst = ei + E;

  // ---- workspace layout ----
  float* ws = (float*)d_ws;
  unsigned short* Whb = (unsigned short*)ws;          // N*512 us
  float* hA = ws + (size_t)N * 256;                   // N*128 f32
  float* hB = hA + (size_t)N * 128;                   // N*128 f32
  unsigned short* xb = (unsigned short*)(hB + (size_t)N * 128);  // N*128 us
  float* es = (float*)(xb + (size_t)N * 128);         // N*4
  float* ed = es + (size_t)N * 4;                     // N*4
  unsigned short* h0b = (unsigned short*)(ed + (size_t)N * 4);   // N*128 us
  unsigned short* hAb = h0b + (size_t)N * 128;        // N*128 us
  unsigned short* hBb = hAb + (size_t)N * 128;        // N*128 us
  unsigned short* B1 = hBb + (size_t)N * 128;         // 65536 us
  unsigned short* B2 = B1 + 65536;                    // 65536 us
  unsigned short* B3 = B2 + 65536;                    // 65536 us
  unsigned short* B4 = B3 + 65536;                    // 16384 us
  unsigned short* Bih = B4 + 16384;                   // 49152 us
  unsigned short* Bhh = Bih + 49152;                  // 49152 us
  int* deg = (int*)(Bhh + 49152);                     // N
  int* rowptr = deg + N;                              // N+1
  int* fill = rowptr + N + 1;                         // N
  int* srcs = fill + N;                               // E

  // ---- one-time prep ----
  k_f2b<<<(N * 128 + 255) / 256, 256, 0, stream>>>(h0, h0b, N * 128);
  k_pack_all<<<1216, 256, 0, stream>>>(W1, W2, W3, W4, Wih, Whh, B1, B2, B3, B4, Bih, Bhh);
  hipMemsetAsync(deg, 0, (size_t)N * 4, stream);
  k_hist<<<(E + 255) / 256, 256, 0, stream>>>(dst, deg, E);
  k_scan<<<1, 1024, 0, stream>>>(deg, rowptr, fill, N);
  k_scatter<<<(E + 255) / 256, 256, 0, stream>>>(src, dst, fill, srcs, E);

  const int gW16 = N / 16;       // 1250
  const dim3 gW2(gW16, 2);
  const int gE4 = (N + 3) / 4;   // 5000
  const int gE1 = (N + 15) / 16; // 1250
  // ---- layer 1: H=4, no GRU; edge emits elu as f32 (hA) + bf16 (hAb) ----
  k_wh_mfma<512, 2, true><<<gW2, 256, 0, stream>>>(h0b, B1, Whb, as1, ad1, es, ed);
  k_edge_fused4<1><<<gE4, 256, 0, stream>>>(rowptr, srcs, es, ed, Whb, hA, hAb, N);
  // ---- layer 2: H=4, GRU; edge emits xb bf16 only ----
  k_wh_mfma<512, 2, true><<<gW2, 256, 0, stream>>>(hAb, B2, Whb, as2, ad2, es, ed);
  k_edge_fused4<2><<<gE4, 256, 0, stream>>>(rowptr, srcs, es, ed, Whb, nullptr, xb, N);
  k_gru_mfma<0><<<gW2, 256, 0, stream>>>(xb, hAb, hA, Bih, Bhh, bih, bhh, hB, hBb,
                                         nullptr, nullptr, nullptr);
  // ---- layer 3: H=4, GRU ----
  k_wh_mfma<512, 2, true><<<gW2, 256, 0, stream>>>(hBb, B3, Whb, as3, ad3, es, ed);
  k_edge_fused4<2><<<gE4, 256, 0, stream>>>(rowptr, srcs, es, ed, Whb, nullptr, xb, N);
  k_gru_mfma<0><<<gW2, 256, 0, stream>>>(xb, hBb, hB, Bih, Bhh, bih, bhh, hA, hAb,
                                         nullptr, nullptr, nullptr);
  // ---- layer 4: H=1, GRU + fused output head ----
  k_wh_mfma<128, 1, false><<<dim3(gW16, 1), 256, 0, stream>>>(hAb, B4, Whb, nullptr, nullptr, nullptr, nullptr);
  k_es_ed1<<<(N + 3) / 4, 256, 0, stream>>>(Whb, as4, ad4, es, ed, N);
  k_edge_fused1<2><<<gE1, 256, 0, stream>>>(rowptr, srcs, es, ed, Whb, nullptr, xb, N);
  k_gru_mfma<1><<<dim3(gW16, 1), 256, 0, stream>>>(xb, hAb, hA, Bih, Bhh, bih, bhh,
                                                   nullptr, nullptr, W5, b5, (float*)d_out);
}

// Round 11
// 344.732 us; speedup vs baseline: 1.2593x; 1.0606x over previous
//
#include <hip/hip_runtime.h>
#include <math.h>

#define D 128

typedef __attribute__((ext_vector_type(8))) short bf16x8;
typedef __attribute__((ext_vector_type(4))) float f32x4;

__device__ __forceinline__ float sigmoidf_(float x) { return 1.f / (1.f + __expf(-x)); }
__device__ __forceinline__ float bf2f(unsigned short u) { return __uint_as_float(((unsigned)u) << 16); }
__device__ __forceinline__ float u2f_lo(unsigned u) { return __uint_as_float(u << 16); }
__device__ __forceinline__ float u2f_hi(unsigned u) { return __uint_as_float(u & 0xffff0000u); }
__device__ __forceinline__ unsigned short f2b(float f) {
  unsigned u = __float_as_uint(f);
  return (unsigned short)((u + 0x7fffu + ((u >> 16) & 1u)) >> 16);  // RNE
}

// ---------- fp32 -> bf16 convert ----------
__global__ void __launch_bounds__(256) k_f2b(const float* __restrict__ in,
                                             unsigned short* __restrict__ out, int n) {
  int i = blockIdx.x * 256 + threadIdx.x;
  if (i < n) out[i] = f2b(in[i]);
}

// ---------- packing ----------
// post-GEMM B: Bp[((kb*8+db)*64+lane)*8+j] = W[h][k][d]*scale, k=kb*32+8*(lane>>4)+j (h=k>>7), d=db*16+(lane&15)
__device__ __forceinline__ void pack_post_elem(const float* __restrict__ W,
                                               unsigned short* __restrict__ Bp, int i, float scale) {
  int j = i & 7;
  int lane = (i >> 3) & 63;
  int rest = i >> 9;
  int db = rest & 7;
  int kb = rest >> 3;
  int k = kb * 32 + ((lane >> 4) << 3) + j;
  int d = db * 16 + (lane & 15);
  int h = k >> 7, kk = k & 127;
  Bp[i] = f2b(W[((size_t)h * 128 + kk) * 128 + d] * scale);
}
__device__ __forceinline__ void pack_gru_elem(const float* __restrict__ S,
                                              unsigned short* __restrict__ Bp, int i) {
  int j = i & 7;
  int lane = (i >> 3) & 63;
  int rest = i >> 9;
  int db = rest % 24;
  int kb = rest / 24;
  int k = kb * 32 + ((lane >> 4) << 3) + j;
  int col = db * 16 + (lane & 15);
  Bp[i] = f2b(S[(size_t)col * 128 + k]);
}

__global__ void __launch_bounds__(256) k_pack_all(const float* __restrict__ W1, const float* __restrict__ W2,
                                                  const float* __restrict__ W3, const float* __restrict__ W4,
                                                  const float* __restrict__ Wih, const float* __restrict__ Whh,
                                                  unsigned short* __restrict__ B1, unsigned short* __restrict__ B2,
                                                  unsigned short* __restrict__ B3, unsigned short* __restrict__ B4,
                                                  unsigned short* __restrict__ Bih, unsigned short* __restrict__ Bhh) {
  int i = blockIdx.x * 256 + threadIdx.x;
  if (i < 65536) pack_post_elem(W1, B1, i, 0.25f);
  else if (i < 131072) pack_post_elem(W2, B2, i - 65536, 0.25f);
  else if (i < 196608) pack_post_elem(W3, B3, i - 131072, 0.25f);
  else if (i < 212992) pack_post_elem(W4, B4, i - 196608, 1.0f);
  else if (i < 262144) pack_gru_elem(Wih, Bih, i - 212992);
  else if (i < 311296) pack_gru_elem(Whh, Bhh, i - 262144);
}

// ---------- projection vectors P = W@a, packed as MFMA B-frag [128 x 16] per layer ----------
// Pp[(kb*64+lane)*8+j] = P[k][col], k=kb*32+8*(lane>>4)+j, col=lane&15
// cols [0,H) = es proj, [H,2H) = ed proj, rest 0.
__global__ void __launch_bounds__(256) k_proj(const float* __restrict__ W1, const float* __restrict__ as1, const float* __restrict__ ad1,
                                              const float* __restrict__ W2, const float* __restrict__ as2, const float* __restrict__ ad2,
                                              const float* __restrict__ W3, const float* __restrict__ as3, const float* __restrict__ ad3,
                                              const float* __restrict__ W4, const float* __restrict__ as4, const float* __restrict__ ad4,
                                              unsigned short* __restrict__ Pp1, unsigned short* __restrict__ Pp2,
                                              unsigned short* __restrict__ Pp3, unsigned short* __restrict__ Pp4) {
  int tid = blockIdx.x * 256 + threadIdx.x;
  if (tid >= 4 * 2048) return;
  int layer = tid >> 11;
  int i = tid & 2047;
  int j = i & 7;
  int lane = (i >> 3) & 63;
  int kb = i >> 9;
  int k = kb * 32 + ((lane >> 4) << 3) + j;
  int col = lane & 15;
  const float *W, *as_, *ad_;
  unsigned short* out;
  int H;
  if (layer == 0) { W = W1; as_ = as1; ad_ = ad1; out = Pp1; H = 4; }
  else if (layer == 1) { W = W2; as_ = as2; ad_ = ad2; out = Pp2; H = 4; }
  else if (layer == 2) { W = W3; as_ = as3; ad_ = ad3; out = Pp3; H = 4; }
  else { W = W4; as_ = as4; ad_ = ad4; out = Pp4; H = 1; }
  float val = 0.f;
  if (col < 2 * H) {
    int c = (col >= H) ? 1 : 0;
    int h = c ? (col - H) : col;
    const float* wrow = W + ((size_t)h * 128 + k) * 128;
    const float* av = (c ? ad_ : as_) + (size_t)h * 128;
    for (int d2 = 0; d2 < 128; ++d2) val += wrow[d2] * av[d2];
  }
  out[i] = f2b(val);
}

// ---------- es/ed via MFMA: [es|ed](n, h) = hb[n,:] @ Pp ----------
template <int H>
__global__ void __launch_bounds__(256) k_esed(const unsigned short* __restrict__ hb,
                                              const unsigned short* __restrict__ Pp,
                                              float* __restrict__ es, float* __restrict__ ed, int N) {
  const int w = threadIdx.x >> 6;
  const int lane = threadIdx.x & 63;
  const int r = lane & 15, g = lane >> 4;
  const int n0 = blockIdx.x * 64 + w * 16;
  f32x4 acc = (f32x4)0.f;
  const int koff = g << 3;
#pragma unroll
  for (int kb = 0; kb < 4; ++kb) {
    int row = min(n0 + r, N - 1);
    bf16x8 a = *(const bf16x8*)&hb[(size_t)row * 128 + kb * 32 + koff];
    bf16x8 b = *(const bf16x8*)&Pp[((size_t)(kb * 64) + lane) * 8];
    acc = __builtin_amdgcn_mfma_f32_16x16x32_bf16(a, b, acc, 0, 0, 0);
  }
  const int rbase = n0 + g * 4;
#pragma unroll
  for (int i = 0; i < 4; ++i) {
    int row = rbase + i;
    if (row < N) {
      if (r < H) es[(size_t)row * H + r] = acc[i];
      else if (r < 2 * H) ed[(size_t)row * H + (r - H)] = acc[i];
    }
  }
}

// ---------- CSR build ----------
__global__ void __launch_bounds__(256) k_hist(const int* __restrict__ dst, int* __restrict__ deg, int E) {
  int e = blockIdx.x * 256 + threadIdx.x;
  if (e < E) atomicAdd(&deg[dst[e]], 1);
}

__global__ void __launch_bounds__(1024) k_scan(const int* __restrict__ deg, int* __restrict__ rowptr,
                                               int* __restrict__ fill, int N) {
  __shared__ int part[1024];
  const int tid = threadIdx.x;
  const int chunk = (N + 1023) / 1024;
  const int b = tid * chunk;
  const int e = min(N, b + chunk);
  int s = 0;
  for (int i = b; i < e; ++i) s += deg[i];
  part[tid] = s;
  __syncthreads();
  for (int off = 1; off < 1024; off <<= 1) {
    int v = (tid >= off) ? part[tid - off] : 0;
    __syncthreads();
    part[tid] += v;
    __syncthreads();
  }
  int run = (tid == 0) ? 0 : part[tid - 1];
  for (int i = b; i < e; ++i) {
    rowptr[i] = run;
    fill[i] = run;
    run += deg[i];
  }
  if (b < N && e == N) rowptr[N] = run;
}

__global__ void __launch_bounds__(256) k_scatter(const int* __restrict__ src, const int* __restrict__ dst,
                                                 int* __restrict__ fill, int* __restrict__ srcs, int E) {
  int e = blockIdx.x * 256 + threadIdx.x;
  if (e >= E) return;
  int pos = atomicAdd(&fill[dst[e]], 1);
  srcs[pos] = src[e];
}

// ---------- edge gather v6: aggregate t_h = sum_e alpha_eh * h[src_e] (256B rows) ----------
// 64 lanes/node, 4 nodes/block. Phase B: 4 edge-groups (eg=lane>>4) process 4 edges/step;
// lane q=lane&15 covers dims [8q,8q+8). Head-fold across groups via shfl_xor(16,32).
template <int H>
__global__ void __launch_bounds__(256) k_edge_gather(const int* __restrict__ rowptr,
                                                     const int* __restrict__ srcs,
                                                     const float* __restrict__ es,
                                                     const float* __restrict__ ed,
                                                     const unsigned short* __restrict__ hb,
                                                     unsigned short* __restrict__ tb, int N) {
  __shared__ unsigned s_off[4][64];
  __shared__ float s_af[4][64][H == 1 ? 1 : 4];
  const int wid = threadIdx.x >> 6;
  const int t = blockIdx.x * 4 + wid;
  if (t >= N) return;
  const int lane = threadIdx.x & 63;
  const int q = lane & 15;
  const int eg = lane >> 4;
  const int b0 = rowptr[t];
  const int deg = rowptr[t + 1] - b0;
  unsigned short* trow = tb + (size_t)t * (H * 128);
  if (deg == 0) {
    if (lane < 16) {
#pragma unroll
      for (int h = 0; h < H; ++h)
        *(uint4*)&trow[h * 128 + q * 8] = make_uint4(0u, 0u, 0u, 0u);
    }
    return;
  }
  float edv[H];
#pragma unroll
  for (int h = 0; h < H; ++h) edv[h] = ed[(size_t)t * H + h];
  // ---- phase A: online softmax across 64 lanes ----
  float m[H], den[H], vreg[H];
  int sreg = 0;
#pragma unroll
  for (int h = 0; h < H; ++h) {
    m[h] = -1e30f;
    den[h] = 0.f;
    vreg[h] = -1e30f;
  }
  for (int i = lane; i < deg; i += 64) {
    int s = srcs[b0 + i];
    float vv[H];
    if constexpr (H == 4) {
      float4 ev = *(const float4*)&es[(size_t)s * 4];
      vv[0] = ev.x + edv[0];
      vv[1] = ev.y + edv[1];
      vv[2] = ev.z + edv[2];
      vv[3] = ev.w + edv[3];
    } else {
      vv[0] = es[s] + edv[0];
    }
#pragma unroll
    for (int h = 0; h < H; ++h) {
      float v = vv[h];
      v = v > 0.f ? v : 0.2f * v;
      vv[h] = v;
      float nm = fmaxf(m[h], v);
      den[h] = den[h] * __expf(m[h] - nm) + __expf(v - nm);
      m[h] = nm;
    }
    if (i == lane) {
      sreg = s;
#pragma unroll
      for (int h = 0; h < H; ++h) vreg[h] = vv[h];
    }
  }
#pragma unroll
  for (int off = 32; off; off >>= 1) {
#pragma unroll
    for (int h = 0; h < H; ++h) {
      float om = __shfl_xor(m[h], off);
      float od = __shfl_xor(den[h], off);
      float nm = fmaxf(m[h], om);
      den[h] = den[h] * __expf(m[h] - nm) + od * __expf(om - nm);
      m[h] = nm;
    }
  }
  float rden[H];
#pragma unroll
  for (int h = 0; h < H; ++h) rden[h] = 1.f / den[h];
  // ---- phase B: 4 edges per wave-step; 16-lane group loads one 256B h-row ----
  float acc[H][8];
#pragma unroll
  for (int h = 0; h < H; ++h)
#pragma unroll
    for (int j = 0; j < 8; ++j) acc[h][j] = 0.f;
  const char* hbase = (const char*)hb + q * 16;
  for (int c0 = 0; c0 < deg; c0 += 64) {
    const int ce = min(64, deg - c0);
    if (c0 == 0) {
      bool ok = lane < deg;
      s_off[wid][lane] = ok ? ((unsigned)sreg << 8) : 0u;  // h row = 256 B
#pragma unroll
      for (int h = 0; h < H; ++h)
        s_af[wid][lane][h] = ok ? (__expf(vreg[h] - m[h]) * rden[h]) : 0.f;
    } else {
      int i = c0 + lane;
      bool ok = i < deg;
      int s = ok ? srcs[b0 + i] : 0;
      s_off[wid][lane] = ok ? ((unsigned)s << 8) : 0u;
      float af[H];
#pragma unroll
      for (int h = 0; h < H; ++h) af[h] = 0.f;
      if (ok) {
        float vv[H];
        if constexpr (H == 4) {
          float4 ev = *(const float4*)&es[(size_t)s * 4];
          vv[0] = ev.x + edv[0];
          vv[1] = ev.y + edv[1];
          vv[2] = ev.z + edv[2];
          vv[3] = ev.w + edv[3];
        } else {
          vv[0] = es[s] + edv[0];
        }
#pragma unroll
        for (int h = 0; h < H; ++h) {
          float v = vv[h];
          v = v > 0.f ? v : 0.2f * v;
          af[h] = __expf(v - m[h]) * rden[h];
        }
      }
#pragma unroll
      for (int h = 0; h < H; ++h) s_af[wid][lane][h] = af[h];
    }
    const int steps = (ce + 3) >> 2;
#pragma unroll 4
    for (int e = 0; e < steps; ++e) {
      const int ei = e * 4 + eg;  // all 64 staging slots initialized; padded slots have af=0
      unsigned off = s_off[wid][ei];
      float af[H];
      if constexpr (H == 4) {
        float4 a4 = *(const float4*)&s_af[wid][ei][0];
        af[0] = a4.x; af[1] = a4.y; af[2] = a4.z; af[3] = a4.w;
      } else {
        af[0] = s_af[wid][ei][0];
      }
      uint4 v = *(const uint4*)(hbase + off);
      float vf[8] = {u2f_lo(v.x), u2f_hi(v.x), u2f_lo(v.y), u2f_hi(v.y),
                     u2f_lo(v.z), u2f_hi(v.z), u2f_lo(v.w), u2f_hi(v.w)};
#pragma unroll
      for (int h = 0; h < H; ++h)
#pragma unroll
        for (int j = 0; j < 8; ++j) acc[h][j] += af[h] * vf[j];
    }
  }
  // fold 4 edge-groups
#pragma unroll
  for (int h = 0; h < H; ++h)
#pragma unroll
    for (int j = 0; j < 8; ++j) {
      acc[h][j] += __shfl_xor(acc[h][j], 16);
      acc[h][j] += __shfl_xor(acc[h][j], 32);
    }
  if (lane < 16) {
#pragma unroll
    for (int h = 0; h < H; ++h) {
      uint4 pk;
      pk.x = (unsigned)f2b(acc[h][0]) | ((unsigned)f2b(acc[h][1]) << 16);
      pk.y = (unsigned)f2b(acc[h][2]) | ((unsigned)f2b(acc[h][3]) << 16);
      pk.z = (unsigned)f2b(acc[h][4]) | ((unsigned)f2b(acc[h][5]) << 16);
      pk.w = (unsigned)f2b(acc[h][6]) | ((unsigned)f2b(acc[h][7]) << 16);
      *(uint4*)&trow[h * 128 + q * 8] = pk;
    }
  }
}

// ---------- post GEMM: agg = tb @ Bp ([N,KD]@[KD,128]); epilogue elu ----------
// EPI=1: write f32 (houtf) + bf16 (houtb); EPI=2: bf16 only
template <int KD, int EPI>
__global__ void __launch_bounds__(256) k_post(const unsigned short* __restrict__ tb,
                                              const unsigned short* __restrict__ Bp,
                                              float* __restrict__ houtf,
                                              unsigned short* __restrict__ houtb) {
  const int n0 = blockIdx.x * 16;
  const int w = threadIdx.x >> 6;
  const int lane = threadIdx.x & 63;
  const int r = lane & 15, g = lane >> 4;
  f32x4 acc[2];
  acc[0] = (f32x4)0.f;
  acc[1] = (f32x4)0.f;
  const int koff = g << 3;
#pragma unroll
  for (int kb = 0; kb < KD / 32; ++kb) {
    bf16x8 a = *(const bf16x8*)&tb[(size_t)(n0 + r) * KD + kb * 32 + koff];
#pragma unroll
    for (int t = 0; t < 2; ++t) {
      bf16x8 b = *(const bf16x8*)&Bp[((size_t)(kb * 8 + w * 2 + t) * 64 + lane) * 8];
      acc[t] = __builtin_amdgcn_mfma_f32_16x16x32_bf16(a, b, acc[t], 0, 0, 0);
    }
  }
#pragma unroll
  for (int t = 0; t < 2; ++t) {
    const int col = (w * 2 + t) * 16 + r;
#pragma unroll
    for (int i = 0; i < 4; ++i) {
      const int row = n0 + g * 4 + i;
      float o = acc[t][i];
      o = o > 0.f ? o : expm1f(o);
      if constexpr (EPI == 1) houtf[(size_t)row * 128 + col] = o;
      houtb[(size_t)row * 128 + col] = f2b(o);
    }
  }
}

// ---------- fused GRU: M=16 ----------
// MODE=0: grid (N/16, 2); writes houtf/houtb. MODE=1: grid (N/16,1); fused sigmoid(h@W5+b5) head.
template <int MODE>
__global__ void __launch_bounds__(256) k_gru_mfma(const unsigned short* __restrict__ xb,
                                                  const unsigned short* __restrict__ hb,
                                                  const float* __restrict__ hf,
                                                  const unsigned short* __restrict__ Bih,
                                                  const unsigned short* __restrict__ Bhh,
                                                  const float* __restrict__ bih,
                                                  const float* __restrict__ bhh,
                                                  float* __restrict__ houtf,
                                                  unsigned short* __restrict__ houtb,
                                                  const float* __restrict__ W5,
                                                  const float* __restrict__ b5,
                                                  float* __restrict__ out) {
  constexpr int QT = (MODE == 0) ? 1 : 2;
  const int n0 = blockIdx.x * 16;
  const int w = threadIdx.x >> 6;
  const int lane = threadIdx.x & 63;
  const int r = lane & 15, g = lane >> 4;
  const int qbase = (MODE == 0) ? (blockIdx.y * 4 + w) : (w * 2);
  f32x4 ai[3][QT], ah[3][QT];
#pragma unroll
  for (int p = 0; p < 3; ++p)
#pragma unroll
    for (int t = 0; t < QT; ++t) {
      ai[p][t] = (f32x4)0.f;
      ah[p][t] = (f32x4)0.f;
    }
  const int koff = g << 3;
#pragma unroll
  for (int kb = 0; kb < 4; ++kb) {
    const size_t abase = (size_t)(n0 + r) * 128 + kb * 32 + koff;
    bf16x8 ax = *(const bf16x8*)&xb[abase];
    bf16x8 ahr = *(const bf16x8*)&hb[abase];
#pragma unroll
    for (int p = 0; p < 3; ++p) {
#pragma unroll
      for (int t = 0; t < QT; ++t) {
        const int ct = p * 8 + qbase + t;
        bf16x8 bi = *(const bf16x8*)&Bih[((size_t)(kb * 24 + ct) * 64 + lane) * 8];
        bf16x8 bh = *(const bf16x8*)&Bhh[((size_t)(kb * 24 + ct) * 64 + lane) * 8];
        ai[p][t] = __builtin_amdgcn_mfma_f32_16x16x32_bf16(ax, bi, ai[p][t], 0, 0, 0);
        ah[p][t] = __builtin_amdgcn_mfma_f32_16x16x32_bf16(ahr, bh, ah[p][t], 0, 0, 0);
      }
    }
  }
  if constexpr (MODE == 0) {
    const int j = qbase * 16 + r;
    const float bir = bih[j], biz = bih[128 + j], bin = bih[256 + j];
    const float bhr = bhh[j], bhz = bhh[128 + j], bhn = bhh[256 + j];
#pragma unroll
    for (int i = 0; i < 4; ++i) {
      const int row = n0 + g * 4 + i;
      float rr = sigmoidf_(ai[0][0][i] + bir + ah[0][0][i] + bhr);
      float z = sigmoidf_(ai[1][0][i] + biz + ah[1][0][i] + bhz);
      float nn = tanhf(ai[2][0][i] + bin + rr * (ah[2][0][i] + bhn));
      float hp = hf[(size_t)row * 128 + j];
      float o = (1.f - z) * nn + z * hp;
      houtf[(size_t)row * 128 + j] = o;
      houtb[(size_t)row * 128 + j] = f2b(o);
    }
  } else {
    __shared__ float s_fin[16][4];
    float pfin[4] = {0.f, 0.f, 0.f, 0.f};
#pragma unroll
    for (int t = 0; t < QT; ++t) {
      const int j = (qbase + t) * 16 + r;
      const float bir = bih[j], biz = bih[128 + j], bin = bih[256 + j];
      const float bhr = bhh[j], bhz = bhh[128 + j], bhn = bhh[256 + j];
      const float w5 = W5[j];
#pragma unroll
      for (int i = 0; i < 4; ++i) {
        const int row = n0 + g * 4 + i;
        float rr = sigmoidf_(ai[0][t][i] + bir + ah[0][t][i] + bhr);
        float z = sigmoidf_(ai[1][t][i] + biz + ah[1][t][i] + bhz);
        float nn = tanhf(ai[2][t][i] + bin + rr * (ah[2][t][i] + bhn));
        float hp = hf[(size_t)row * 128 + j];
        float o = (1.f - z) * nn + z * hp;
        pfin[i] += o * w5;
      }
    }
#pragma unroll
    for (int off = 1; off < 16; off <<= 1)
#pragma unroll
      for (int i = 0; i < 4; ++i) pfin[i] += __shfl_xor(pfin[i], off);
    if (r == 0) {
#pragma unroll
      for (int i = 0; i < 4; ++i) s_fin[g * 4 + i][w] = pfin[i];
    }
    __syncthreads();
    if (threadIdx.x < 16) {
      float s = s_fin[threadIdx.x][0] + s_fin[threadIdx.x][1] +
                s_fin[threadIdx.x][2] + s_fin[threadIdx.x][3] + b5[0];
      out[n0 + threadIdx.x] = sigmoidf_(s);
    }
  }
}

extern "C" void kernel_launch(void* const* d_in, const int* in_sizes, int n_in,
                              void* d_out, int out_size, void* d_ws, size_t ws_size,
                              hipStream_t stream) {
  const float* h0 = (const float*)d_in[0];
  const int* ei = (const int*)d_in[1];
  const float* W1 = (const float*)d_in[2];
  const float* as1 = (const float*)d_in[3];
  const float* ad1 = (const float*)d_in[4];
  const float* W2 = (const float*)d_in[5];
  const float* as2 = (const float*)d_in[6];
  const float* ad2 = (const float*)d_in[7];
  const float* W3 = (const float*)d_in[8];
  const float* as3 = (const float*)d_in[9];
  const float* ad3 = (const float*)d_in[10];
  const float* W4 = (const float*)d_in[11];
  const float* as4 = (const float*)d_in[12];
  const float* ad4 = (const float*)d_in[13];
  const float* Wih = (const float*)d_in[14];
  const float* Whh = (const float*)d_in[15];
  const float* bih = (const float*)d_in[16];
  const float* bhh = (const float*)d_in[17];
  const float* W5 = (const float*)d_in[18];
  const float* b5 = (const float*)d_in[19];

  const int N = in_sizes[0] / D;  // 20000
  const int E = in_sizes[1] / 2;  // 320000
  const int* src = ei;
  const int* dst = ei + E;

  // ---- workspace layout ----
  float* ws = (float*)d_ws;
  unsigned short* tb = (unsigned short*)ws;           // N*512 us (reused for H=1: N*128)
  float* hA = ws + (size_t)N * 256;                   // N*128 f32
  float* hB = hA + (size_t)N * 128;                   // N*128 f32
  unsigned short* xb = (unsigned short*)(hB + (size_t)N * 128);  // N*128 us
  float* es = (float*)(xb + (size_t)N * 128);         // N*4
  float* ed = es + (size_t)N * 4;                     // N*4
  unsigned short* h0b = (unsigned short*)(ed + (size_t)N * 4);   // N*128 us
  unsigned short* hAb = h0b + (size_t)N * 128;        // N*128 us
  unsigned short* hBb = hAb + (size_t)N * 128;        // N*128 us
  unsigned short* B1 = hBb + (size_t)N * 128;         // 65536 us
  unsigned short* B2 = B1 + 65536;                    // 65536 us
  unsigned short* B3 = B2 + 65536;                    // 65536 us
  unsigned short* B4 = B3 + 65536;                    // 16384 us
  unsigned short* Bih = B4 + 16384;                   // 49152 us
  unsigned short* Bhh = Bih + 49152;                  // 49152 us
  unsigned short* Pp1 = Bhh + 49152;                  // 2048 us
  unsigned short* Pp2 = Pp1 + 2048;
  unsigned short* Pp3 = Pp2 + 2048;
  unsigned short* Pp4 = Pp3 + 2048;
  int* deg = (int*)(Pp4 + 2048);                      // N
  int* rowptr = deg + N;                              // N+1
  int* fill = rowptr + N + 1;                         // N
  int* srcs = fill + N;                               // E

  // ---- one-time prep ----
  k_f2b<<<(N * 128 + 255) / 256, 256, 0, stream>>>(h0, h0b, N * 128);
  k_pack_all<<<1216, 256, 0, stream>>>(W1, W2, W3, W4, Wih, Whh, B1, B2, B3, B4, Bih, Bhh);
  k_proj<<<32, 256, 0, stream>>>(W1, as1, ad1, W2, as2, ad2, W3, as3, ad3, W4, as4, ad4,
                                 Pp1, Pp2, Pp3, Pp4);
  hipMemsetAsync(deg, 0, (size_t)N * 4, stream);
  k_hist<<<(E + 255) / 256, 256, 0, stream>>>(dst, deg, E);
  k_scan<<<1, 1024, 0, stream>>>(deg, rowptr, fill, N);
  k_scatter<<<(E + 255) / 256, 256, 0, stream>>>(src, dst, fill, srcs, E);

  const int gES = (N + 63) / 64;  // 313
  const int gE = (N + 3) / 4;     // 5000
  const int gP = N / 16;          // 1250
  const dim3 gW2(gP, 2);

  // ---- layer 1: H=4, no GRU ----
  k_esed<4><<<gES, 256, 0, stream>>>(h0b, Pp1, es, ed, N);
  k_edge_gather<4><<<gE, 256, 0, stream>>>(rowptr, srcs, es, ed, h0b, tb, N);
  k_post<512, 1><<<gP, 256, 0, stream>>>(tb, B1, hA, hAb);
  // ---- layer 2: H=4, GRU ----
  k_esed<4><<<gES, 256, 0, stream>>>(hAb, Pp2, es, ed, N);
  k_edge_gather<4><<<gE, 256, 0, stream>>>(rowptr, srcs, es, ed, hAb, tb, N);
  k_post<512, 2><<<gP, 256, 0, stream>>>(tb, B2, nullptr, xb);
  k_gru_mfma<0><<<gW2, 256, 0, stream>>>(xb, hAb, hA, Bih, Bhh, bih, bhh, hB, hBb,
                                         nullptr, nullptr, nullptr);
  // ---- layer 3: H=4, GRU ----
  k_esed<4><<<gES, 256, 0, stream>>>(hBb, Pp3, es, ed, N);
  k_edge_gather<4><<<gE, 256, 0, stream>>>(rowptr, srcs, es, ed, hBb, tb, N);
  k_post<512, 2><<<gP, 256, 0, stream>>>(tb, B3, nullptr, xb);
  k_gru_mfma<0><<<gW2, 256, 0, stream>>>(xb, hBb, hB, Bih, Bhh, bih, bhh, hA, hAb,
                                         nullptr, nullptr, nullptr);
  // ---- layer 4: H=1, GRU + fused output head ----
  k_esed<1><<<gES, 256, 0, stream>>>(hAb, Pp4, es, ed, N);
  k_edge_gather<1><<<gE, 256, 0, stream>>>(rowptr, srcs, es, ed, hAb, tb, N);
  k_post<128, 2><<<gP, 256, 0, stream>>>(tb, B4, nullptr, xb);
  k_gru_mfma<1><<<dim3(gP, 1), 256, 0, stream>>>(xb, hAb, hA, Bih, Bhh, bih, bhh,
                                                 nullptr, nullptr, W5, b5, (float*)d_out);
}

// Round 12
// 332.116 us; speedup vs baseline: 1.3072x; 1.0380x over previous
//
#include <hip/hip_runtime.h>
#include <math.h>

#define D 128

typedef __attribute__((ext_vector_type(8))) short bf16x8;
typedef __attribute__((ext_vector_type(4))) float f32x4;

__device__ __forceinline__ float sigmoidf_(float x) { return 1.f / (1.f + __expf(-x)); }
__device__ __forceinline__ float bf2f(unsigned short u) { return __uint_as_float(((unsigned)u) << 16); }
__device__ __forceinline__ float u2f_lo(unsigned u) { return __uint_as_float(u << 16); }
__device__ __forceinline__ float u2f_hi(unsigned u) { return __uint_as_float(u & 0xffff0000u); }
__device__ __forceinline__ unsigned short f2b(float f) {
  unsigned u = __float_as_uint(f);
  return (unsigned short)((u + 0x7fffu + ((u >> 16) & 1u)) >> 16);  // RNE
}
__device__ __forceinline__ float leaky_(float v) { return v > 0.f ? v : 0.2f * v; }

// ---------- fp32 -> bf16 convert ----------
__global__ void __launch_bounds__(256) k_f2b(const float* __restrict__ in,
                                             unsigned short* __restrict__ out, int n) {
  int i = blockIdx.x * 256 + threadIdx.x;
  if (i < n) out[i] = f2b(in[i]);
}

// ---------- packing ----------
__device__ __forceinline__ void pack_post_elem(const float* __restrict__ W,
                                               unsigned short* __restrict__ Bp, int i, float scale) {
  int j = i & 7;
  int lane = (i >> 3) & 63;
  int rest = i >> 9;
  int db = rest & 7;
  int kb = rest >> 3;
  int k = kb * 32 + ((lane >> 4) << 3) + j;
  int d = db * 16 + (lane & 15);
  int h = k >> 7, kk = k & 127;
  Bp[i] = f2b(W[((size_t)h * 128 + kk) * 128 + d] * scale);
}
__device__ __forceinline__ void pack_gru_elem(const float* __restrict__ S,
                                              unsigned short* __restrict__ Bp, int i) {
  int j = i & 7;
  int lane = (i >> 3) & 63;
  int rest = i >> 9;
  int db = rest % 24;
  int kb = rest / 24;
  int k = kb * 32 + ((lane >> 4) << 3) + j;
  int col = db * 16 + (lane & 15);
  Bp[i] = f2b(S[(size_t)col * 128 + k]);
}

__global__ void __launch_bounds__(256) k_pack_all(const float* __restrict__ W1, const float* __restrict__ W2,
                                                  const float* __restrict__ W3, const float* __restrict__ W4,
                                                  const float* __restrict__ Wih, const float* __restrict__ Whh,
                                                  unsigned short* __restrict__ B1, unsigned short* __restrict__ B2,
                                                  unsigned short* __restrict__ B3, unsigned short* __restrict__ B4,
                                                  unsigned short* __restrict__ Bih, unsigned short* __restrict__ Bhh) {
  int i = blockIdx.x * 256 + threadIdx.x;
  if (i < 65536) pack_post_elem(W1, B1, i, 0.25f);
  else if (i < 131072) pack_post_elem(W2, B2, i - 65536, 0.25f);
  else if (i < 196608) pack_post_elem(W3, B3, i - 131072, 0.25f);
  else if (i < 212992) pack_post_elem(W4, B4, i - 196608, 1.0f);
  else if (i < 262144) pack_gru_elem(Wih, Bih, i - 212992);
  else if (i < 311296) pack_gru_elem(Whh, Bhh, i - 262144);
}

// ---------- projections: Pp1 (MFMA-packed, layer1) + plain Pf2/3/4 [128][8] f32 ----------
// Pf slots: 0..3 = es heads, 4..7 = ed heads (zero when h >= H).
__global__ void __launch_bounds__(256) k_proj(const float* __restrict__ W1, const float* __restrict__ as1, const float* __restrict__ ad1,
                                              const float* __restrict__ W2, const float* __restrict__ as2, const float* __restrict__ ad2,
                                              const float* __restrict__ W3, const float* __restrict__ as3, const float* __restrict__ ad3,
                                              const float* __restrict__ W4, const float* __restrict__ as4, const float* __restrict__ ad4,
                                              unsigned short* __restrict__ Pp1, float* __restrict__ Pf2,
                                              float* __restrict__ Pf3, float* __restrict__ Pf4) {
  int tid = blockIdx.x * 256 + threadIdx.x;
  if (tid < 2048) {
    int i = tid;
    int j = i & 7;
    int lane = (i >> 3) & 63;
    int kb = i >> 9;
    int k = kb * 32 + ((lane >> 4) << 3) + j;
    int col = lane & 15;
    float val = 0.f;
    if (col < 8) {
      int c = col >= 4;
      int h = c ? (col - 4) : col;
      const float* wrow = W1 + ((size_t)h * 128 + k) * 128;
      const float* av = (c ? ad1 : as1) + (size_t)h * 128;
      for (int d2 = 0; d2 < 128; ++d2) val += wrow[d2] * av[d2];
    }
    Pp1[i] = f2b(val);
  } else if (tid < 2048 + 3072) {
    int p = tid - 2048;
    int layer = p >> 10;
    int qq = p & 1023;
    int k = qq >> 3;
    int slot = qq & 7;
    const float *W, *as_, *ad_;
    float* out;
    int H;
    if (layer == 0) { W = W2; as_ = as2; ad_ = ad2; out = Pf2; H = 4; }
    else if (layer == 1) { W = W3; as_ = as3; ad_ = ad3; out = Pf3; H = 4; }
    else { W = W4; as_ = as4; ad_ = ad4; out = Pf4; H = 1; }
    int h = slot & 3;
    bool isEd = slot >= 4;
    float val = 0.f;
    if (h < H) {
      const float* wrow = W + ((size_t)h * 128 + k) * 128;
      const float* av = (isEd ? ad_ : as_) + (size_t)h * 128;
      for (int d2 = 0; d2 < 128; ++d2) val += wrow[d2] * av[d2];
    }
    out[qq] = val;
  }
}

// ---------- es/ed via MFMA (layer 1 only) ----------
__global__ void __launch_bounds__(256) k_esed(const unsigned short* __restrict__ hb,
                                              const unsigned short* __restrict__ Pp,
                                              float* __restrict__ es, float* __restrict__ ed, int N) {
  const int w = threadIdx.x >> 6;
  const int lane = threadIdx.x & 63;
  const int r = lane & 15, g = lane >> 4;
  const int n0 = blockIdx.x * 64 + w * 16;
  f32x4 acc = (f32x4)0.f;
  const int koff = g << 3;
#pragma unroll
  for (int kb = 0; kb < 4; ++kb) {
    int row = min(n0 + r, N - 1);
    bf16x8 a = *(const bf16x8*)&hb[(size_t)row * 128 + kb * 32 + koff];
    bf16x8 b = *(const bf16x8*)&Pp[((size_t)(kb * 64) + lane) * 8];
    acc = __builtin_amdgcn_mfma_f32_16x16x32_bf16(a, b, acc, 0, 0, 0);
  }
  const int rbase = n0 + g * 4;
#pragma unroll
  for (int i = 0; i < 4; ++i) {
    int row = rbase + i;
    if (row < N) {
      if (r < 4) es[(size_t)row * 4 + r] = acc[i];
      else if (r < 8) ed[(size_t)row * 4 + (r - 4)] = acc[i];
    }
  }
}

// ---------- CSR build ----------
__global__ void __launch_bounds__(256) k_hist(const int* __restrict__ dst, int* __restrict__ deg, int E) {
  int e = blockIdx.x * 256 + threadIdx.x;
  if (e < E) atomicAdd(&deg[dst[e]], 1);
}

__global__ void __launch_bounds__(1024) k_scan(const int* __restrict__ deg, int* __restrict__ rowptr,
                                               int* __restrict__ fill, int N) {
  __shared__ int part[1024];
  const int tid = threadIdx.x;
  const int chunk = (N + 1023) / 1024;
  const int b = tid * chunk;
  const int e = min(N, b + chunk);
  int s = 0;
  for (int i = b; i < e; ++i) s += deg[i];
  part[tid] = s;
  __syncthreads();
  for (int off = 1; off < 1024; off <<= 1) {
    int v = (tid >= off) ? part[tid - off] : 0;
    __syncthreads();
    part[tid] += v;
    __syncthreads();
  }
  int run = (tid == 0) ? 0 : part[tid - 1];
  for (int i = b; i < e; ++i) {
    rowptr[i] = run;
    fill[i] = run;
    run += deg[i];
  }
  if (b < N && e == N) rowptr[N] = run;
}

__global__ void __launch_bounds__(256) k_scatter(const int* __restrict__ src, const int* __restrict__ dst,
                                                 int* __restrict__ fill, int* __restrict__ srcs, int E) {
  int e = blockIdx.x * 256 + threadIdx.x;
  if (e >= E) return;
  int pos = atomicAdd(&fill[dst[e]], 1);
  srcs[pos] = src[e];
}

// ---------- edge gather v7: fast-path softmax (deg<=64), aggregate t_h = sum alpha_h h[src] ----------
template <int H>
__global__ void __launch_bounds__(256) k_edge_gather(const int* __restrict__ rowptr,
                                                     const int* __restrict__ srcs,
                                                     const float* __restrict__ es,
                                                     const float* __restrict__ ed,
                                                     const unsigned short* __restrict__ hb,
                                                     unsigned short* __restrict__ tb, int N) {
  __shared__ unsigned s_off[4][64];
  __shared__ float s_af[4][64][H == 1 ? 1 : 4];
  const int wid = threadIdx.x >> 6;
  const int t = blockIdx.x * 4 + wid;
  if (t >= N) return;
  const int lane = threadIdx.x & 63;
  const int q = lane & 15;
  const int eg = lane >> 4;
  const int b0 = rowptr[t];
  const int deg = rowptr[t + 1] - b0;
  unsigned short* trow = tb + (size_t)t * (H * 128);
  if (deg == 0) {
    if (lane < 16) {
#pragma unroll
      for (int h = 0; h < H; ++h)
        *(uint4*)&trow[h * 128 + q * 8] = make_uint4(0u, 0u, 0u, 0u);
    }
    return;
  }
  float edv[H];
#pragma unroll
  for (int h = 0; h < H; ++h) edv[h] = ed[(size_t)t * H + h];

  float acc[H][8];
#pragma unroll
  for (int h = 0; h < H; ++h)
#pragma unroll
    for (int j = 0; j < 8; ++j) acc[h][j] = 0.f;
  const char* hbase = (const char*)hb + q * 16;

  if (deg <= 64) {
    // ---- fast path: 1 edge/lane; max-reduce, single exp/edge, sum-reduce ----
    const bool act = lane < deg;
    int s = 0;
    float vv[H];
    if (act) {
      s = srcs[b0 + lane];
      if constexpr (H == 4) {
        float4 ev = *(const float4*)&es[(size_t)s * 4];
        vv[0] = leaky_(ev.x + edv[0]);
        vv[1] = leaky_(ev.y + edv[1]);
        vv[2] = leaky_(ev.z + edv[2]);
        vv[3] = leaky_(ev.w + edv[3]);
      } else {
        vv[0] = leaky_(es[s] + edv[0]);
      }
    } else {
#pragma unroll
      for (int h = 0; h < H; ++h) vv[h] = -1e30f;
    }
    float mv[H];
#pragma unroll
    for (int h = 0; h < H; ++h) mv[h] = vv[h];
#pragma unroll
    for (int off = 32; off; off >>= 1)
#pragma unroll
      for (int h = 0; h < H; ++h) mv[h] = fmaxf(mv[h], __shfl_xor(mv[h], off));
    float e[H], den[H];
#pragma unroll
    for (int h = 0; h < H; ++h) {
      e[h] = act ? __expf(vv[h] - mv[h]) : 0.f;
      den[h] = e[h];
    }
#pragma unroll
    for (int off = 32; off; off >>= 1)
#pragma unroll
      for (int h = 0; h < H; ++h) den[h] += __shfl_xor(den[h], off);
    s_off[wid][lane] = act ? ((unsigned)s << 8) : 0u;
#pragma unroll
    for (int h = 0; h < H; ++h) s_af[wid][lane][h] = e[h] * (1.f / den[h]);
    const int steps = (deg + 3) >> 2;
#pragma unroll 4
    for (int e2 = 0; e2 < steps; ++e2) {
      const int ei = e2 * 4 + eg;
      unsigned off = s_off[wid][ei];
      float af[H];
      if constexpr (H == 4) {
        float4 a4 = *(const float4*)&s_af[wid][ei][0];
        af[0] = a4.x; af[1] = a4.y; af[2] = a4.z; af[3] = a4.w;
      } else {
        af[0] = s_af[wid][ei][0];
      }
      uint4 v = *(const uint4*)(hbase + off);
      float vf[8] = {u2f_lo(v.x), u2f_hi(v.x), u2f_lo(v.y), u2f_hi(v.y),
                     u2f_lo(v.z), u2f_hi(v.z), u2f_lo(v.w), u2f_hi(v.w)};
#pragma unroll
      for (int h = 0; h < H; ++h)
#pragma unroll
        for (int j = 0; j < 8; ++j) acc[h][j] += af[h] * vf[j];
    }
  } else {
    // ---- slow path (deg > 64): online softmax + chunked staging ----
    float m[H], den[H], vreg[H];
    int sreg = 0;
#pragma unroll
    for (int h = 0; h < H; ++h) {
      m[h] = -1e30f;
      den[h] = 0.f;
      vreg[h] = -1e30f;
    }
    for (int i = lane; i < deg; i += 64) {
      int s = srcs[b0 + i];
      float vv[H];
      if constexpr (H == 4) {
        float4 ev = *(const float4*)&es[(size_t)s * 4];
        vv[0] = ev.x + edv[0];
        vv[1] = ev.y + edv[1];
        vv[2] = ev.z + edv[2];
        vv[3] = ev.w + edv[3];
      } else {
        vv[0] = es[s] + edv[0];
      }
#pragma unroll
      for (int h = 0; h < H; ++h) {
        float v = leaky_(vv[h]);
        vv[h] = v;
        float nm = fmaxf(m[h], v);
        den[h] = den[h] * __expf(m[h] - nm) + __expf(v - nm);
        m[h] = nm;
      }
      if (i == lane) {
        sreg = s;
#pragma unroll
        for (int h = 0; h < H; ++h) vreg[h] = vv[h];
      }
    }
#pragma unroll
    for (int off = 32; off; off >>= 1) {
#pragma unroll
      for (int h = 0; h < H; ++h) {
        float om = __shfl_xor(m[h], off);
        float od = __shfl_xor(den[h], off);
        float nm = fmaxf(m[h], om);
        den[h] = den[h] * __expf(m[h] - nm) + od * __expf(om - nm);
        m[h] = nm;
      }
    }
    float rden[H];
#pragma unroll
    for (int h = 0; h < H; ++h) rden[h] = 1.f / den[h];
    for (int c0 = 0; c0 < deg; c0 += 64) {
      const int ce = min(64, deg - c0);
      if (c0 == 0) {
        bool ok = lane < deg;
        s_off[wid][lane] = ok ? ((unsigned)sreg << 8) : 0u;
#pragma unroll
        for (int h = 0; h < H; ++h)
          s_af[wid][lane][h] = ok ? (__expf(vreg[h] - m[h]) * rden[h]) : 0.f;
      } else {
        int i = c0 + lane;
        bool ok = i < deg;
        int s = ok ? srcs[b0 + i] : 0;
        s_off[wid][lane] = ok ? ((unsigned)s << 8) : 0u;
        float af[H];
#pragma unroll
        for (int h = 0; h < H; ++h) af[h] = 0.f;
        if (ok) {
          float vv[H];
          if constexpr (H == 4) {
            float4 ev = *(const float4*)&es[(size_t)s * 4];
            vv[0] = ev.x + edv[0];
            vv[1] = ev.y + edv[1];
            vv[2] = ev.z + edv[2];
            vv[3] = ev.w + edv[3];
          } else {
            vv[0] = es[s] + edv[0];
          }
#pragma unroll
          for (int h = 0; h < H; ++h)
            af[h] = __expf(leaky_(vv[h]) - m[h]) * rden[h];
        }
#pragma unroll
        for (int h = 0; h < H; ++h) s_af[wid][lane][h] = af[h];
      }
      const int steps = (ce + 3) >> 2;
#pragma unroll 4
      for (int e2 = 0; e2 < steps; ++e2) {
        const int ei = e2 * 4 + eg;
        unsigned off = s_off[wid][ei];
        float af[H];
        if constexpr (H == 4) {
          float4 a4 = *(const float4*)&s_af[wid][ei][0];
          af[0] = a4.x; af[1] = a4.y; af[2] = a4.z; af[3] = a4.w;
        } else {
          af[0] = s_af[wid][ei][0];
        }
        uint4 v = *(const uint4*)(hbase + off);
        float vf[8] = {u2f_lo(v.x), u2f_hi(v.x), u2f_lo(v.y), u2f_hi(v.y),
                       u2f_lo(v.z), u2f_hi(v.z), u2f_lo(v.w), u2f_hi(v.w)};
#pragma unroll
        for (int h = 0; h < H; ++h)
#pragma unroll
          for (int j = 0; j < 8; ++j) acc[h][j] += af[h] * vf[j];
      }
    }
  }
  // fold 4 edge-groups
#pragma unroll
  for (int h = 0; h < H; ++h)
#pragma unroll
    for (int j = 0; j < 8; ++j) {
      acc[h][j] += __shfl_xor(acc[h][j], 16);
      acc[h][j] += __shfl_xor(acc[h][j], 32);
    }
  if (lane < 16) {
#pragma unroll
    for (int h = 0; h < H; ++h) {
      uint4 pk;
      pk.x = (unsigned)f2b(acc[h][0]) | ((unsigned)f2b(acc[h][1]) << 16);
      pk.y = (unsigned)f2b(acc[h][2]) | ((unsigned)f2b(acc[h][3]) << 16);
      pk.z = (unsigned)f2b(acc[h][4]) | ((unsigned)f2b(acc[h][5]) << 16);
      pk.w = (unsigned)f2b(acc[h][6]) | ((unsigned)f2b(acc[h][7]) << 16);
      *(uint4*)&trow[h * 128 + q * 8] = pk;
    }
  }
}

// ---------- post GEMM: agg = tb @ Bp; epilogue elu (+ optional next-layer es/ed proj) ----------
// EPI=1: write f32 + bf16 + proj(es/ed via Pf, Hn=4); EPI=2: bf16 only
template <int KD, int EPI>
__global__ void __launch_bounds__(256) k_post(const unsigned short* __restrict__ tb,
                                              const unsigned short* __restrict__ Bp,
                                              float* __restrict__ houtf,
                                              unsigned short* __restrict__ houtb,
                                              const float* __restrict__ Pf,
                                              float* __restrict__ es, float* __restrict__ ed) {
  __shared__ float s_pr[16][8][4];
  const int n0 = blockIdx.x * 16;
  const int w = threadIdx.x >> 6;
  const int lane = threadIdx.x & 63;
  const int r = lane & 15, g = lane >> 4;
  f32x4 acc[2];
  acc[0] = (f32x4)0.f;
  acc[1] = (f32x4)0.f;
  const int koff = g << 3;
#pragma unroll
  for (int kb = 0; kb < KD / 32; ++kb) {
    bf16x8 a = *(const bf16x8*)&tb[(size_t)(n0 + r) * KD + kb * 32 + koff];
#pragma unroll
    for (int t = 0; t < 2; ++t) {
      bf16x8 b = *(const bf16x8*)&Bp[((size_t)(kb * 8 + w * 2 + t) * 64 + lane) * 8];
      acc[t] = __builtin_amdgcn_mfma_f32_16x16x32_bf16(a, b, acc[t], 0, 0, 0);
    }
  }
  float ps[4][8];
  if constexpr (EPI == 1) {
#pragma unroll
    for (int i = 0; i < 4; ++i)
#pragma unroll
      for (int c = 0; c < 8; ++c) ps[i][c] = 0.f;
  }
#pragma unroll
  for (int t = 0; t < 2; ++t) {
    const int col = (w * 2 + t) * 16 + r;
    float4 pj0, pj1;
    if constexpr (EPI == 1) {
      pj0 = *(const float4*)&Pf[col * 8];
      pj1 = *(const float4*)&Pf[col * 8 + 4];
    }
#pragma unroll
    for (int i = 0; i < 4; ++i) {
      const int row = n0 + g * 4 + i;
      float o = acc[t][i];
      o = o > 0.f ? o : expm1f(o);
      if constexpr (EPI == 1) {
        houtf[(size_t)row * 128 + col] = o;
        ps[i][0] += o * pj0.x; ps[i][1] += o * pj0.y;
        ps[i][2] += o * pj0.z; ps[i][3] += o * pj0.w;
        ps[i][4] += o * pj1.x; ps[i][5] += o * pj1.y;
        ps[i][6] += o * pj1.z; ps[i][7] += o * pj1.w;
      }
      houtb[(size_t)row * 128 + col] = f2b(o);
    }
  }
  if constexpr (EPI == 1) {
#pragma unroll
    for (int off = 1; off < 16; off <<= 1)
#pragma unroll
      for (int i = 0; i < 4; ++i)
#pragma unroll
        for (int c = 0; c < 8; ++c) ps[i][c] += __shfl_xor(ps[i][c], off);
    if (r == 0) {
#pragma unroll
      for (int i = 0; i < 4; ++i)
#pragma unroll
        for (int c = 0; c < 8; ++c) s_pr[g * 4 + i][c][w] = ps[i][c];
    }
    __syncthreads();
    if (threadIdx.x < 128) {
      int row = threadIdx.x >> 3;
      int c = threadIdx.x & 7;
      float val = s_pr[row][c][0] + s_pr[row][c][1] + s_pr[row][c][2] + s_pr[row][c][3];
      int gr = n0 + row;
      if (c < 4) es[(size_t)gr * 4 + c] = val;
      else ed[(size_t)gr * 4 + (c - 4)] = val;
    }
  }
}

// ---------- fused GRU (QT=2, one block covers all 128 cols) ----------
// MODE=0: writes houtf/houtb + next-layer es/ed proj (Pf, Hn). MODE=1: fused sigmoid(h@W5+b5) head.
template <int MODE>
__global__ void __launch_bounds__(256) k_gru_mfma(const unsigned short* __restrict__ xb,
                                                  const unsigned short* __restrict__ hb,
                                                  const float* __restrict__ hf,
                                                  const unsigned short* __restrict__ Bih,
                                                  const unsigned short* __restrict__ Bhh,
                                                  const float* __restrict__ bih,
                                                  const float* __restrict__ bhh,
                                                  float* __restrict__ houtf,
                                                  unsigned short* __restrict__ houtb,
                                                  const float* __restrict__ Pf,
                                                  float* __restrict__ es, float* __restrict__ ed, int Hn,
                                                  const float* __restrict__ W5,
                                                  const float* __restrict__ b5,
                                                  float* __restrict__ out) {
  __shared__ float s_pr[16][8][4];
  const int n0 = blockIdx.x * 16;
  const int w = threadIdx.x >> 6;
  const int lane = threadIdx.x & 63;
  const int r = lane & 15, g = lane >> 4;
  const int qbase = w * 2;
  f32x4 ai[3][2], ah[3][2];
#pragma unroll
  for (int p = 0; p < 3; ++p)
#pragma unroll
    for (int t = 0; t < 2; ++t) {
      ai[p][t] = (f32x4)0.f;
      ah[p][t] = (f32x4)0.f;
    }
  const int koff = g << 3;
#pragma unroll
  for (int kb = 0; kb < 4; ++kb) {
    const size_t abase = (size_t)(n0 + r) * 128 + kb * 32 + koff;
    bf16x8 ax = *(const bf16x8*)&xb[abase];
    bf16x8 ahr = *(const bf16x8*)&hb[abase];
#pragma unroll
    for (int p = 0; p < 3; ++p) {
#pragma unroll
      for (int t = 0; t < 2; ++t) {
        const int ct = p * 8 + qbase + t;
        bf16x8 bi = *(const bf16x8*)&Bih[((size_t)(kb * 24 + ct) * 64 + lane) * 8];
        bf16x8 bh = *(const bf16x8*)&Bhh[((size_t)(kb * 24 + ct) * 64 + lane) * 8];
        ai[p][t] = __builtin_amdgcn_mfma_f32_16x16x32_bf16(ax, bi, ai[p][t], 0, 0, 0);
        ah[p][t] = __builtin_amdgcn_mfma_f32_16x16x32_bf16(ahr, bh, ah[p][t], 0, 0, 0);
      }
    }
  }
  if constexpr (MODE == 0) {
    float ps[4][8];
#pragma unroll
    for (int i = 0; i < 4; ++i)
#pragma unroll
      for (int c = 0; c < 8; ++c) ps[i][c] = 0.f;
#pragma unroll
    for (int t = 0; t < 2; ++t) {
      const int j = (qbase + t) * 16 + r;
      const float bir = bih[j], biz = bih[128 + j], bin = bih[256 + j];
      const float bhr = bhh[j], bhz = bhh[128 + j], bhn = bhh[256 + j];
      float4 pj0 = *(const float4*)&Pf[j * 8];
      float4 pj1 = *(const float4*)&Pf[j * 8 + 4];
#pragma unroll
      for (int i = 0; i < 4; ++i) {
        const int row = n0 + g * 4 + i;
        float rr = sigmoidf_(ai[0][t][i] + bir + ah[0][t][i] + bhr);
        float z = sigmoidf_(ai[1][t][i] + biz + ah[1][t][i] + bhz);
        float nn = tanhf(ai[2][t][i] + bin + rr * (ah[2][t][i] + bhn));
        float hp = hf[(size_t)row * 128 + j];
        float o = (1.f - z) * nn + z * hp;
        houtf[(size_t)row * 128 + j] = o;
        houtb[(size_t)row * 128 + j] = f2b(o);
        ps[i][0] += o * pj0.x; ps[i][1] += o * pj0.y;
        ps[i][2] += o * pj0.z; ps[i][3] += o * pj0.w;
        ps[i][4] += o * pj1.x; ps[i][5] += o * pj1.y;
        ps[i][6] += o * pj1.z; ps[i][7] += o * pj1.w;
      }
    }
#pragma unroll
    for (int off = 1; off < 16; off <<= 1)
#pragma unroll
      for (int i = 0; i < 4; ++i)
#pragma unroll
        for (int c = 0; c < 8; ++c) ps[i][c] += __shfl_xor(ps[i][c], off);
    if (r == 0) {
#pragma unroll
      for (int i = 0; i < 4; ++i)
#pragma unroll
        for (int c = 0; c < 8; ++c) s_pr[g * 4 + i][c][w] = ps[i][c];
    }
    __syncthreads();
    if (threadIdx.x < 128) {
      int row = threadIdx.x >> 3;
      int c = threadIdx.x & 7;
      float val = s_pr[row][c][0] + s_pr[row][c][1] + s_pr[row][c][2] + s_pr[row][c][3];
      int gr = n0 + row;
      if (c < Hn) es[(size_t)gr * Hn + c] = val;
      else if (c >= 4 && c < 4 + Hn) ed[(size_t)gr * Hn + (c - 4)] = val;
    }
  } else {
    float pfin[4] = {0.f, 0.f, 0.f, 0.f};
#pragma unroll
    for (int t = 0; t < 2; ++t) {
      const int j = (qbase + t) * 16 + r;
      const float bir = bih[j], biz = bih[128 + j], bin = bih[256 + j];
      const float bhr = bhh[j], bhz = bhh[128 + j], bhn = bhh[256 + j];
      const float w5 = W5[j];
#pragma unroll
      for (int i = 0; i < 4; ++i) {
        const int row = n0 + g * 4 + i;
        float rr = sigmoidf_(ai[0][t][i] + bir + ah[0][t][i] + bhr);
        float z = sigmoidf_(ai[1][t][i] + biz + ah[1][t][i] + bhz);
        float nn = tanhf(ai[2][t][i] + bin + rr * (ah[2][t][i] + bhn));
        float hp = hf[(size_t)row * 128 + j];
        float o = (1.f - z) * nn + z * hp;
        pfin[i] += o * w5;
      }
    }
#pragma unroll
    for (int off = 1; off < 16; off <<= 1)
#pragma unroll
      for (int i = 0; i < 4; ++i) pfin[i] += __shfl_xor(pfin[i], off);
    if (r == 0) {
#pragma unroll
      for (int i = 0; i < 4; ++i) s_pr[g * 4 + i][0][w] = pfin[i];
    }
    __syncthreads();
    if (threadIdx.x < 16) {
      float s = s_pr[threadIdx.x][0][0] + s_pr[threadIdx.x][0][1] +
                s_pr[threadIdx.x][0][2] + s_pr[threadIdx.x][0][3] + b5[0];
      out[n0 + threadIdx.x] = sigmoidf_(s);
    }
  }
}

extern "C" void kernel_launch(void* const* d_in, const int* in_sizes, int n_in,
                              void* d_out, int out_size, void* d_ws, size_t ws_size,
                              hipStream_t stream) {
  const float* h0 = (const float*)d_in[0];
  const int* ei = (const int*)d_in[1];
  const float* W1 = (const float*)d_in[2];
  const float* as1 = (const float*)d_in[3];
  const float* ad1 = (const float*)d_in[4];
  const float* W2 = (const float*)d_in[5];
  const float* as2 = (const float*)d_in[6];
  const float* ad2 = (const float*)d_in[7];
  const float* W3 = (const float*)d_in[8];
  const float* as3 = (const float*)d_in[9];
  const float* ad3 = (const float*)d_in[10];
  const float* W4 = (const float*)d_in[11];
  const float* as4 = (const float*)d_in[12];
  const float* ad4 = (const float*)d_in[13];
  const float* Wih = (const float*)d_in[14];
  const float* Whh = (const float*)d_in[15];
  const float* bih = (const float*)d_in[16];
  const float* bhh = (const float*)d_in[17];
  const float* W5 = (const float*)d_in[18];
  const float* b5 = (const float*)d_in[19];

  const int N = in_sizes[0] / D;  // 20000
  const int E = in_sizes[1] / 2;  // 320000
  const int* src = ei;
  const int* dst = ei + E;

  // ---- workspace layout ----
  float* ws = (float*)d_ws;
  unsigned short* tb = (unsigned short*)ws;           // N*512 us
  float* hA = ws + (size_t)N * 256;                   // N*128 f32
  float* hB = hA + (size_t)N * 128;                   // N*128 f32
  unsigned short* xb = (unsigned short*)(hB + (size_t)N * 128);  // N*128 us
  float* es = (float*)(xb + (size_t)N * 128);         // N*4
  float* ed = es + (size_t)N * 4;                     // N*4
  unsigned short* h0b = (unsigned short*)(ed + (size_t)N * 4);   // N*128 us
  unsigned short* hAb = h0b + (size_t)N * 128;        // N*128 us
  unsigned short* hBb = hAb + (size_t)N * 128;        // N*128 us
  unsigned short* B1 = hBb + (size_t)N * 128;         // 65536 us
  unsigned short* B2 = B1 + 65536;                    // 65536 us
  unsigned short* B3 = B2 + 65536;                    // 65536 us
  unsigned short* B4 = B3 + 65536;                    // 16384 us
  unsigned short* Bih = B4 + 16384;                   // 49152 us
  unsigned short* Bhh = Bih + 49152;                  // 49152 us
  unsigned short* Pp1 = Bhh + 49152;                  // 2048 us
  float* Pf2 = (float*)(Pp1 + 2048);                  // 1024 f
  float* Pf3 = Pf2 + 1024;                            // 1024 f
  float* Pf4 = Pf3 + 1024;                            // 1024 f
  int* deg = (int*)(Pf4 + 1024);                      // N
  int* rowptr = deg + N;                              // N+1
  int* fill = rowptr + N + 1;                         // N
  int* srcs = fill + N;                               // E

  // ---- one-time prep ----
  k_f2b<<<(N * 128 + 255) / 256, 256, 0, stream>>>(h0, h0b, N * 128);
  k_pack_all<<<1216, 256, 0, stream>>>(W1, W2, W3, W4, Wih, Whh, B1, B2, B3, B4, Bih, Bhh);
  k_proj<<<20, 256, 0, stream>>>(W1, as1, ad1, W2, as2, ad2, W3, as3, ad3, W4, as4, ad4,
                                 Pp1, Pf2, Pf3, Pf4);
  hipMemsetAsync(deg, 0, (size_t)N * 4, stream);
  k_hist<<<(E + 255) / 256, 256, 0, stream>>>(dst, deg, E);
  k_scan<<<1, 1024, 0, stream>>>(deg, rowptr, fill, N);
  k_scatter<<<(E + 255) / 256, 256, 0, stream>>>(src, dst, fill, srcs, E);

  const int gES = (N + 63) / 64;  // 313
  const int gE = (N + 3) / 4;     // 5000
  const int gP = N / 16;          // 1250

  // ---- layer 1: H=4, no GRU; post emits h1 + es/ed(L2) ----
  k_esed<<<gES, 256, 0, stream>>>(h0b, Pp1, es, ed, N);
  k_edge_gather<4><<<gE, 256, 0, stream>>>(rowptr, srcs, es, ed, h0b, tb, N);
  k_post<512, 1><<<gP, 256, 0, stream>>>(tb, B1, hA, hAb, Pf2, es, ed);
  // ---- layer 2: H=4, GRU emits h2 + es/ed(L3) ----
  k_edge_gather<4><<<gE, 256, 0, stream>>>(rowptr, srcs, es, ed, hAb, tb, N);
  k_post<512, 2><<<gP, 256, 0, stream>>>(tb, B2, nullptr, xb, nullptr, nullptr, nullptr);
  k_gru_mfma<0><<<gP, 256, 0, stream>>>(xb, hAb, hA, Bih, Bhh, bih, bhh, hB, hBb,
                                        Pf3, es, ed, 4, nullptr, nullptr, nullptr);
  // ---- layer 3: H=4, GRU emits h3 + es/ed(L4, H=1) ----
  k_edge_gather<4><<<gE, 256, 0, stream>>>(rowptr, srcs, es, ed, hBb, tb, N);
  k_post<512, 2><<<gP, 256, 0, stream>>>(tb, B3, nullptr, xb, nullptr, nullptr, nullptr);
  k_gru_mfma<0><<<gP, 256, 0, stream>>>(xb, hBb, hB, Bih, Bhh, bih, bhh, hA, hAb,
                                        Pf4, es, ed, 1, nullptr, nullptr, nullptr);
  // ---- layer 4: H=1, GRU + fused output head ----
  k_edge_gather<1><<<gE, 256, 0, stream>>>(rowptr, srcs, es, ed, hAb, tb, N);
  k_post<128, 2><<<gP, 256, 0, stream>>>(tb, B4, nullptr, xb, nullptr, nullptr, nullptr);
  k_gru_mfma<1><<<gP, 256, 0, stream>>>(xb, hAb, hA, Bih, Bhh, bih, bhh,
                                        nullptr, nullptr, nullptr, nullptr, nullptr, 0,
                                        W5, b5, (float*)d_out);
}

// Round 13
// 306.223 us; speedup vs baseline: 1.4177x; 1.0846x over previous
//
#include <hip/hip_runtime.h>
#include <math.h>

#define D 128

typedef __attribute__((ext_vector_type(8))) short bf16x8;
typedef __attribute__((ext_vector_type(4))) float f32x4;

__device__ __forceinline__ float sigmoidf_(float x) { return 1.f / (1.f + __expf(-x)); }
__device__ __forceinline__ float bf2f(unsigned short u) { return __uint_as_float(((unsigned)u) << 16); }
__device__ __forceinline__ float u2f_lo(unsigned u) { return __uint_as_float(u << 16); }
__device__ __forceinline__ float u2f_hi(unsigned u) { return __uint_as_float(u & 0xffff0000u); }
__device__ __forceinline__ unsigned short f2b(float f) {
  unsigned u = __float_as_uint(f);
  return (unsigned short)((u + 0x7fffu + ((u >> 16) & 1u)) >> 16);  // RNE
}
__device__ __forceinline__ float leaky_(float v) { return v > 0.f ? v : 0.2f * v; }

// ---------- packing helpers ----------
__device__ __forceinline__ void pack_post_elem(const float* __restrict__ W,
                                               unsigned short* __restrict__ Bp, int i, float scale) {
  int j = i & 7;
  int lane = (i >> 3) & 63;
  int rest = i >> 9;
  int db = rest & 7;
  int kb = rest >> 3;
  int k = kb * 32 + ((lane >> 4) << 3) + j;
  int d = db * 16 + (lane & 15);
  int h = k >> 7, kk = k & 127;
  Bp[i] = f2b(W[((size_t)h * 128 + kk) * 128 + d] * scale);
}
__device__ __forceinline__ void pack_gru_elem(const float* __restrict__ S,
                                              unsigned short* __restrict__ Bp, int i) {
  int j = i & 7;
  int lane = (i >> 3) & 63;
  int rest = i >> 9;
  int db = rest % 24;
  int kb = rest / 24;
  int k = kb * 32 + ((lane >> 4) << 3) + j;
  int col = db * 16 + (lane & 15);
  Bp[i] = f2b(S[(size_t)col * 128 + k]);
}

// ---------- mega prep: f2b(h0) + pack all weights + projections + degree histogram ----------
__global__ void __launch_bounds__(256) k_prep(const float* __restrict__ h0, unsigned short* __restrict__ h0b,
                                              const float* __restrict__ W1, const float* __restrict__ W2,
                                              const float* __restrict__ W3, const float* __restrict__ W4,
                                              const float* __restrict__ Wih, const float* __restrict__ Whh,
                                              unsigned short* __restrict__ B1, unsigned short* __restrict__ B2,
                                              unsigned short* __restrict__ B3, unsigned short* __restrict__ B4,
                                              unsigned short* __restrict__ Bih, unsigned short* __restrict__ Bhh,
                                              const float* __restrict__ as1, const float* __restrict__ ad1,
                                              const float* __restrict__ as2, const float* __restrict__ ad2,
                                              const float* __restrict__ as3, const float* __restrict__ ad3,
                                              const float* __restrict__ as4, const float* __restrict__ ad4,
                                              unsigned short* __restrict__ Pp1, float* __restrict__ Pf2,
                                              float* __restrict__ Pf3, float* __restrict__ Pf4,
                                              const int* __restrict__ dst, int* __restrict__ deg,
                                              int N, int E) {
  int i = blockIdx.x * 256 + threadIdx.x;
  const int NH = N * 128;
  if (i < NH) {
    h0b[i] = f2b(h0[i]);
    return;
  }
  i -= NH;
  if (i < 311296) {
    if (i < 65536) pack_post_elem(W1, B1, i, 0.25f);
    else if (i < 131072) pack_post_elem(W2, B2, i - 65536, 0.25f);
    else if (i < 196608) pack_post_elem(W3, B3, i - 131072, 0.25f);
    else if (i < 212992) pack_post_elem(W4, B4, i - 196608, 1.0f);
    else if (i < 262144) pack_gru_elem(Wih, Bih, i - 212992);
    else pack_gru_elem(Whh, Bhh, i - 262144);
    return;
  }
  i -= 311296;
  if (i < 2048) {
    // Pp1: MFMA-packed layer-1 projections (cols 0..3 es, 4..7 ed)
    int j = i & 7;
    int lane = (i >> 3) & 63;
    int kb = i >> 9;
    int k = kb * 32 + ((lane >> 4) << 3) + j;
    int col = lane & 15;
    float val = 0.f;
    if (col < 8) {
      int c = col >= 4;
      int h = c ? (col - 4) : col;
      const float* wrow = W1 + ((size_t)h * 128 + k) * 128;
      const float* av = (c ? ad1 : as1) + (size_t)h * 128;
      for (int d2 = 0; d2 < 128; ++d2) val += wrow[d2] * av[d2];
    }
    Pp1[i] = f2b(val);
    return;
  }
  i -= 2048;
  if (i < 3072) {
    // Pf2/3/4: plain-f32 projection tables [128][8]
    int layer = i >> 10;
    int qq = i & 1023;
    int k = qq >> 3;
    int slot = qq & 7;
    const float *W, *as_, *ad_;
    float* out;
    int H;
    if (layer == 0) { W = W2; as_ = as2; ad_ = ad2; out = Pf2; H = 4; }
    else if (layer == 1) { W = W3; as_ = as3; ad_ = ad3; out = Pf3; H = 4; }
    else { W = W4; as_ = as4; ad_ = ad4; out = Pf4; H = 1; }
    int h = slot & 3;
    bool isEd = slot >= 4;
    float val = 0.f;
    if (h < H) {
      const float* wrow = W + ((size_t)h * 128 + k) * 128;
      const float* av = (isEd ? ad_ : as_) + (size_t)h * 128;
      for (int d2 = 0; d2 < 128; ++d2) val += wrow[d2] * av[d2];
    }
    out[qq] = val;
    return;
  }
  i -= 3072;
  if (i < E) atomicAdd(&deg[dst[i]], 1);
}

// ---------- es/ed via MFMA (layer 1 only) ----------
__global__ void __launch_bounds__(256) k_esed(const unsigned short* __restrict__ hb,
                                              const unsigned short* __restrict__ Pp,
                                              float* __restrict__ es, float* __restrict__ ed, int N) {
  const int w = threadIdx.x >> 6;
  const int lane = threadIdx.x & 63;
  const int r = lane & 15, g = lane >> 4;
  const int n0 = blockIdx.x * 64 + w * 16;
  f32x4 acc = (f32x4)0.f;
  const int koff = g << 3;
#pragma unroll
  for (int kb = 0; kb < 4; ++kb) {
    int row = min(n0 + r, N - 1);
    bf16x8 a = *(const bf16x8*)&hb[(size_t)row * 128 + kb * 32 + koff];
    bf16x8 b = *(const bf16x8*)&Pp[((size_t)(kb * 64) + lane) * 8];
    acc = __builtin_amdgcn_mfma_f32_16x16x32_bf16(a, b, acc, 0, 0, 0);
  }
  const int rbase = n0 + g * 4;
#pragma unroll
  for (int i = 0; i < 4; ++i) {
    int row = rbase + i;
    if (row < N) {
      if (r < 4) es[(size_t)row * 4 + r] = acc[i];
      else if (r < 8) ed[(size_t)row * 4 + (r - 4)] = acc[i];
    }
  }
}

// ---------- CSR build ----------
__global__ void __launch_bounds__(1024) k_scan(const int* __restrict__ deg, int* __restrict__ rowptr,
                                               int* __restrict__ fill, int N) {
  __shared__ int part[1024];
  const int tid = threadIdx.x;
  const int chunk = (N + 1023) / 1024;
  const int b = tid * chunk;
  const int e = min(N, b + chunk);
  int s = 0;
  for (int i = b; i < e; ++i) s += deg[i];
  part[tid] = s;
  __syncthreads();
  for (int off = 1; off < 1024; off <<= 1) {
    int v = (tid >= off) ? part[tid - off] : 0;
    __syncthreads();
    part[tid] += v;
    __syncthreads();
  }
  int run = (tid == 0) ? 0 : part[tid - 1];
  for (int i = b; i < e; ++i) {
    rowptr[i] = run;
    fill[i] = run;
    run += deg[i];
  }
  if (b < N && e == N) rowptr[N] = run;
}

__global__ void __launch_bounds__(256) k_scatter(const int* __restrict__ src, const int* __restrict__ dst,
                                                 int* __restrict__ fill, int* __restrict__ srcs, int E) {
  int e = blockIdx.x * 256 + threadIdx.x;
  if (e >= E) return;
  int pos = atomicAdd(&fill[dst[e]], 1);
  srcs[pos] = src[e];
}

// ---------- edge gather v7: fast-path softmax (deg<=64), aggregate t_h = sum alpha_h h[src] ----------
template <int H>
__global__ void __launch_bounds__(256) k_edge_gather(const int* __restrict__ rowptr,
                                                     const int* __restrict__ srcs,
                                                     const float* __restrict__ es,
                                                     const float* __restrict__ ed,
                                                     const unsigned short* __restrict__ hb,
                                                     unsigned short* __restrict__ tb, int N) {
  __shared__ unsigned s_off[4][64];
  __shared__ float s_af[4][64][H == 1 ? 1 : 4];
  const int wid = threadIdx.x >> 6;
  const int t = blockIdx.x * 4 + wid;
  if (t >= N) return;
  const int lane = threadIdx.x & 63;
  const int q = lane & 15;
  const int eg = lane >> 4;
  const int b0 = rowptr[t];
  const int deg = rowptr[t + 1] - b0;
  unsigned short* trow = tb + (size_t)t * (H * 128);
  if (deg == 0) {
    if (lane < 16) {
#pragma unroll
      for (int h = 0; h < H; ++h)
        *(uint4*)&trow[h * 128 + q * 8] = make_uint4(0u, 0u, 0u, 0u);
    }
    return;
  }
  float edv[H];
#pragma unroll
  for (int h = 0; h < H; ++h) edv[h] = ed[(size_t)t * H + h];

  float acc[H][8];
#pragma unroll
  for (int h = 0; h < H; ++h)
#pragma unroll
    for (int j = 0; j < 8; ++j) acc[h][j] = 0.f;
  const char* hbase = (const char*)hb + q * 16;

  if (deg <= 64) {
    // ---- fast path: 1 edge/lane; max-reduce, single exp/edge, sum-reduce ----
    const bool act = lane < deg;
    int s = 0;
    float vv[H];
    if (act) {
      s = srcs[b0 + lane];
      if constexpr (H == 4) {
        float4 ev = *(const float4*)&es[(size_t)s * 4];
        vv[0] = leaky_(ev.x + edv[0]);
        vv[1] = leaky_(ev.y + edv[1]);
        vv[2] = leaky_(ev.z + edv[2]);
        vv[3] = leaky_(ev.w + edv[3]);
      } else {
        vv[0] = leaky_(es[s] + edv[0]);
      }
    } else {
#pragma unroll
      for (int h = 0; h < H; ++h) vv[h] = -1e30f;
    }
    float mv[H];
#pragma unroll
    for (int h = 0; h < H; ++h) mv[h] = vv[h];
#pragma unroll
    for (int off = 32; off; off >>= 1)
#pragma unroll
      for (int h = 0; h < H; ++h) mv[h] = fmaxf(mv[h], __shfl_xor(mv[h], off));
    float e[H], den[H];
#pragma unroll
    for (int h = 0; h < H; ++h) {
      e[h] = act ? __expf(vv[h] - mv[h]) : 0.f;
      den[h] = e[h];
    }
#pragma unroll
    for (int off = 32; off; off >>= 1)
#pragma unroll
      for (int h = 0; h < H; ++h) den[h] += __shfl_xor(den[h], off);
    s_off[wid][lane] = act ? ((unsigned)s << 8) : 0u;
#pragma unroll
    for (int h = 0; h < H; ++h) s_af[wid][lane][h] = e[h] * (1.f / den[h]);
    const int steps = (deg + 3) >> 2;
#pragma unroll 4
    for (int e2 = 0; e2 < steps; ++e2) {
      const int ei = e2 * 4 + eg;
      unsigned off = s_off[wid][ei];
      float af[H];
      if constexpr (H == 4) {
        float4 a4 = *(const float4*)&s_af[wid][ei][0];
        af[0] = a4.x; af[1] = a4.y; af[2] = a4.z; af[3] = a4.w;
      } else {
        af[0] = s_af[wid][ei][0];
      }
      uint4 v = *(const uint4*)(hbase + off);
      float vf[8] = {u2f_lo(v.x), u2f_hi(v.x), u2f_lo(v.y), u2f_hi(v.y),
                     u2f_lo(v.z), u2f_hi(v.z), u2f_lo(v.w), u2f_hi(v.w)};
#pragma unroll
      for (int h = 0; h < H; ++h)
#pragma unroll
        for (int j = 0; j < 8; ++j) acc[h][j] += af[h] * vf[j];
    }
  } else {
    // ---- slow path (deg > 64): online softmax + chunked staging ----
    float m[H], den[H], vreg[H];
    int sreg = 0;
#pragma unroll
    for (int h = 0; h < H; ++h) {
      m[h] = -1e30f;
      den[h] = 0.f;
      vreg[h] = -1e30f;
    }
    for (int i = lane; i < deg; i += 64) {
      int s = srcs[b0 + i];
      float vv[H];
      if constexpr (H == 4) {
        float4 ev = *(const float4*)&es[(size_t)s * 4];
        vv[0] = ev.x + edv[0];
        vv[1] = ev.y + edv[1];
        vv[2] = ev.z + edv[2];
        vv[3] = ev.w + edv[3];
      } else {
        vv[0] = es[s] + edv[0];
      }
#pragma unroll
      for (int h = 0; h < H; ++h) {
        float v = leaky_(vv[h]);
        vv[h] = v;
        float nm = fmaxf(m[h], v);
        den[h] = den[h] * __expf(m[h] - nm) + __expf(v - nm);
        m[h] = nm;
      }
      if (i == lane) {
        sreg = s;
#pragma unroll
        for (int h = 0; h < H; ++h) vreg[h] = vv[h];
      }
    }
#pragma unroll
    for (int off = 32; off; off >>= 1) {
#pragma unroll
      for (int h = 0; h < H; ++h) {
        float om = __shfl_xor(m[h], off);
        float od = __shfl_xor(den[h], off);
        float nm = fmaxf(m[h], om);
        den[h] = den[h] * __expf(m[h] - nm) + od * __expf(om - nm);
        m[h] = nm;
      }
    }
    float rden[H];
#pragma unroll
    for (int h = 0; h < H; ++h) rden[h] = 1.f / den[h];
    for (int c0 = 0; c0 < deg; c0 += 64) {
      const int ce = min(64, deg - c0);
      if (c0 == 0) {
        bool ok = lane < deg;
        s_off[wid][lane] = ok ? ((unsigned)sreg << 8) : 0u;
#pragma unroll
        for (int h = 0; h < H; ++h)
          s_af[wid][lane][h] = ok ? (__expf(vreg[h] - m[h]) * rden[h]) : 0.f;
      } else {
        int i = c0 + lane;
        bool ok = i < deg;
        int s = ok ? srcs[b0 + i] : 0;
        s_off[wid][lane] = ok ? ((unsigned)s << 8) : 0u;
        float af[H];
#pragma unroll
        for (int h = 0; h < H; ++h) af[h] = 0.f;
        if (ok) {
          float vv[H];
          if constexpr (H == 4) {
            float4 ev = *(const float4*)&es[(size_t)s * 4];
            vv[0] = ev.x + edv[0];
            vv[1] = ev.y + edv[1];
            vv[2] = ev.z + edv[2];
            vv[3] = ev.w + edv[3];
          } else {
            vv[0] = es[s] + edv[0];
          }
#pragma unroll
          for (int h = 0; h < H; ++h)
            af[h] = __expf(leaky_(vv[h]) - m[h]) * rden[h];
        }
#pragma unroll
        for (int h = 0; h < H; ++h) s_af[wid][lane][h] = af[h];
      }
      const int steps = (ce + 3) >> 2;
#pragma unroll 4
      for (int e2 = 0; e2 < steps; ++e2) {
        const int ei = e2 * 4 + eg;
        unsigned off = s_off[wid][ei];
        float af[H];
        if constexpr (H == 4) {
          float4 a4 = *(const float4*)&s_af[wid][ei][0];
          af[0] = a4.x; af[1] = a4.y; af[2] = a4.z; af[3] = a4.w;
        } else {
          af[0] = s_af[wid][ei][0];
        }
        uint4 v = *(const uint4*)(hbase + off);
        float vf[8] = {u2f_lo(v.x), u2f_hi(v.x), u2f_lo(v.y), u2f_hi(v.y),
                       u2f_lo(v.z), u2f_hi(v.z), u2f_lo(v.w), u2f_hi(v.w)};
#pragma unroll
        for (int h = 0; h < H; ++h)
#pragma unroll
          for (int j = 0; j < 8; ++j) acc[h][j] += af[h] * vf[j];
      }
    }
  }
  // fold 4 edge-groups
#pragma unroll
  for (int h = 0; h < H; ++h)
#pragma unroll
    for (int j = 0; j < 8; ++j) {
      acc[h][j] += __shfl_xor(acc[h][j], 16);
      acc[h][j] += __shfl_xor(acc[h][j], 32);
    }
  if (lane < 16) {
#pragma unroll
    for (int h = 0; h < H; ++h) {
      uint4 pk;
      pk.x = (unsigned)f2b(acc[h][0]) | ((unsigned)f2b(acc[h][1]) << 16);
      pk.y = (unsigned)f2b(acc[h][2]) | ((unsigned)f2b(acc[h][3]) << 16);
      pk.z = (unsigned)f2b(acc[h][4]) | ((unsigned)f2b(acc[h][5]) << 16);
      pk.w = (unsigned)f2b(acc[h][6]) | ((unsigned)f2b(acc[h][7]) << 16);
      *(uint4*)&trow[h * 128 + q * 8] = pk;
    }
  }
}

// ---------- layer-1 post GEMM: agg = tb @ Bp; epilogue elu + f32/bf16 out + next-layer proj ----------
__global__ void __launch_bounds__(256) k_post1(const unsigned short* __restrict__ tb,
                                               const unsigned short* __restrict__ Bp,
                                               float* __restrict__ houtf,
                                               unsigned short* __restrict__ houtb,
                                               const float* __restrict__ Pf,
                                               float* __restrict__ es, float* __restrict__ ed) {
  __shared__ float s_pr[16][8][4];
  const int n0 = blockIdx.x * 16;
  const int w = threadIdx.x >> 6;
  const int lane = threadIdx.x & 63;
  const int r = lane & 15, g = lane >> 4;
  f32x4 acc[2];
  acc[0] = (f32x4)0.f;
  acc[1] = (f32x4)0.f;
  const int koff = g << 3;
#pragma unroll
  for (int kb = 0; kb < 16; ++kb) {
    bf16x8 a = *(const bf16x8*)&tb[(size_t)(n0 + r) * 512 + kb * 32 + koff];
#pragma unroll
    for (int t = 0; t < 2; ++t) {
      bf16x8 b = *(const bf16x8*)&Bp[((size_t)(kb * 8 + w * 2 + t) * 64 + lane) * 8];
      acc[t] = __builtin_amdgcn_mfma_f32_16x16x32_bf16(a, b, acc[t], 0, 0, 0);
    }
  }
  float ps[4][8];
#pragma unroll
  for (int i = 0; i < 4; ++i)
#pragma unroll
    for (int c = 0; c < 8; ++c) ps[i][c] = 0.f;
#pragma unroll
  for (int t = 0; t < 2; ++t) {
    const int col = (w * 2 + t) * 16 + r;
    float4 pj0 = *(const float4*)&Pf[col * 8];
    float4 pj1 = *(const float4*)&Pf[col * 8 + 4];
#pragma unroll
    for (int i = 0; i < 4; ++i) {
      const int row = n0 + g * 4 + i;
      float o = acc[t][i];
      o = o > 0.f ? o : expm1f(o);
      houtf[(size_t)row * 128 + col] = o;
      houtb[(size_t)row * 128 + col] = f2b(o);
      ps[i][0] += o * pj0.x; ps[i][1] += o * pj0.y;
      ps[i][2] += o * pj0.z; ps[i][3] += o * pj0.w;
      ps[i][4] += o * pj1.x; ps[i][5] += o * pj1.y;
      ps[i][6] += o * pj1.z; ps[i][7] += o * pj1.w;
    }
  }
#pragma unroll
  for (int off = 1; off < 16; off <<= 1)
#pragma unroll
    for (int i = 0; i < 4; ++i)
#pragma unroll
      for (int c = 0; c < 8; ++c) ps[i][c] += __shfl_xor(ps[i][c], off);
  if (r == 0) {
#pragma unroll
    for (int i = 0; i < 4; ++i)
#pragma unroll
      for (int c = 0; c < 8; ++c) s_pr[g * 4 + i][c][w] = ps[i][c];
  }
  __syncthreads();
  if (threadIdx.x < 128) {
    int row = threadIdx.x >> 3;
    int c = threadIdx.x & 7;
    float val = s_pr[row][c][0] + s_pr[row][c][1] + s_pr[row][c][2] + s_pr[row][c][3];
    int gr = n0 + row;
    if (c < 4) es[(size_t)gr * 4 + c] = val;
    else ed[(size_t)gr * 4 + (c - 4)] = val;
  }
}

// ---------- fused post+GRU: x = elu(tb@Bp) staged in LDS; gi=x@Wih^T; gh=h@Whh^T; gates ----------
// MODE=0: writes houtf/houtb + next-layer es/ed proj (Pf, Hn). MODE=1: fused sigmoid(h@W5+b5) head.
template <int KD, int MODE>
__global__ void __launch_bounds__(256) k_postgru(const unsigned short* __restrict__ tb,
                                                 const unsigned short* __restrict__ Bp,
                                                 const unsigned short* __restrict__ hb,
                                                 const float* __restrict__ hf,
                                                 const unsigned short* __restrict__ Bih,
                                                 const unsigned short* __restrict__ Bhh,
                                                 const float* __restrict__ bih,
                                                 const float* __restrict__ bhh,
                                                 float* __restrict__ houtf,
                                                 unsigned short* __restrict__ houtb,
                                                 const float* __restrict__ Pf,
                                                 float* __restrict__ es, float* __restrict__ ed, int Hn,
                                                 const float* __restrict__ W5,
                                                 const float* __restrict__ b5,
                                                 float* __restrict__ out) {
  __shared__ unsigned short xs[16][136];  // padded: rows r and r+8 alias -> 2-way max (free)
  __shared__ float s_pr[16][8][4];
  const int n0 = blockIdx.x * 16;
  const int w = threadIdx.x >> 6;
  const int lane = threadIdx.x & 63;
  const int r = lane & 15, g = lane >> 4;
  const int koff = g << 3;
  // ---- phase 1: agg = tb @ Bp; elu -> xs (LDS) ----
  {
    f32x4 acc[2];
    acc[0] = (f32x4)0.f;
    acc[1] = (f32x4)0.f;
#pragma unroll
    for (int kb = 0; kb < KD / 32; ++kb) {
      bf16x8 a = *(const bf16x8*)&tb[(size_t)(n0 + r) * KD + kb * 32 + koff];
#pragma unroll
      for (int t = 0; t < 2; ++t) {
        bf16x8 b = *(const bf16x8*)&Bp[((size_t)(kb * 8 + w * 2 + t) * 64 + lane) * 8];
        acc[t] = __builtin_amdgcn_mfma_f32_16x16x32_bf16(a, b, acc[t], 0, 0, 0);
      }
    }
#pragma unroll
    for (int t = 0; t < 2; ++t) {
      const int col = (w * 2 + t) * 16 + r;
#pragma unroll
      for (int i = 0; i < 4; ++i) {
        float o = acc[t][i];
        o = o > 0.f ? o : expm1f(o);
        xs[g * 4 + i][col] = f2b(o);
      }
    }
  }
  __syncthreads();
  // ---- phase 2: GRU ----
  const int qbase = w * 2;
  f32x4 ai[3][2], ah[3][2];
#pragma unroll
  for (int p = 0; p < 3; ++p)
#pragma unroll
    for (int t = 0; t < 2; ++t) {
      ai[p][t] = (f32x4)0.f;
      ah[p][t] = (f32x4)0.f;
    }
#pragma unroll
  for (int kb = 0; kb < 4; ++kb) {
    bf16x8 ax = *(const bf16x8*)&xs[r][kb * 32 + koff];
    bf16x8 ahr = *(const bf16x8*)&hb[(size_t)(n0 + r) * 128 + kb * 32 + koff];
#pragma unroll
    for (int p = 0; p < 3; ++p) {
#pragma unroll
      for (int t = 0; t < 2; ++t) {
        const int ct = p * 8 + qbase + t;
        bf16x8 bi = *(const bf16x8*)&Bih[((size_t)(kb * 24 + ct) * 64 + lane) * 8];
        bf16x8 bh = *(const bf16x8*)&Bhh[((size_t)(kb * 24 + ct) * 64 + lane) * 8];
        ai[p][t] = __builtin_amdgcn_mfma_f32_16x16x32_bf16(ax, bi, ai[p][t], 0, 0, 0);
        ah[p][t] = __builtin_amdgcn_mfma_f32_16x16x32_bf16(ahr, bh, ah[p][t], 0, 0, 0);
      }
    }
  }
  if constexpr (MODE == 0) {
    float ps[4][8];
#pragma unroll
    for (int i = 0; i < 4; ++i)
#pragma unroll
      for (int c = 0; c < 8; ++c) ps[i][c] = 0.f;
#pragma unroll
    for (int t = 0; t < 2; ++t) {
      const int j = (qbase + t) * 16 + r;
      const float bir = bih[j], biz = bih[128 + j], bin = bih[256 + j];
      const float bhr = bhh[j], bhz = bhh[128 + j], bhn = bhh[256 + j];
      float4 pj0 = *(const float4*)&Pf[j * 8];
      float4 pj1 = *(const float4*)&Pf[j * 8 + 4];
#pragma unroll
      for (int i = 0; i < 4; ++i) {
        const int row = n0 + g * 4 + i;
        float rr = sigmoidf_(ai[0][t][i] + bir + ah[0][t][i] + bhr);
        float z = sigmoidf_(ai[1][t][i] + biz + ah[1][t][i] + bhz);
        float nn = tanhf(ai[2][t][i] + bin + rr * (ah[2][t][i] + bhn));
        float hp = hf[(size_t)row * 128 + j];
        float o = (1.f - z) * nn + z * hp;
        houtf[(size_t)row * 128 + j] = o;
        houtb[(size_t)row * 128 + j] = f2b(o);
        ps[i][0] += o * pj0.x; ps[i][1] += o * pj0.y;
        ps[i][2] += o * pj0.z; ps[i][3] += o * pj0.w;
        ps[i][4] += o * pj1.x; ps[i][5] += o * pj1.y;
        ps[i][6] += o * pj1.z; ps[i][7] += o * pj1.w;
      }
    }
#pragma unroll
    for (int off = 1; off < 16; off <<= 1)
#pragma unroll
      for (int i = 0; i < 4; ++i)
#pragma unroll
        for (int c = 0; c < 8; ++c) ps[i][c] += __shfl_xor(ps[i][c], off);
    if (r == 0) {
#pragma unroll
      for (int i = 0; i < 4; ++i)
#pragma unroll
        for (int c = 0; c < 8; ++c) s_pr[g * 4 + i][c][w] = ps[i][c];
    }
    __syncthreads();
    if (threadIdx.x < 128) {
      int row = threadIdx.x >> 3;
      int c = threadIdx.x & 7;
      float val = s_pr[row][c][0] + s_pr[row][c][1] + s_pr[row][c][2] + s_pr[row][c][3];
      int gr = n0 + row;
      if (c < Hn) es[(size_t)gr * Hn + c] = val;
      else if (c >= 4 && c < 4 + Hn) ed[(size_t)gr * Hn + (c - 4)] = val;
    }
  } else {
    float pfin[4] = {0.f, 0.f, 0.f, 0.f};
#pragma unroll
    for (int t = 0; t < 2; ++t) {
      const int j = (qbase + t) * 16 + r;
      const float bir = bih[j], biz = bih[128 + j], bin = bih[256 + j];
      const float bhr = bhh[j], bhz = bhh[128 + j], bhn = bhh[256 + j];
      const float w5 = W5[j];
#pragma unroll
      for (int i = 0; i < 4; ++i) {
        const int row = n0 + g * 4 + i;
        float rr = sigmoidf_(ai[0][t][i] + bir + ah[0][t][i] + bhr);
        float z = sigmoidf_(ai[1][t][i] + biz + ah[1][t][i] + bhz);
        float nn = tanhf(ai[2][t][i] + bin + rr * (ah[2][t][i] + bhn));
        float hp = hf[(size_t)row * 128 + j];
        float o = (1.f - z) * nn + z * hp;
        pfin[i] += o * w5;
      }
    }
#pragma unroll
    for (int off = 1; off < 16; off <<= 1)
#pragma unroll
      for (int i = 0; i < 4; ++i) pfin[i] += __shfl_xor(pfin[i], off);
    if (r == 0) {
#pragma unroll
      for (int i = 0; i < 4; ++i) s_pr[g * 4 + i][0][w] = pfin[i];
    }
    __syncthreads();
    if (threadIdx.x < 16) {
      float s = s_pr[threadIdx.x][0][0] + s_pr[threadIdx.x][0][1] +
                s_pr[threadIdx.x][0][2] + s_pr[threadIdx.x][0][3] + b5[0];
      out[n0 + threadIdx.x] = sigmoidf_(s);
    }
  }
}

extern "C" void kernel_launch(void* const* d_in, const int* in_sizes, int n_in,
                              void* d_out, int out_size, void* d_ws, size_t ws_size,
                              hipStream_t stream) {
  const float* h0 = (const float*)d_in[0];
  const int* ei = (const int*)d_in[1];
  const float* W1 = (const float*)d_in[2];
  const float* as1 = (const float*)d_in[3];
  const float* ad1 = (const float*)d_in[4];
  const float* W2 = (const float*)d_in[5];
  const float* as2 = (const float*)d_in[6];
  const float* ad2 = (const float*)d_in[7];
  const float* W3 = (const float*)d_in[8];
  const float* as3 = (const float*)d_in[9];
  const float* ad3 = (const float*)d_in[10];
  const float* W4 = (const float*)d_in[11];
  const float* as4 = (const float*)d_in[12];
  const float* ad4 = (const float*)d_in[13];
  const float* Wih = (const float*)d_in[14];
  const float* Whh = (const float*)d_in[15];
  const float* bih = (const float*)d_in[16];
  const float* bhh = (const float*)d_in[17];
  const float* W5 = (const float*)d_in[18];
  const float* b5 = (const float*)d_in[19];

  const int N = in_sizes[0] / D;  // 20000
  const int E = in_sizes[1] / 2;  // 320000
  const int* src = ei;
  const int* dst = ei + E;

  // ---- workspace layout ----
  float* ws = (float*)d_ws;
  unsigned short* tb = (unsigned short*)ws;           // N*512 us
  float* hA = ws + (size_t)N * 256;                   // N*128 f32
  float* hB = hA + (size_t)N * 128;                   // N*128 f32
  float* es = hB + (size_t)N * 128;                   // N*4
  float* ed = es + (size_t)N * 4;                     // N*4
  unsigned short* h0b = (unsigned short*)(ed + (size_t)N * 4);   // N*128 us
  unsigned short* hAb = h0b + (size_t)N * 128;        // N*128 us
  unsigned short* hBb = hAb + (size_t)N * 128;        // N*128 us
  unsigned short* B1 = hBb + (size_t)N * 128;         // 65536 us
  unsigned short* B2 = B1 + 65536;                    // 65536 us
  unsigned short* B3 = B2 + 65536;                    // 65536 us
  unsigned short* B4 = B3 + 65536;                    // 16384 us
  unsigned short* Bih = B4 + 16384;                   // 49152 us
  unsigned short* Bhh = Bih + 49152;                  // 49152 us
  unsigned short* Pp1 = Bhh + 49152;                  // 2048 us
  float* Pf2 = (float*)(Pp1 + 2048);                  // 1024 f
  float* Pf3 = Pf2 + 1024;                            // 1024 f
  float* Pf4 = Pf3 + 1024;                            // 1024 f
  int* deg = (int*)(Pf4 + 1024);                      // N
  int* rowptr = deg + N;                              // N+1
  int* fill = rowptr + N + 1;                         // N
  int* srcs = fill + N;                               // E

  // ---- prep: 1 memset + 3 kernels ----
  hipMemsetAsync(deg, 0, (size_t)N * 4, stream);
  {
    const int total = N * 128 + 311296 + 2048 + 3072 + E;
    k_prep<<<(total + 255) / 256, 256, 0, stream>>>(
        h0, h0b, W1, W2, W3, W4, Wih, Whh, B1, B2, B3, B4, Bih, Bhh,
        as1, ad1, as2, ad2, as3, ad3, as4, ad4, Pp1, Pf2, Pf3, Pf4, dst, deg, N, E);
  }
  k_scan<<<1, 1024, 0, stream>>>(deg, rowptr, fill, N);
  k_scatter<<<(E + 255) / 256, 256, 0, stream>>>(src, dst, fill, srcs, E);

  const int gES = (N + 63) / 64;  // 313
  const int gE = (N + 3) / 4;     // 5000
  const int gP = N / 16;          // 1250

  // ---- layer 1: H=4, no GRU; post emits h1 + es/ed(L2) ----
  k_esed<<<gES, 256, 0, stream>>>(h0b, Pp1, es, ed, N);
  k_edge_gather<4><<<gE, 256, 0, stream>>>(rowptr, srcs, es, ed, h0b, tb, N);
  k_post1<<<gP, 256, 0, stream>>>(tb, B1, hA, hAb, Pf2, es, ed);
  // ---- layer 2: H=4, GRU; fused post+gru emits h2 + es/ed(L3) ----
  k_edge_gather<4><<<gE, 256, 0, stream>>>(rowptr, srcs, es, ed, hAb, tb, N);
  k_postgru<512, 0><<<gP, 256, 0, stream>>>(tb, B2, hAb, hA, Bih, Bhh, bih, bhh, hB, hBb,
                                            Pf3, es, ed, 4, nullptr, nullptr, nullptr);
  // ---- layer 3: H=4, GRU; emits h3 + es/ed(L4, H=1) ----
  k_edge_gather<4><<<gE, 256, 0, stream>>>(rowptr, srcs, es, ed, hBb, tb, N);
  k_postgru<512, 0><<<gP, 256, 0, stream>>>(tb, B3, hBb, hB, Bih, Bhh, bih, bhh, hA, hAb,
                                            Pf4, es, ed, 1, nullptr, nullptr, nullptr);
  // ---- layer 4: H=1, GRU + fused output head ----
  k_edge_gather<1><<<gE, 256, 0, stream>>>(rowptr, srcs, es, ed, hAb, tb, N);
  k_postgru<128, 1><<<gP, 256, 0, stream>>>(tb, B4, hAb, hA, Bih, Bhh, bih, bhh,
                                            nullptr, nullptr, nullptr, nullptr, nullptr, 0,
                                            W5, b5, (float*)d_out);
}

// Round 14
// 267.011 us; speedup vs baseline: 1.6259x; 1.1469x over previous
//
#include <hip/hip_runtime.h>
#include <math.h>

#define D 128

typedef __attribute__((ext_vector_type(8))) short bf16x8;
typedef __attribute__((ext_vector_type(4))) float f32x4;
typedef __attribute__((ext_vector_type(2))) float f32x2;

__device__ __forceinline__ float sigmoidf_(float x) { return 1.f / (1.f + __expf(-x)); }
__device__ __forceinline__ float bf2f(unsigned short u) { return __uint_as_float(((unsigned)u) << 16); }
__device__ __forceinline__ float u2f_lo(unsigned u) { return __uint_as_float(u << 16); }
__device__ __forceinline__ float u2f_hi(unsigned u) { return __uint_as_float(u & 0xffff0000u); }
__device__ __forceinline__ unsigned short f2b(float f) {
  unsigned u = __float_as_uint(f);
  return (unsigned short)((u + 0x7fffu + ((u >> 16) & 1u)) >> 16);  // RNE
}
__device__ __forceinline__ float leaky_(float v) { return v > 0.f ? v : 0.2f * v; }

// ---------- packing helpers ----------
__device__ __forceinline__ void pack_post_elem(const float* __restrict__ W,
                                               unsigned short* __restrict__ Bp, int i, float scale) {
  int j = i & 7;
  int lane = (i >> 3) & 63;
  int rest = i >> 9;
  int db = rest & 7;
  int kb = rest >> 3;
  int k = kb * 32 + ((lane >> 4) << 3) + j;
  int d = db * 16 + (lane & 15);
  int h = k >> 7, kk = k & 127;
  Bp[i] = f2b(W[((size_t)h * 128 + kk) * 128 + d] * scale);
}
__device__ __forceinline__ void pack_gru_elem(const float* __restrict__ S,
                                              unsigned short* __restrict__ Bp, int i) {
  int j = i & 7;
  int lane = (i >> 3) & 63;
  int rest = i >> 9;
  int db = rest % 24;
  int kb = rest / 24;
  int k = kb * 32 + ((lane >> 4) << 3) + j;
  int col = db * 16 + (lane & 15);
  Bp[i] = f2b(S[(size_t)col * 128 + k]);
}

// ---------- mega prep: f2b(h0) + pack all weights + projections + degree histogram ----------
__global__ void __launch_bounds__(256) k_prep(const float* __restrict__ h0, unsigned short* __restrict__ h0b,
                                              const float* __restrict__ W1, const float* __restrict__ W2,
                                              const float* __restrict__ W3, const float* __restrict__ W4,
                                              const float* __restrict__ Wih, const float* __restrict__ Whh,
                                              unsigned short* __restrict__ B1, unsigned short* __restrict__ B2,
                                              unsigned short* __restrict__ B3, unsigned short* __restrict__ B4,
                                              unsigned short* __restrict__ Bih, unsigned short* __restrict__ Bhh,
                                              const float* __restrict__ as1, const float* __restrict__ ad1,
                                              const float* __restrict__ as2, const float* __restrict__ ad2,
                                              const float* __restrict__ as3, const float* __restrict__ ad3,
                                              const float* __restrict__ as4, const float* __restrict__ ad4,
                                              unsigned short* __restrict__ Pp1, float* __restrict__ Pf2,
                                              float* __restrict__ Pf3, float* __restrict__ Pf4,
                                              const int* __restrict__ dst, int* __restrict__ deg,
                                              int N, int E) {
  int i = blockIdx.x * 256 + threadIdx.x;
  const int NH = N * 128;
  if (i < NH) {
    h0b[i] = f2b(h0[i]);
    return;
  }
  i -= NH;
  if (i < 311296) {
    if (i < 65536) pack_post_elem(W1, B1, i, 0.25f);
    else if (i < 131072) pack_post_elem(W2, B2, i - 65536, 0.25f);
    else if (i < 196608) pack_post_elem(W3, B3, i - 131072, 0.25f);
    else if (i < 212992) pack_post_elem(W4, B4, i - 196608, 1.0f);
    else if (i < 262144) pack_gru_elem(Wih, Bih, i - 212992);
    else pack_gru_elem(Whh, Bhh, i - 262144);
    return;
  }
  i -= 311296;
  if (i < 2048) {
    int j = i & 7;
    int lane = (i >> 3) & 63;
    int kb = i >> 9;
    int k = kb * 32 + ((lane >> 4) << 3) + j;
    int col = lane & 15;
    float val = 0.f;
    if (col < 8) {
      int c = col >= 4;
      int h = c ? (col - 4) : col;
      const float* wrow = W1 + ((size_t)h * 128 + k) * 128;
      const float* av = (c ? ad1 : as1) + (size_t)h * 128;
      for (int d2 = 0; d2 < 128; ++d2) val += wrow[d2] * av[d2];
    }
    Pp1[i] = f2b(val);
    return;
  }
  i -= 2048;
  if (i < 3072) {
    int layer = i >> 10;
    int qq = i & 1023;
    int k = qq >> 3;
    int slot = qq & 7;
    const float *W, *as_, *ad_;
    float* out;
    int H;
    if (layer == 0) { W = W2; as_ = as2; ad_ = ad2; out = Pf2; H = 4; }
    else if (layer == 1) { W = W3; as_ = as3; ad_ = ad3; out = Pf3; H = 4; }
    else { W = W4; as_ = as4; ad_ = ad4; out = Pf4; H = 1; }
    int h = slot & 3;
    bool isEd = slot >= 4;
    float val = 0.f;
    if (h < H) {
      const float* wrow = W + ((size_t)h * 128 + k) * 128;
      const float* av = (isEd ? ad_ : as_) + (size_t)h * 128;
      for (int d2 = 0; d2 < 128; ++d2) val += wrow[d2] * av[d2];
    }
    out[qq] = val;
    return;
  }
  i -= 3072;
  if (i < E) atomicAdd(&deg[dst[i]], 1);
}

// ---------- CSR scan ----------
__global__ void __launch_bounds__(1024) k_scan(const int* __restrict__ deg, int* __restrict__ rowptr,
                                               int* __restrict__ fill, int N) {
  __shared__ int part[1024];
  const int tid = threadIdx.x;
  const int chunk = (N + 1023) / 1024;
  const int b = tid * chunk;
  const int e = min(N, b + chunk);
  int s = 0;
  for (int i = b; i < e; ++i) s += deg[i];
  part[tid] = s;
  __syncthreads();
  for (int off = 1; off < 1024; off <<= 1) {
    int v = (tid >= off) ? part[tid - off] : 0;
    __syncthreads();
    part[tid] += v;
    __syncthreads();
  }
  int run = (tid == 0) ? 0 : part[tid - 1];
  for (int i = b; i < e; ++i) {
    rowptr[i] = run;
    fill[i] = run;
    run += deg[i];
  }
  if (b < N && e == N) rowptr[N] = run;
}

// ---------- merged: CSR scatter (blocks [0,nS)) + layer-1 es/ed MFMA (blocks [nS,...)) ----------
__global__ void __launch_bounds__(256) k_scatter_esed(const int* __restrict__ src, const int* __restrict__ dst,
                                                      int* __restrict__ fill, int* __restrict__ srcs, int E,
                                                      const unsigned short* __restrict__ hb,
                                                      const unsigned short* __restrict__ Pp,
                                                      float* __restrict__ es, float* __restrict__ ed,
                                                      int N, int nS) {
  if ((int)blockIdx.x < nS) {
    int e = blockIdx.x * 256 + threadIdx.x;
    if (e < E) {
      int pos = atomicAdd(&fill[dst[e]], 1);
      srcs[pos] = src[e];
    }
    return;
  }
  const int blk = blockIdx.x - nS;
  const int w = threadIdx.x >> 6;
  const int lane = threadIdx.x & 63;
  const int r = lane & 15, g = lane >> 4;
  const int n0 = blk * 64 + w * 16;
  f32x4 acc = (f32x4)0.f;
  const int koff = g << 3;
#pragma unroll
  for (int kb = 0; kb < 4; ++kb) {
    int row = min(n0 + r, N - 1);
    bf16x8 a = *(const bf16x8*)&hb[(size_t)row * 128 + kb * 32 + koff];
    bf16x8 b = *(const bf16x8*)&Pp[((size_t)(kb * 64) + lane) * 8];
    acc = __builtin_amdgcn_mfma_f32_16x16x32_bf16(a, b, acc, 0, 0, 0);
  }
  const int rbase = n0 + g * 4;
#pragma unroll
  for (int i = 0; i < 4; ++i) {
    int row = rbase + i;
    if (row < N) {
      if (r < 4) es[(size_t)row * 4 + r] = acc[i];
      else if (r < 8) ed[(size_t)row * 4 + (r - 4)] = acc[i];
    }
  }
}

// ---------- edge gather v8: 32 lanes/node (2 nodes/wave), packed f32x2 accumulation ----------
// fast path deg<=32; slow online path deg>32. lane l in [0,32): q=l&15 covers dims [8q,8q+8),
// eg=l>>4 selects edge parity. Head-fold: single shfl_xor(16).
template <int H>
__global__ void __launch_bounds__(256) k_edge_gather(const int* __restrict__ rowptr,
                                                     const int* __restrict__ srcs,
                                                     const float* __restrict__ es,
                                                     const float* __restrict__ ed,
                                                     const unsigned short* __restrict__ hb,
                                                     unsigned short* __restrict__ tb, int N) {
  __shared__ __align__(16) unsigned s_off[8][32];
  __shared__ __align__(16) float s_af[8][32][H == 1 ? 1 : 4];
  const int slot = threadIdx.x >> 5;  // 0..7 node slot in block
  const int t = blockIdx.x * 8 + slot;
  if (t >= N) return;
  const int l = threadIdx.x & 31;
  const int q = l & 15;
  const int eg = l >> 4;  // 0..1
  const int b0 = rowptr[t];
  const int deg = rowptr[t + 1] - b0;
  unsigned short* trow = tb + (size_t)t * (H * 128);
  if (deg == 0) {
    if (l < 16) {
#pragma unroll
      for (int h = 0; h < H; ++h)
        *(uint4*)&trow[h * 128 + q * 8] = make_uint4(0u, 0u, 0u, 0u);
    }
    return;
  }
  float edv[H];
#pragma unroll
  for (int h = 0; h < H; ++h) edv[h] = ed[(size_t)t * H + h];

  f32x2 acc[H][4];
#pragma unroll
  for (int h = 0; h < H; ++h)
#pragma unroll
    for (int j = 0; j < 4; ++j) acc[h][j] = (f32x2)0.f;
  const char* hbase = (const char*)hb + q * 16;

  if (deg <= 32) {
    // ---- fast path: 1 edge/lane; 5-level reduce shared by 2 nodes/wave ----
    const bool act = l < deg;
    int s = 0;
    float vv[H];
    if (act) {
      s = srcs[b0 + l];
      if constexpr (H == 4) {
        float4 ev = *(const float4*)&es[(size_t)s * 4];
        vv[0] = leaky_(ev.x + edv[0]);
        vv[1] = leaky_(ev.y + edv[1]);
        vv[2] = leaky_(ev.z + edv[2]);
        vv[3] = leaky_(ev.w + edv[3]);
      } else {
        vv[0] = leaky_(es[s] + edv[0]);
      }
    } else {
#pragma unroll
      for (int h = 0; h < H; ++h) vv[h] = -1e30f;
    }
    float mv[H];
#pragma unroll
    for (int h = 0; h < H; ++h) mv[h] = vv[h];
#pragma unroll
    for (int off = 16; off; off >>= 1)
#pragma unroll
      for (int h = 0; h < H; ++h) mv[h] = fmaxf(mv[h], __shfl_xor(mv[h], off));
    float e[H], den[H];
#pragma unroll
    for (int h = 0; h < H; ++h) {
      e[h] = act ? __expf(vv[h] - mv[h]) : 0.f;
      den[h] = e[h];
    }
#pragma unroll
    for (int off = 16; off; off >>= 1)
#pragma unroll
      for (int h = 0; h < H; ++h) den[h] += __shfl_xor(den[h], off);
    s_off[slot][l] = act ? ((unsigned)s << 8) : 0u;
#pragma unroll
    for (int h = 0; h < H; ++h) s_af[slot][l][h] = e[h] * (1.f / den[h]);
    const int steps = (deg + 1) >> 1;
#pragma unroll 4
    for (int e2 = 0; e2 < steps; ++e2) {
      const int ei = e2 * 2 + eg;
      unsigned off = s_off[slot][ei];
      float af[H];
      if constexpr (H == 4) {
        float4 a4 = *(const float4*)&s_af[slot][ei][0];
        af[0] = a4.x; af[1] = a4.y; af[2] = a4.z; af[3] = a4.w;
      } else {
        af[0] = s_af[slot][ei][0];
      }
      uint4 v = *(const uint4*)(hbase + off);
      f32x2 vf0 = {u2f_lo(v.x), u2f_hi(v.x)};
      f32x2 vf1 = {u2f_lo(v.y), u2f_hi(v.y)};
      f32x2 vf2 = {u2f_lo(v.z), u2f_hi(v.z)};
      f32x2 vf3 = {u2f_lo(v.w), u2f_hi(v.w)};
#pragma unroll
      for (int h = 0; h < H; ++h) {
        f32x2 a2 = {af[h], af[h]};
        acc[h][0] += a2 * vf0;
        acc[h][1] += a2 * vf1;
        acc[h][2] += a2 * vf2;
        acc[h][3] += a2 * vf3;
      }
    }
  } else {
    // ---- slow path (deg > 32): online softmax + chunked staging ----
    float m[H], den[H], vreg[H];
    int sreg = 0;
#pragma unroll
    for (int h = 0; h < H; ++h) {
      m[h] = -1e30f;
      den[h] = 0.f;
      vreg[h] = -1e30f;
    }
    for (int i = l; i < deg; i += 32) {
      int s = srcs[b0 + i];
      float vv[H];
      if constexpr (H == 4) {
        float4 ev = *(const float4*)&es[(size_t)s * 4];
        vv[0] = ev.x + edv[0];
        vv[1] = ev.y + edv[1];
        vv[2] = ev.z + edv[2];
        vv[3] = ev.w + edv[3];
      } else {
        vv[0] = es[s] + edv[0];
      }
#pragma unroll
      for (int h = 0; h < H; ++h) {
        float v = leaky_(vv[h]);
        vv[h] = v;
        float nm = fmaxf(m[h], v);
        den[h] = den[h] * __expf(m[h] - nm) + __expf(v - nm);
        m[h] = nm;
      }
      if (i == l) {
        sreg = s;
#pragma unroll
        for (int h = 0; h < H; ++h) vreg[h] = vv[h];
      }
    }
#pragma unroll
    for (int off = 16; off; off >>= 1) {
#pragma unroll
      for (int h = 0; h < H; ++h) {
        float om = __shfl_xor(m[h], off);
        float od = __shfl_xor(den[h], off);
        float nm = fmaxf(m[h], om);
        den[h] = den[h] * __expf(m[h] - nm) + od * __expf(om - nm);
        m[h] = nm;
      }
    }
    float rden[H];
#pragma unroll
    for (int h = 0; h < H; ++h) rden[h] = 1.f / den[h];
    for (int c0 = 0; c0 < deg; c0 += 32) {
      const int ce = min(32, deg - c0);
      if (c0 == 0) {
        bool ok = l < deg;
        s_off[slot][l] = ok ? ((unsigned)sreg << 8) : 0u;
#pragma unroll
        for (int h = 0; h < H; ++h)
          s_af[slot][l][h] = ok ? (__expf(vreg[h] - m[h]) * rden[h]) : 0.f;
      } else {
        int i = c0 + l;
        bool ok = i < deg;
        int s = ok ? srcs[b0 + i] : 0;
        s_off[slot][l] = ok ? ((unsigned)s << 8) : 0u;
        float af[H];
#pragma unroll
        for (int h = 0; h < H; ++h) af[h] = 0.f;
        if (ok) {
          float vv[H];
          if constexpr (H == 4) {
            float4 ev = *(const float4*)&es[(size_t)s * 4];
            vv[0] = ev.x + edv[0];
            vv[1] = ev.y + edv[1];
            vv[2] = ev.z + edv[2];
            vv[3] = ev.w + edv[3];
          } else {
            vv[0] = es[s] + edv[0];
          }
#pragma unroll
          for (int h = 0; h < H; ++h)
            af[h] = __expf(leaky_(vv[h]) - m[h]) * rden[h];
        }
#pragma unroll
        for (int h = 0; h < H; ++h) s_af[slot][l][h] = af[h];
      }
      const int steps = (ce + 1) >> 1;
#pragma unroll 4
      for (int e2 = 0; e2 < steps; ++e2) {
        const int ei = e2 * 2 + eg;
        unsigned off = s_off[slot][ei];
        float af[H];
        if constexpr (H == 4) {
          float4 a4 = *(const float4*)&s_af[slot][ei][0];
          af[0] = a4.x; af[1] = a4.y; af[2] = a4.z; af[3] = a4.w;
        } else {
          af[0] = s_af[slot][ei][0];
        }
        uint4 v = *(const uint4*)(hbase + off);
        f32x2 vf0 = {u2f_lo(v.x), u2f_hi(v.x)};
        f32x2 vf1 = {u2f_lo(v.y), u2f_hi(v.y)};
        f32x2 vf2 = {u2f_lo(v.z), u2f_hi(v.z)};
        f32x2 vf3 = {u2f_lo(v.w), u2f_hi(v.w)};
#pragma unroll
        for (int h = 0; h < H; ++h) {
          f32x2 a2 = {af[h], af[h]};
          acc[h][0] += a2 * vf0;
          acc[h][1] += a2 * vf1;
          acc[h][2] += a2 * vf2;
          acc[h][3] += a2 * vf3;
        }
      }
    }
  }
  // fold the 2 edge-groups (single level, shared by both nodes of the wave)
#pragma unroll
  for (int h = 0; h < H; ++h)
#pragma unroll
    for (int j = 0; j < 4; ++j) {
      acc[h][j].x += __shfl_xor(acc[h][j].x, 16);
      acc[h][j].y += __shfl_xor(acc[h][j].y, 16);
    }
  if (l < 16) {
#pragma unroll
    for (int h = 0; h < H; ++h) {
      uint4 pk;
      pk.x = (unsigned)f2b(acc[h][0].x) | ((unsigned)f2b(acc[h][0].y) << 16);
      pk.y = (unsigned)f2b(acc[h][1].x) | ((unsigned)f2b(acc[h][1].y) << 16);
      pk.z = (unsigned)f2b(acc[h][2].x) | ((unsigned)f2b(acc[h][2].y) << 16);
      pk.w = (unsigned)f2b(acc[h][3].x) | ((unsigned)f2b(acc[h][3].y) << 16);
      *(uint4*)&trow[h * 128 + q * 8] = pk;
    }
  }
}

// ---------- layer-1 post GEMM: agg = tb @ Bp; epilogue elu + f32/bf16 out + next-layer proj ----------
__global__ void __launch_bounds__(256) k_post1(const unsigned short* __restrict__ tb,
                                               const unsigned short* __restrict__ Bp,
                                               float* __restrict__ houtf,
                                               unsigned short* __restrict__ houtb,
                                               const float* __restrict__ Pf,
                                               float* __restrict__ es, float* __restrict__ ed) {
  __shared__ float s_pr[16][8][4];
  const int n0 = blockIdx.x * 16;
  const int w = threadIdx.x >> 6;
  const int lane = threadIdx.x & 63;
  const int r = lane & 15, g = lane >> 4;
  f32x4 acc[2];
  acc[0] = (f32x4)0.f;
  acc[1] = (f32x4)0.f;
  const int koff = g << 3;
#pragma unroll
  for (int kb = 0; kb < 16; ++kb) {
    bf16x8 a = *(const bf16x8*)&tb[(size_t)(n0 + r) * 512 + kb * 32 + koff];
#pragma unroll
    for (int t = 0; t < 2; ++t) {
      bf16x8 b = *(const bf16x8*)&Bp[((size_t)(kb * 8 + w * 2 + t) * 64 + lane) * 8];
      acc[t] = __builtin_amdgcn_mfma_f32_16x16x32_bf16(a, b, acc[t], 0, 0, 0);
    }
  }
  float ps[4][8];
#pragma unroll
  for (int i = 0; i < 4; ++i)
#pragma unroll
    for (int c = 0; c < 8; ++c) ps[i][c] = 0.f;
#pragma unroll
  for (int t = 0; t < 2; ++t) {
    const int col = (w * 2 + t) * 16 + r;
    float4 pj0 = *(const float4*)&Pf[col * 8];
    float4 pj1 = *(const float4*)&Pf[col * 8 + 4];
#pragma unroll
    for (int i = 0; i < 4; ++i) {
      const int row = n0 + g * 4 + i;
      float o = acc[t][i];
      o = o > 0.f ? o : expm1f(o);
      houtf[(size_t)row * 128 + col] = o;
      houtb[(size_t)row * 128 + col] = f2b(o);
      ps[i][0] += o * pj0.x; ps[i][1] += o * pj0.y;
      ps[i][2] += o * pj0.z; ps[i][3] += o * pj0.w;
      ps[i][4] += o * pj1.x; ps[i][5] += o * pj1.y;
      ps[i][6] += o * pj1.z; ps[i][7] += o * pj1.w;
    }
  }
#pragma unroll
  for (int off = 1; off < 16; off <<= 1)
#pragma unroll
    for (int i = 0; i < 4; ++i)
#pragma unroll
      for (int c = 0; c < 8; ++c) ps[i][c] += __shfl_xor(ps[i][c], off);
  if (r == 0) {
#pragma unroll
    for (int i = 0; i < 4; ++i)
#pragma unroll
      for (int c = 0; c < 8; ++c) s_pr[g * 4 + i][c][w] = ps[i][c];
  }
  __syncthreads();
  if (threadIdx.x < 128) {
    int row = threadIdx.x >> 3;
    int c = threadIdx.x & 7;
    float val = s_pr[row][c][0] + s_pr[row][c][1] + s_pr[row][c][2] + s_pr[row][c][3];
    int gr = n0 + row;
    if (c < 4) es[(size_t)gr * 4 + c] = val;
    else ed[(size_t)gr * 4 + (c - 4)] = val;
  }
}

// ---------- fused post+GRU: x = elu(tb@Bp) staged in LDS; gi=x@Wih^T; gh=h@Whh^T; gates ----------
template <int KD, int MODE>
__global__ void __launch_bounds__(256) k_postgru(const unsigned short* __restrict__ tb,
                                                 const unsigned short* __restrict__ Bp,
                                                 const unsigned short* __restrict__ hb,
                                                 const float* __restrict__ hf,
                                                 const unsigned short* __restrict__ Bih,
                                                 const unsigned short* __restrict__ Bhh,
                                                 const float* __restrict__ bih,
                                                 const float* __restrict__ bhh,
                                                 float* __restrict__ houtf,
                                                 unsigned short* __restrict__ houtb,
                                                 const float* __restrict__ Pf,
                                                 float* __restrict__ es, float* __restrict__ ed, int Hn,
                                                 const float* __restrict__ W5,
                                                 const float* __restrict__ b5,
                                                 float* __restrict__ out) {
  __shared__ unsigned short xs[16][136];
  __shared__ float s_pr[16][8][4];
  const int n0 = blockIdx.x * 16;
  const int w = threadIdx.x >> 6;
  const int lane = threadIdx.x & 63;
  const int r = lane & 15, g = lane >> 4;
  const int koff = g << 3;
  {
    f32x4 acc[2];
    acc[0] = (f32x4)0.f;
    acc[1] = (f32x4)0.f;
#pragma unroll
    for (int kb = 0; kb < KD / 32; ++kb) {
      bf16x8 a = *(const bf16x8*)&tb[(size_t)(n0 + r) * KD + kb * 32 + koff];
#pragma unroll
      for (int t = 0; t < 2; ++t) {
        bf16x8 b = *(const bf16x8*)&Bp[((size_t)(kb * 8 + w * 2 + t) * 64 + lane) * 8];
        acc[t] = __builtin_amdgcn_mfma_f32_16x16x32_bf16(a, b, acc[t], 0, 0, 0);
      }
    }
#pragma unroll
    for (int t = 0; t < 2; ++t) {
      const int col = (w * 2 + t) * 16 + r;
#pragma unroll
      for (int i = 0; i < 4; ++i) {
        float o = acc[t][i];
        o = o > 0.f ? o : expm1f(o);
        xs[g * 4 + i][col] = f2b(o);
      }
    }
  }
  __syncthreads();
  const int qbase = w * 2;
  f32x4 ai[3][2], ah[3][2];
#pragma unroll
  for (int p = 0; p < 3; ++p)
#pragma unroll
    for (int t = 0; t < 2; ++t) {
      ai[p][t] = (f32x4)0.f;
      ah[p][t] = (f32x4)0.f;
    }
#pragma unroll
  for (int kb = 0; kb < 4; ++kb) {
    bf16x8 ax = *(const bf16x8*)&xs[r][kb * 32 + koff];
    bf16x8 ahr = *(const bf16x8*)&hb[(size_t)(n0 + r) * 128 + kb * 32 + koff];
#pragma unroll
    for (int p = 0; p < 3; ++p) {
#pragma unroll
      for (int t = 0; t < 2; ++t) {
        const int ct = p * 8 + qbase + t;
        bf16x8 bi = *(const bf16x8*)&Bih[((size_t)(kb * 24 + ct) * 64 + lane) * 8];
        bf16x8 bh = *(const bf16x8*)&Bhh[((size_t)(kb * 24 + ct) * 64 + lane) * 8];
        ai[p][t] = __builtin_amdgcn_mfma_f32_16x16x32_bf16(ax, bi, ai[p][t], 0, 0, 0);
        ah[p][t] = __builtin_amdgcn_mfma_f32_16x16x32_bf16(ahr, bh, ah[p][t], 0, 0, 0);
      }
    }
  }
  if constexpr (MODE == 0) {
    float ps[4][8];
#pragma unroll
    for (int i = 0; i < 4; ++i)
#pragma unroll
      for (int c = 0; c < 8; ++c) ps[i][c] = 0.f;
#pragma unroll
    for (int t = 0; t < 2; ++t) {
      const int j = (qbase + t) * 16 + r;
      const float bir = bih[j], biz = bih[128 + j], bin = bih[256 + j];
      const float bhr = bhh[j], bhz = bhh[128 + j], bhn = bhh[256 + j];
      float4 pj0 = *(const float4*)&Pf[j * 8];
      float4 pj1 = *(const float4*)&Pf[j * 8 + 4];
#pragma unroll
      for (int i = 0; i < 4; ++i) {
        const int row = n0 + g * 4 + i;
        float rr = sigmoidf_(ai[0][t][i] + bir + ah[0][t][i] + bhr);
        float z = sigmoidf_(ai[1][t][i] + biz + ah[1][t][i] + bhz);
        float nn = tanhf(ai[2][t][i] + bin + rr * (ah[2][t][i] + bhn));
        float hp = hf[(size_t)row * 128 + j];
        float o = (1.f - z) * nn + z * hp;
        houtf[(size_t)row * 128 + j] = o;
        houtb[(size_t)row * 128 + j] = f2b(o);
        ps[i][0] += o * pj0.x; ps[i][1] += o * pj0.y;
        ps[i][2] += o * pj0.z; ps[i][3] += o * pj0.w;
        ps[i][4] += o * pj1.x; ps[i][5] += o * pj1.y;
        ps[i][6] += o * pj1.z; ps[i][7] += o * pj1.w;
      }
    }
#pragma unroll
    for (int off = 1; off < 16; off <<= 1)
#pragma unroll
      for (int i = 0; i < 4; ++i)
#pragma unroll
        for (int c = 0; c < 8; ++c) ps[i][c] += __shfl_xor(ps[i][c], off);
    if (r == 0) {
#pragma unroll
      for (int i = 0; i < 4; ++i)
#pragma unroll
        for (int c = 0; c < 8; ++c) s_pr[g * 4 + i][c][w] = ps[i][c];
    }
    __syncthreads();
    if (threadIdx.x < 128) {
      int row = threadIdx.x >> 3;
      int c = threadIdx.x & 7;
      float val = s_pr[row][c][0] + s_pr[row][c][1] + s_pr[row][c][2] + s_pr[row][c][3];
      int gr = n0 + row;
      if (c < Hn) es[(size_t)gr * Hn + c] = val;
      else if (c >= 4 && c < 4 + Hn) ed[(size_t)gr * Hn + (c - 4)] = val;
    }
  } else {
    float pfin[4] = {0.f, 0.f, 0.f, 0.f};
#pragma unroll
    for (int t = 0; t < 2; ++t) {
      const int j = (qbase + t) * 16 + r;
      const float bir = bih[j], biz = bih[128 + j], bin = bih[256 + j];
      const float bhr = bhh[j], bhz = bhh[128 + j], bhn = bhh[256 + j];
      const float w5 = W5[j];
#pragma unroll
      for (int i = 0; i < 4; ++i) {
        const int row = n0 + g * 4 + i;
        float rr = sigmoidf_(ai[0][t][i] + bir + ah[0][t][i] + bhr);
        float z = sigmoidf_(ai[1][t][i] + biz + ah[1][t][i] + bhz);
        float nn = tanhf(ai[2][t][i] + bin + rr * (ah[2][t][i] + bhn));
        float hp = hf[(size_t)row * 128 + j];
        float o = (1.f - z) * nn + z * hp;
        pfin[i] += o * w5;
      }
    }
#pragma unroll
    for (int off = 1; off < 16; off <<= 1)
#pragma unroll
      for (int i = 0; i < 4; ++i) pfin[i] += __shfl_xor(pfin[i], off);
    if (r == 0) {
#pragma unroll
      for (int i = 0; i < 4; ++i) s_pr[g * 4 + i][0][w] = pfin[i];
    }
    __syncthreads();
    if (threadIdx.x < 16) {
      float s = s_pr[threadIdx.x][0][0] + s_pr[threadIdx.x][0][1] +
                s_pr[threadIdx.x][0][2] + s_pr[threadIdx.x][0][3] + b5[0];
      out[n0 + threadIdx.x] = sigmoidf_(s);
    }
  }
}

extern "C" void kernel_launch(void* const* d_in, const int* in_sizes, int n_in,
                              void* d_out, int out_size, void* d_ws, size_t ws_size,
                              hipStream_t stream) {
  const float* h0 = (const float*)d_in[0];
  const int* ei = (const int*)d_in[1];
  const float* W1 = (const float*)d_in[2];
  const float* as1 = (const float*)d_in[3];
  const float* ad1 = (const float*)d_in[4];
  const float* W2 = (const float*)d_in[5];
  const float* as2 = (const float*)d_in[6];
  const float* ad2 = (const float*)d_in[7];
  const float* W3 = (const float*)d_in[8];
  const float* as3 = (const float*)d_in[9];
  const float* ad3 = (const float*)d_in[10];
  const float* W4 = (const float*)d_in[11];
  const float* as4 = (const float*)d_in[12];
  const float* ad4 = (const float*)d_in[13];
  const float* Wih = (const float*)d_in[14];
  const float* Whh = (const float*)d_in[15];
  const float* bih = (const float*)d_in[16];
  const float* bhh = (const float*)d_in[17];
  const float* W5 = (const float*)d_in[18];
  const float* b5 = (const float*)d_in[19];

  const int N = in_sizes[0] / D;  // 20000
  const int E = in_sizes[1] / 2;  // 320000
  const int* src = ei;
  const int* dst = ei + E;

  // ---- workspace layout ----
  float* ws = (float*)d_ws;
  unsigned short* tb = (unsigned short*)ws;           // N*512 us
  float* hA = ws + (size_t)N * 256;                   // N*128 f32
  float* hB = hA + (size_t)N * 128;                   // N*128 f32
  float* es = hB + (size_t)N * 128;                   // N*4
  float* ed = es + (size_t)N * 4;                     // N*4
  unsigned short* h0b = (unsigned short*)(ed + (size_t)N * 4);   // N*128 us
  unsigned short* hAb = h0b + (size_t)N * 128;        // N*128 us
  unsigned short* hBb = hAb + (size_t)N * 128;        // N*128 us
  unsigned short* B1 = hBb + (size_t)N * 128;         // 65536 us
  unsigned short* B2 = B1 + 65536;                    // 65536 us
  unsigned short* B3 = B2 + 65536;                    // 65536 us
  unsigned short* B4 = B3 + 65536;                    // 16384 us
  unsigned short* Bih = B4 + 16384;                   // 49152 us
  unsigned short* Bhh = Bih + 49152;                  // 49152 us
  unsigned short* Pp1 = Bhh + 49152;                  // 2048 us
  float* Pf2 = (float*)(Pp1 + 2048);                  // 1024 f
  float* Pf3 = Pf2 + 1024;                            // 1024 f
  float* Pf4 = Pf3 + 1024;                            // 1024 f
  int* deg = (int*)(Pf4 + 1024);                      // N
  int* rowptr = deg + N;                              // N+1
  int* fill = rowptr + N + 1;                         // N
  int* srcs = fill + N;                               // E

  // ---- prep ----
  hipMemsetAsync(deg, 0, (size_t)N * 4, stream);
  {
    const int total = N * 128 + 311296 + 2048 + 3072 + E;
    k_prep<<<(total + 255) / 256, 256, 0, stream>>>(
        h0, h0b, W1, W2, W3, W4, Wih, Whh, B1, B2, B3, B4, Bih, Bhh,
        as1, ad1, as2, ad2, as3, ad3, as4, ad4, Pp1, Pf2, Pf3, Pf4, dst, deg, N, E);
  }
  k_scan<<<1, 1024, 0, stream>>>(deg, rowptr, fill, N);
  {
    const int nS = (E + 255) / 256;       // 1250 scatter blocks
    const int nE = (N + 63) / 64;         // 313 esed blocks
    k_scatter_esed<<<nS + nE, 256, 0, stream>>>(src, dst, fill, srcs, E,
                                                h0b, Pp1, es, ed, N, nS);
  }

  const int gE = (N + 7) / 8;   // 2500
  const int gP = N / 16;        // 1250

  // ---- layer 1: H=4, no GRU; post emits h1 + es/ed(L2) ----
  k_edge_gather<4><<<gE, 256, 0, stream>>>(rowptr, srcs, es, ed, h0b, tb, N);
  k_post1<<<gP, 256, 0, stream>>>(tb, B1, hA, hAb, Pf2, es, ed);
  // ---- layer 2: H=4, GRU; fused post+gru emits h2 + es/ed(L3) ----
  k_edge_gather<4><<<gE, 256, 0, stream>>>(rowptr, srcs, es, ed, hAb, tb, N);
  k_postgru<512, 0><<<gP, 256, 0, stream>>>(tb, B2, hAb, hA, Bih, Bhh, bih, bhh, hB, hBb,
                                            Pf3, es, ed, 4, nullptr, nullptr, nullptr);
  // ---- layer 3: H=4, GRU; emits h3 + es/ed(L4, H=1) ----
  k_edge_gather<4><<<gE, 256, 0, stream>>>(rowptr, srcs, es, ed, hBb, tb, N);
  k_postgru<512, 0><<<gP, 256, 0, stream>>>(tb, B3, hBb, hB, Bih, Bhh, bih, bhh, hA, hAb,
                                            Pf4, es, ed, 1, nullptr, nullptr, nullptr);
  // ---- layer 4: H=1, GRU + fused output head ----
  k_edge_gather<1><<<gE, 256, 0, stream>>>(rowptr, srcs, es, ed, hAb, tb, N);
  k_postgru<128, 1><<<gP, 256, 0, stream>>>(tb, B4, hAb, hA, Bih, Bhh, bih, bhh,
                                            nullptr, nullptr, nullptr, nullptr, nullptr, 0,
                                            W5, b5, (float*)d_out);
}

// Round 15
// 262.092 us; speedup vs baseline: 1.6564x; 1.0188x over previous
//
#include <hip/hip_runtime.h>
#include <math.h>

#define D 128

typedef __attribute__((ext_vector_type(8))) short bf16x8;
typedef __attribute__((ext_vector_type(4))) float f32x4;
typedef __attribute__((ext_vector_type(2))) float f32x2;

__device__ __forceinline__ float sigmoidf_(float x) { return 1.f / (1.f + __expf(-x)); }
__device__ __forceinline__ float u2f_lo(unsigned u) { return __uint_as_float(u << 16); }
__device__ __forceinline__ float u2f_hi(unsigned u) { return __uint_as_float(u & 0xffff0000u); }
__device__ __forceinline__ unsigned short f2b(float f) {
  unsigned u = __float_as_uint(f);
  return (unsigned short)((u + 0x7fffu + ((u >> 16) & 1u)) >> 16);  // RNE
}
__device__ __forceinline__ float leaky_(float v) { return v > 0.f ? v : 0.2f * v; }

// ---------- packing helpers ----------
__device__ __forceinline__ void pack_post_elem(const float* __restrict__ W,
                                               unsigned short* __restrict__ Bp, int i, float scale) {
  int j = i & 7;
  int lane = (i >> 3) & 63;
  int rest = i >> 9;
  int db = rest & 7;
  int kb = rest >> 3;
  int k = kb * 32 + ((lane >> 4) << 3) + j;
  int d = db * 16 + (lane & 15);
  int h = k >> 7, kk = k & 127;
  Bp[i] = f2b(W[((size_t)h * 128 + kk) * 128 + d] * scale);
}
__device__ __forceinline__ void pack_gru_elem(const float* __restrict__ S,
                                              unsigned short* __restrict__ Bp, int i) {
  int j = i & 7;
  int lane = (i >> 3) & 63;
  int rest = i >> 9;
  int db = rest % 24;
  int kb = rest / 24;
  int k = kb * 32 + ((lane >> 4) << 3) + j;
  int col = db * 16 + (lane & 15);
  Bp[i] = f2b(S[(size_t)col * 128 + k]);
}

// ---------- mega prep: f2b(h0) + pack all weights + projections + degree histogram ----------
__global__ void __launch_bounds__(256) k_prep(const float* __restrict__ h0, unsigned short* __restrict__ h0b,
                                              const float* __restrict__ W1, const float* __restrict__ W2,
                                              const float* __restrict__ W3, const float* __restrict__ W4,
                                              const float* __restrict__ Wih, const float* __restrict__ Whh,
                                              unsigned short* __restrict__ B1, unsigned short* __restrict__ B2,
                                              unsigned short* __restrict__ B3, unsigned short* __restrict__ B4,
                                              unsigned short* __restrict__ Bih, unsigned short* __restrict__ Bhh,
                                              const float* __restrict__ as1, const float* __restrict__ ad1,
                                              const float* __restrict__ as2, const float* __restrict__ ad2,
                                              const float* __restrict__ as3, const float* __restrict__ ad3,
                                              const float* __restrict__ as4, const float* __restrict__ ad4,
                                              unsigned short* __restrict__ Pp1, float* __restrict__ Pf2,
                                              float* __restrict__ Pf3, float* __restrict__ Pf4,
                                              const int* __restrict__ dst, int* __restrict__ deg,
                                              int N, int E) {
  int i = blockIdx.x * 256 + threadIdx.x;
  const int NH = N * 128;
  if (i < NH) {
    h0b[i] = f2b(h0[i]);
    return;
  }
  i -= NH;
  if (i < 311296) {
    if (i < 65536) pack_post_elem(W1, B1, i, 0.25f);
    else if (i < 131072) pack_post_elem(W2, B2, i - 65536, 0.25f);
    else if (i < 196608) pack_post_elem(W3, B3, i - 131072, 0.25f);
    else if (i < 212992) pack_post_elem(W4, B4, i - 196608, 1.0f);
    else if (i < 262144) pack_gru_elem(Wih, Bih, i - 212992);
    else pack_gru_elem(Whh, Bhh, i - 262144);
    return;
  }
  i -= 311296;
  if (i < 2048) {
    int j = i & 7;
    int lane = (i >> 3) & 63;
    int kb = i >> 9;
    int k = kb * 32 + ((lane >> 4) << 3) + j;
    int col = lane & 15;
    float val = 0.f;
    if (col < 8) {
      int c = col >= 4;
      int h = c ? (col - 4) : col;
      const float* wrow = W1 + ((size_t)h * 128 + k) * 128;
      const float* av = (c ? ad1 : as1) + (size_t)h * 128;
      for (int d2 = 0; d2 < 128; ++d2) val += wrow[d2] * av[d2];
    }
    Pp1[i] = f2b(val);
    return;
  }
  i -= 2048;
  if (i < 3072) {
    int layer = i >> 10;
    int qq = i & 1023;
    int k = qq >> 3;
    int slot = qq & 7;
    const float *W, *as_, *ad_;
    float* out;
    int H;
    if (layer == 0) { W = W2; as_ = as2; ad_ = ad2; out = Pf2; H = 4; }
    else if (layer == 1) { W = W3; as_ = as3; ad_ = ad3; out = Pf3; H = 4; }
    else { W = W4; as_ = as4; ad_ = ad4; out = Pf4; H = 1; }
    int h = slot & 3;
    bool isEd = slot >= 4;
    float val = 0.f;
    if (h < H) {
      const float* wrow = W + ((size_t)h * 128 + k) * 128;
      const float* av = (isEd ? ad_ : as_) + (size_t)h * 128;
      for (int d2 = 0; d2 < 128; ++d2) val += wrow[d2] * av[d2];
    }
    out[qq] = val;
    return;
  }
  i -= 3072;
  if (i < E) atomicAdd(&deg[dst[i]], 1);
}

// ---------- CSR scan ----------
__global__ void __launch_bounds__(1024) k_scan(const int* __restrict__ deg, int* __restrict__ rowptr,
                                               int* __restrict__ fill, int N) {
  __shared__ int part[1024];
  const int tid = threadIdx.x;
  const int chunk = (N + 1023) / 1024;
  const int b = tid * chunk;
  const int e = min(N, b + chunk);
  int s = 0;
  for (int i = b; i < e; ++i) s += deg[i];
  part[tid] = s;
  __syncthreads();
  for (int off = 1; off < 1024; off <<= 1) {
    int v = (tid >= off) ? part[tid - off] : 0;
    __syncthreads();
    part[tid] += v;
    __syncthreads();
  }
  int run = (tid == 0) ? 0 : part[tid - 1];
  for (int i = b; i < e; ++i) {
    rowptr[i] = run;
    fill[i] = run;
    run += deg[i];
  }
  if (b < N && e == N) rowptr[N] = run;
}

// ---------- merged: CSR scatter (blocks [0,nS)) + layer-1 es/ed MFMA (blocks [nS,...)) ----------
__global__ void __launch_bounds__(256) k_scatter_esed(const int* __restrict__ src, const int* __restrict__ dst,
                                                      int* __restrict__ fill, int* __restrict__ srcs, int E,
                                                      const unsigned short* __restrict__ hb,
                                                      const unsigned short* __restrict__ Pp,
                                                      float* __restrict__ es, float* __restrict__ ed,
                                                      int N, int nS) {
  if ((int)blockIdx.x < nS) {
    int e = blockIdx.x * 256 + threadIdx.x;
    if (e < E) {
      int pos = atomicAdd(&fill[dst[e]], 1);
      srcs[pos] = src[e];
    }
    return;
  }
  const int blk = blockIdx.x - nS;
  const int w = threadIdx.x >> 6;
  const int lane = threadIdx.x & 63;
  const int r = lane & 15, g = lane >> 4;
  const int n0 = blk * 64 + w * 16;
  f32x4 acc = (f32x4)0.f;
  const int koff = g << 3;
#pragma unroll
  for (int kb = 0; kb < 4; ++kb) {
    int row = min(n0 + r, N - 1);
    bf16x8 a = *(const bf16x8*)&hb[(size_t)row * 128 + kb * 32 + koff];
    bf16x8 b = *(const bf16x8*)&Pp[((size_t)(kb * 64) + lane) * 8];
    acc = __builtin_amdgcn_mfma_f32_16x16x32_bf16(a, b, acc, 0, 0, 0);
  }
  const int rbase = n0 + g * 4;
#pragma unroll
  for (int i = 0; i < 4; ++i) {
    int row = rbase + i;
    if (row < N) {
      if (r < 4) es[(size_t)row * 4 + r] = acc[i];
      else if (r < 8) ed[(size_t)row * 4 + (r - 4)] = acc[i];
    }
  }
}

// ---------- fused layer kernel: gather(LDS) -> post GEMM -> {elu | GRU} -> {proj | head} ----------
// 512 threads, 16 nodes/block. H in {4,1}; MODE: 0 = L1 (no GRU, elu out f32+bf16 + proj),
// 1 = GRU + proj, 2 = GRU + sigmoid(h@W5+b5) head.
// NOTE: no early returns (block-wide barriers); N must be a multiple of 16.
template <int H, int MODE>
__global__ void __launch_bounds__(512) k_layer(const int* __restrict__ rowptr,
                                               const int* __restrict__ srcs,
                                               const float* __restrict__ es,
                                               const float* __restrict__ ed,
                                               const unsigned short* __restrict__ hbG,
                                               const unsigned short* __restrict__ Bp,
                                               const float* __restrict__ hf,
                                               const unsigned short* __restrict__ Bih,
                                               const unsigned short* __restrict__ Bhh,
                                               const float* __restrict__ bih,
                                               const float* __restrict__ bhh,
                                               float* __restrict__ houtf,
                                               unsigned short* __restrict__ houtb,
                                               const float* __restrict__ Pf,
                                               float* __restrict__ eso, float* __restrict__ edo, int Hn,
                                               const float* __restrict__ W5,
                                               const float* __restrict__ b5,
                                               float* __restrict__ out) {
  constexpr int KD = H * 128;
  __shared__ unsigned short ts[16][KD + 8];   // +8 pad: row stride 4 banks -> only free 2-way alias
  __shared__ unsigned short xs[16][136];
  __shared__ float s_pr[16][8][8];
  __shared__ __align__(16) unsigned s_off[16][32];
  __shared__ __align__(16) float s_af[16][32][H == 1 ? 1 : 4];

  const int tid = threadIdx.x;
  const int n0 = blockIdx.x * 16;

  // ======== phase 1: per-node gather (16 nodes x 32 lanes) ========
  {
    const int slot = tid >> 5;
    const int t = n0 + slot;
    const int l = tid & 31;
    const int q = l & 15;
    const int eg = l >> 4;
    const int b0 = rowptr[t];
    const int deg = rowptr[t + 1] - b0;
    if (deg == 0) {
      if (l < 16) {
#pragma unroll
        for (int h = 0; h < H; ++h)
          *(uint4*)&ts[slot][h * 128 + q * 8] = make_uint4(0u, 0u, 0u, 0u);
      }
    } else {
      float edv[H];
#pragma unroll
      for (int h = 0; h < H; ++h) edv[h] = ed[(size_t)t * H + h];
      f32x2 acc[H][4];
#pragma unroll
      for (int h = 0; h < H; ++h)
#pragma unroll
        for (int j = 0; j < 4; ++j) acc[h][j] = (f32x2)0.f;
      const char* hbase = (const char*)hbG + q * 16;

      if (deg <= 32) {
        const bool act = l < deg;
        int s = 0;
        float vv[H];
        if (act) {
          s = srcs[b0 + l];
          if constexpr (H == 4) {
            float4 ev = *(const float4*)&es[(size_t)s * 4];
            vv[0] = leaky_(ev.x + edv[0]);
            vv[1] = leaky_(ev.y + edv[1]);
            vv[2] = leaky_(ev.z + edv[2]);
            vv[3] = leaky_(ev.w + edv[3]);
          } else {
            vv[0] = leaky_(es[s] + edv[0]);
          }
        } else {
#pragma unroll
          for (int h = 0; h < H; ++h) vv[h] = -1e30f;
        }
        float mv[H];
#pragma unroll
        for (int h = 0; h < H; ++h) mv[h] = vv[h];
#pragma unroll
        for (int off = 16; off; off >>= 1)
#pragma unroll
          for (int h = 0; h < H; ++h) mv[h] = fmaxf(mv[h], __shfl_xor(mv[h], off));
        float e[H], den[H];
#pragma unroll
        for (int h = 0; h < H; ++h) {
          e[h] = act ? __expf(vv[h] - mv[h]) : 0.f;
          den[h] = e[h];
        }
#pragma unroll
        for (int off = 16; off; off >>= 1)
#pragma unroll
          for (int h = 0; h < H; ++h) den[h] += __shfl_xor(den[h], off);
        s_off[slot][l] = act ? ((unsigned)s << 8) : 0u;
#pragma unroll
        for (int h = 0; h < H; ++h) s_af[slot][l][h] = e[h] * (1.f / den[h]);
        const int steps = (deg + 1) >> 1;
#pragma unroll 4
        for (int e2 = 0; e2 < steps; ++e2) {
          const int ei = e2 * 2 + eg;
          unsigned off = s_off[slot][ei];
          float af[H];
          if constexpr (H == 4) {
            float4 a4 = *(const float4*)&s_af[slot][ei][0];
            af[0] = a4.x; af[1] = a4.y; af[2] = a4.z; af[3] = a4.w;
          } else {
            af[0] = s_af[slot][ei][0];
          }
          uint4 v = *(const uint4*)(hbase + off);
          f32x2 vf0 = {u2f_lo(v.x), u2f_hi(v.x)};
          f32x2 vf1 = {u2f_lo(v.y), u2f_hi(v.y)};
          f32x2 vf2 = {u2f_lo(v.z), u2f_hi(v.z)};
          f32x2 vf3 = {u2f_lo(v.w), u2f_hi(v.w)};
#pragma unroll
          for (int h = 0; h < H; ++h) {
            f32x2 a2 = {af[h], af[h]};
            acc[h][0] += a2 * vf0;
            acc[h][1] += a2 * vf1;
            acc[h][2] += a2 * vf2;
            acc[h][3] += a2 * vf3;
          }
        }
      } else {
        // slow path (deg > 32): online softmax + chunked staging
        float m[H], den[H], vreg[H];
        int sreg = 0;
#pragma unroll
        for (int h = 0; h < H; ++h) {
          m[h] = -1e30f;
          den[h] = 0.f;
          vreg[h] = -1e30f;
        }
        for (int i = l; i < deg; i += 32) {
          int s = srcs[b0 + i];
          float vv[H];
          if constexpr (H == 4) {
            float4 ev = *(const float4*)&es[(size_t)s * 4];
            vv[0] = ev.x + edv[0];
            vv[1] = ev.y + edv[1];
            vv[2] = ev.z + edv[2];
            vv[3] = ev.w + edv[3];
          } else {
            vv[0] = es[s] + edv[0];
          }
#pragma unroll
          for (int h = 0; h < H; ++h) {
            float v = leaky_(vv[h]);
            vv[h] = v;
            float nm = fmaxf(m[h], v);
            den[h] = den[h] * __expf(m[h] - nm) + __expf(v - nm);
            m[h] = nm;
          }
          if (i == l) {
            sreg = s;
#pragma unroll
            for (int h = 0; h < H; ++h) vreg[h] = vv[h];
          }
        }
#pragma unroll
        for (int off = 16; off; off >>= 1) {
#pragma unroll
          for (int h = 0; h < H; ++h) {
            float om = __shfl_xor(m[h], off);
            float od = __shfl_xor(den[h], off);
            float nm = fmaxf(m[h], om);
            den[h] = den[h] * __expf(m[h] - nm) + od * __expf(om - nm);
            m[h] = nm;
          }
        }
        float rden[H];
#pragma unroll
        for (int h = 0; h < H; ++h) rden[h] = 1.f / den[h];
        for (int c0 = 0; c0 < deg; c0 += 32) {
          const int ce = min(32, deg - c0);
          if (c0 == 0) {
            bool ok = l < deg;
            s_off[slot][l] = ok ? ((unsigned)sreg << 8) : 0u;
#pragma unroll
            for (int h = 0; h < H; ++h)
              s_af[slot][l][h] = ok ? (__expf(vreg[h] - m[h]) * rden[h]) : 0.f;
          } else {
            int i = c0 + l;
            bool ok = i < deg;
            int s = ok ? srcs[b0 + i] : 0;
            s_off[slot][l] = ok ? ((unsigned)s << 8) : 0u;
            float af[H];
#pragma unroll
            for (int h = 0; h < H; ++h) af[h] = 0.f;
            if (ok) {
              float vv[H];
              if constexpr (H == 4) {
                float4 ev = *(const float4*)&es[(size_t)s * 4];
                vv[0] = ev.x + edv[0];
                vv[1] = ev.y + edv[1];
                vv[2] = ev.z + edv[2];
                vv[3] = ev.w + edv[3];
              } else {
                vv[0] = es[s] + edv[0];
              }
#pragma unroll
              for (int h = 0; h < H; ++h)
                af[h] = __expf(leaky_(vv[h]) - m[h]) * rden[h];
            }
#pragma unroll
            for (int h = 0; h < H; ++h) s_af[slot][l][h] = af[h];
          }
          const int steps = (ce + 1) >> 1;
#pragma unroll 4
          for (int e2 = 0; e2 < steps; ++e2) {
            const int ei = e2 * 2 + eg;
            unsigned off = s_off[slot][ei];
            float af[H];
            if constexpr (H == 4) {
              float4 a4 = *(const float4*)&s_af[slot][ei][0];
              af[0] = a4.x; af[1] = a4.y; af[2] = a4.z; af[3] = a4.w;
            } else {
              af[0] = s_af[slot][ei][0];
            }
            uint4 v = *(const uint4*)(hbase + off);
            f32x2 vf0 = {u2f_lo(v.x), u2f_hi(v.x)};
            f32x2 vf1 = {u2f_lo(v.y), u2f_hi(v.y)};
            f32x2 vf2 = {u2f_lo(v.z), u2f_hi(v.z)};
            f32x2 vf3 = {u2f_lo(v.w), u2f_hi(v.w)};
#pragma unroll
            for (int h = 0; h < H; ++h) {
              f32x2 a2 = {af[h], af[h]};
              acc[h][0] += a2 * vf0;
              acc[h][1] += a2 * vf1;
              acc[h][2] += a2 * vf2;
              acc[h][3] += a2 * vf3;
            }
          }
        }
      }
      // fold the 2 edge-groups and write t-row to LDS
#pragma unroll
      for (int h = 0; h < H; ++h)
#pragma unroll
        for (int j = 0; j < 4; ++j) {
          acc[h][j].x += __shfl_xor(acc[h][j].x, 16);
          acc[h][j].y += __shfl_xor(acc[h][j].y, 16);
        }
      if (l < 16) {
#pragma unroll
        for (int h = 0; h < H; ++h) {
          uint4 pk;
          pk.x = (unsigned)f2b(acc[h][0].x) | ((unsigned)f2b(acc[h][0].y) << 16);
          pk.y = (unsigned)f2b(acc[h][1].x) | ((unsigned)f2b(acc[h][1].y) << 16);
          pk.z = (unsigned)f2b(acc[h][2].x) | ((unsigned)f2b(acc[h][2].y) << 16);
          pk.w = (unsigned)f2b(acc[h][3].x) | ((unsigned)f2b(acc[h][3].y) << 16);
          *(uint4*)&ts[slot][h * 128 + q * 8] = pk;
        }
      }
    }
  }
  __syncthreads();

  // ======== phase 2: post GEMM (8 waves, wave w -> col tile w) ========
  const int w = tid >> 6;
  const int lane = tid & 63;
  const int r = lane & 15, g = lane >> 4;
  const int koff = g << 3;
  f32x4 pacc = (f32x4)0.f;
#pragma unroll
  for (int kb = 0; kb < KD / 32; ++kb) {
    bf16x8 a = *(const bf16x8*)&ts[r][kb * 32 + koff];
    bf16x8 b = *(const bf16x8*)&Bp[((size_t)(kb * 8 + w) * 64 + lane) * 8];
    pacc = __builtin_amdgcn_mfma_f32_16x16x32_bf16(a, b, pacc, 0, 0, 0);
  }
  const int col = w * 16 + r;

  if constexpr (MODE == 0) {
    // elu -> h_out (f32 + bf16) + next-layer es/ed projection
    float ps[4][8];
#pragma unroll
    for (int i = 0; i < 4; ++i)
#pragma unroll
      for (int c = 0; c < 8; ++c) ps[i][c] = 0.f;
    float4 pj0 = *(const float4*)&Pf[col * 8];
    float4 pj1 = *(const float4*)&Pf[col * 8 + 4];
#pragma unroll
    for (int i = 0; i < 4; ++i) {
      const int row = n0 + g * 4 + i;
      float o = pacc[i];
      o = o > 0.f ? o : expm1f(o);
      houtf[(size_t)row * 128 + col] = o;
      houtb[(size_t)row * 128 + col] = f2b(o);
      ps[i][0] += o * pj0.x; ps[i][1] += o * pj0.y;
      ps[i][2] += o * pj0.z; ps[i][3] += o * pj0.w;
      ps[i][4] += o * pj1.x; ps[i][5] += o * pj1.y;
      ps[i][6] += o * pj1.z; ps[i][7] += o * pj1.w;
    }
#pragma unroll
    for (int off = 1; off < 16; off <<= 1)
#pragma unroll
      for (int i = 0; i < 4; ++i)
#pragma unroll
        for (int c = 0; c < 8; ++c) ps[i][c] += __shfl_xor(ps[i][c], off);
    if (r == 0) {
#pragma unroll
      for (int i = 0; i < 4; ++i)
#pragma unroll
        for (int c = 0; c < 8; ++c) s_pr[g * 4 + i][c][w] = ps[i][c];
    }
    __syncthreads();
    if (tid < 128) {
      int row = tid >> 3;
      int c = tid & 7;
      float val = 0.f;
#pragma unroll
      for (int ww = 0; ww < 8; ++ww) val += s_pr[row][c][ww];
      int gr = n0 + row;
      if (c < 4) eso[(size_t)gr * 4 + c] = val;
      else edo[(size_t)gr * 4 + (c - 4)] = val;
    }
  } else {
    // stage x = elu(agg) bf16 in LDS, then GRU
#pragma unroll
    for (int i = 0; i < 4; ++i) {
      float o = pacc[i];
      o = o > 0.f ? o : expm1f(o);
      xs[g * 4 + i][col] = f2b(o);
    }
    __syncthreads();
    f32x4 ai[3], ah[3];
#pragma unroll
    for (int p = 0; p < 3; ++p) {
      ai[p] = (f32x4)0.f;
      ah[p] = (f32x4)0.f;
    }
#pragma unroll
    for (int kb = 0; kb < 4; ++kb) {
      bf16x8 ax = *(const bf16x8*)&xs[r][kb * 32 + koff];
      bf16x8 ahr = *(const bf16x8*)&hbG[(size_t)(n0 + r) * 128 + kb * 32 + koff];
#pragma unroll
      for (int p = 0; p < 3; ++p) {
        const int ct = p * 8 + w;
        bf16x8 bi = *(const bf16x8*)&Bih[((size_t)(kb * 24 + ct) * 64 + lane) * 8];
        bf16x8 bh = *(const bf16x8*)&Bhh[((size_t)(kb * 24 + ct) * 64 + lane) * 8];
        ai[p] = __builtin_amdgcn_mfma_f32_16x16x32_bf16(ax, bi, ai[p], 0, 0, 0);
        ah[p] = __builtin_amdgcn_mfma_f32_16x16x32_bf16(ahr, bh, ah[p], 0, 0, 0);
      }
    }
    const int j = col;
    const float bir = bih[j], biz = bih[128 + j], bin = bih[256 + j];
    const float bhr = bhh[j], bhz = bhh[128 + j], bhn = bhh[256 + j];
    if constexpr (MODE == 1) {
      float ps[4][8];
#pragma unroll
      for (int i = 0; i < 4; ++i)
#pragma unroll
        for (int c = 0; c < 8; ++c) ps[i][c] = 0.f;
      float4 pj0 = *(const float4*)&Pf[j * 8];
      float4 pj1 = *(const float4*)&Pf[j * 8 + 4];
#pragma unroll
      for (int i = 0; i < 4; ++i) {
        const int row = n0 + g * 4 + i;
        float rr = sigmoidf_(ai[0][i] + bir + ah[0][i] + bhr);
        float z = sigmoidf_(ai[1][i] + biz + ah[1][i] + bhz);
        float nn = tanhf(ai[2][i] + bin + rr * (ah[2][i] + bhn));
        float hp = hf[(size_t)row * 128 + j];
        float o = (1.f - z) * nn + z * hp;
        houtf[(size_t)row * 128 + j] = o;
        houtb[(size_t)row * 128 + j] = f2b(o);
        ps[i][0] += o * pj0.x; ps[i][1] += o * pj0.y;
        ps[i][2] += o * pj0.z; ps[i][3] += o * pj0.w;
        ps[i][4] += o * pj1.x; ps[i][5] += o * pj1.y;
        ps[i][6] += o * pj1.z; ps[i][7] += o * pj1.w;
      }
#pragma unroll
      for (int off = 1; off < 16; off <<= 1)
#pragma unroll
        for (int i = 0; i < 4; ++i)
#pragma unroll
          for (int c = 0; c < 8; ++c) ps[i][c] += __shfl_xor(ps[i][c], off);
      if (r == 0) {
#pragma unroll
        for (int i = 0; i < 4; ++i)
#pragma unroll
          for (int c = 0; c < 8; ++c) s_pr[g * 4 + i][c][w] = ps[i][c];
      }
      __syncthreads();
      if (tid < 128) {
        int row = tid >> 3;
        int c = tid & 7;
        float val = 0.f;
#pragma unroll
        for (int ww = 0; ww < 8; ++ww) val += s_pr[row][c][ww];
        int gr = n0 + row;
        if (c < Hn) eso[(size_t)gr * Hn + c] = val;
        else if (c >= 4 && c < 4 + Hn) edo[(size_t)gr * Hn + (c - 4)] = val;
      }
    } else {
      // MODE == 2: fused sigmoid(h@W5 + b5) head
      float pfin[4] = {0.f, 0.f, 0.f, 0.f};
      const float w5 = W5[j];
#pragma unroll
      for (int i = 0; i < 4; ++i) {
        const int row = n0 + g * 4 + i;
        float rr = sigmoidf_(ai[0][i] + bir + ah[0][i] + bhr);
        float z = sigmoidf_(ai[1][i] + biz + ah[1][i] + bhz);
        float nn = tanhf(ai[2][i] + bin + rr * (ah[2][i] + bhn));
        float hp = hf[(size_t)row * 128 + j];
        float o = (1.f - z) * nn + z * hp;
        pfin[i] += o * w5;
      }
#pragma unroll
      for (int off = 1; off < 16; off <<= 1)
#pragma unroll
        for (int i = 0; i < 4; ++i) pfin[i] += __shfl_xor(pfin[i], off);
      if (r == 0) {
#pragma unroll
        for (int i = 0; i < 4; ++i) s_pr[g * 4 + i][0][w] = pfin[i];
      }
      __syncthreads();
      if (tid < 16) {
        float s = b5[0];
#pragma unroll
        for (int ww = 0; ww < 8; ++ww) s += s_pr[tid][0][ww];
        out[n0 + tid] = sigmoidf_(s);
      }
    }
  }
}

extern "C" void kernel_launch(void* const* d_in, const int* in_sizes, int n_in,
                              void* d_out, int out_size, void* d_ws, size_t ws_size,
                              hipStream_t stream) {
  const float* h0 = (const float*)d_in[0];
  const int* ei = (const int*)d_in[1];
  const float* W1 = (const float*)d_in[2];
  const float* as1 = (const float*)d_in[3];
  const float* ad1 = (const float*)d_in[4];
  const float* W2 = (const float*)d_in[5];
  const float* as2 = (const float*)d_in[6];
  const float* ad2 = (const float*)d_in[7];
  const float* W3 = (const float*)d_in[8];
  const float* as3 = (const float*)d_in[9];
  const float* ad3 = (const float*)d_in[10];
  const float* W4 = (const float*)d_in[11];
  const float* as4 = (const float*)d_in[12];
  const float* ad4 = (const float*)d_in[13];
  const float* Wih = (const float*)d_in[14];
  const float* Whh = (const float*)d_in[15];
  const float* bih = (const float*)d_in[16];
  const float* bhh = (const float*)d_in[17];
  const float* W5 = (const float*)d_in[18];
  const float* b5 = (const float*)d_in[19];

  const int N = in_sizes[0] / D;  // 20000
  const int E = in_sizes[1] / 2;  // 320000
  const int* src = ei;
  const int* dst = ei + E;

  // ---- workspace layout ----
  float* ws = (float*)d_ws;
  float* hA = ws;                                     // N*128 f32
  float* hB = hA + (size_t)N * 128;                   // N*128 f32
  float* esA = hB + (size_t)N * 128;                  // N*4
  float* edA = esA + (size_t)N * 4;                   // N*4
  float* esB = edA + (size_t)N * 4;                   // N*4
  float* edB = esB + (size_t)N * 4;                   // N*4
  unsigned short* h0b = (unsigned short*)(edB + (size_t)N * 4);  // N*128 us
  unsigned short* hAb = h0b + (size_t)N * 128;        // N*128 us
  unsigned short* hBb = hAb + (size_t)N * 128;        // N*128 us
  unsigned short* B1 = hBb + (size_t)N * 128;         // 65536 us
  unsigned short* B2 = B1 + 65536;                    // 65536 us
  unsigned short* B3 = B2 + 65536;                    // 65536 us
  unsigned short* B4 = B3 + 65536;                    // 16384 us
  unsigned short* Bih = B4 + 16384;                   // 49152 us
  unsigned short* Bhh = Bih + 49152;                  // 49152 us
  unsigned short* Pp1 = Bhh + 49152;                  // 2048 us
  float* Pf2 = (float*)(Pp1 + 2048);                  // 1024 f
  float* Pf3 = Pf2 + 1024;                            // 1024 f
  float* Pf4 = Pf3 + 1024;                            // 1024 f
  int* deg = (int*)(Pf4 + 1024);                      // N
  int* rowptr = deg + N;                              // N+1
  int* fill = rowptr + N + 1;                         // N
  int* srcs = fill + N;                               // E

  // ---- prep ----
  hipMemsetAsync(deg, 0, (size_t)N * 4, stream);
  {
    const int total = N * 128 + 311296 + 2048 + 3072 + E;
    k_prep<<<(total + 255) / 256, 256, 0, stream>>>(
        h0, h0b, W1, W2, W3, W4, Wih, Whh, B1, B2, B3, B4, Bih, Bhh,
        as1, ad1, as2, ad2, as3, ad3, as4, ad4, Pp1, Pf2, Pf3, Pf4, dst, deg, N, E);
  }
  k_scan<<<1, 1024, 0, stream>>>(deg, rowptr, fill, N);
  {
    const int nS = (E + 255) / 256;       // scatter blocks
    const int nE = (N + 63) / 64;         // esed blocks
    k_scatter_esed<<<nS + nE, 256, 0, stream>>>(src, dst, fill, srcs, E,
                                                h0b, Pp1, esA, edA, N, nS);
  }

  const int gL = N / 16;  // 1250 (N divisible by 16)

  // ---- layer 1: H=4, no GRU; emits h1 (hA/hAb) + es/ed(L2) -> B buffers ----
  k_layer<4, 0><<<gL, 512, 0, stream>>>(rowptr, srcs, esA, edA, h0b, B1,
                                        nullptr, nullptr, nullptr, nullptr, nullptr,
                                        hA, hAb, Pf2, esB, edB, 4, nullptr, nullptr, nullptr);
  // ---- layer 2: H=4, GRU; emits h2 (hB/hBb) + es/ed(L3) -> A buffers ----
  k_layer<4, 1><<<gL, 512, 0, stream>>>(rowptr, srcs, esB, edB, hAb, B2,
                                        hA, Bih, Bhh, bih, bhh,
                                        hB, hBb, Pf3, esA, edA, 4, nullptr, nullptr, nullptr);
  // ---- layer 3: H=4, GRU; emits h3 (hA/hAb) + es/ed(L4, Hn=1) -> B buffers ----
  k_layer<4, 1><<<gL, 512, 0, stream>>>(rowptr, srcs, esA, edA, hBb, B3,
                                        hB, Bih, Bhh, bih, bhh,
                                        hA, hAb, Pf4, esB, edB, 1, nullptr, nullptr, nullptr);
  // ---- layer 4: H=1, GRU + fused output head ----
  k_layer<1, 2><<<gL, 512, 0, stream>>>(rowptr, srcs, esB, edB, hAb, B4,
                                        hA, Bih, Bhh, bih, bhh,
                                        nullptr, nullptr, nullptr, nullptr, nullptr, 0,
                                        W5, b5, (float*)d_out);
}